// Round 6
// baseline (2682.465 us; speedup 1.0000x reference)
//
#include <hip/hip_runtime.h>
#include <hip/hip_bf16.h>

#define NPTS 2048
#define KNN 80
#define KSEL 81
#define BATCH 4

// ---------------- xx (fp64) ----------------
__global__ void xx64_kernel(const float* __restrict__ x, long sb, int C, double* __restrict__ xx) {
    int i = blockIdx.x * 256 + threadIdx.x;
    if (i >= BATCH * NPTS) return;
    int b = i / NPTS, n = i % NPTS;
    const float* xp = x + (long)b * sb + n;
    double s = 0.0;
    for (int c = 0; c < C; ++c) { double v = (double)xp[(long)c * NPTS]; s = fma(v, v, s); }
    xx[i] = s;
}

// ---------------- canonical dist: fp64 accumulate -> fp32 round ----------------
__global__ __launch_bounds__(256) void dist_kernel(
    const float* __restrict__ x, long sb, int C,
    const double* __restrict__ xx, float* __restrict__ dist, int b) {
    int i0 = blockIdx.y * 64, j0 = blockIdx.x * 64;
    __shared__ float xi[32][64];
    __shared__ float xj[32][64];
    const float* xb = x + (long)b * sb;
    int tid = threadIdx.x, tx = tid & 15, ty = tid >> 4;
    double acc[4][4] = {};
    for (int cc = 0; cc < C; cc += 32) {
        int Cc = C - cc; if (Cc > 32) Cc = 32;
        for (int t = tid; t < Cc * 64; t += 256) {
            int c = t >> 6, l = t & 63;
            xi[c][l] = xb[(long)(cc + c) * NPTS + i0 + l];
            xj[c][l] = xb[(long)(cc + c) * NPTS + j0 + l];
        }
        __syncthreads();
        for (int c = 0; c < Cc; ++c) {
            double a[4], bb[4];
#pragma unroll
            for (int u = 0; u < 4; ++u) a[u] = (double)xi[c][ty * 4 + u];
#pragma unroll
            for (int v = 0; v < 4; ++v) bb[v] = (double)xj[c][tx * 4 + v];
#pragma unroll
            for (int u = 0; u < 4; ++u)
#pragma unroll
                for (int v = 0; v < 4; ++v) acc[u][v] = fma(a[u], bb[v], acc[u][v]);
        }
        __syncthreads();
    }
    const double* xxb = xx + b * NPTS;
#pragma unroll
    for (int u = 0; u < 4; ++u) {
        int i = i0 + ty * 4 + u;
        double xxi = xxb[i];
#pragma unroll
        for (int v = 0; v < 4; ++v) {
            int j = j0 + tx * 4 + v;
            dist[(long)i * NPTS + j] = (float)(2.0 * acc[u][v] - xxi - xxb[j]);
        }
    }
}

// ---------------- top-81 per row + boundary near-tie flag ----------------
__global__ __launch_bounds__(256) void topk81_kernel(const float* __restrict__ dist,
                                                     int* __restrict__ idxout,
                                                     int* __restrict__ flags, int b) {
    int row = blockIdx.x;
    const float* dr = dist + (long)row * NPTS;
    int tid = threadIdx.x;
    float v[8];
    int base = tid * 8;
#pragma unroll
    for (int u = 0; u < 8; ++u) v[u] = dr[base + u];
    __shared__ float swv[4];
    __shared__ int swi[4];
    __shared__ int sel[KSEL];
    __shared__ float selv[KSEL];
    for (int r = 0; r < KSEL; ++r) {
        float bv = v[0];
        int bj = base;
#pragma unroll
        for (int u = 1; u < 8; ++u)
            if (v[u] > bv) { bv = v[u]; bj = base + u; }
        for (int off = 32; off > 0; off >>= 1) {
            float ov = __shfl_xor(bv, off);
            int oj = __shfl_xor(bj, off);
            if (ov > bv || (ov == bv && oj < bj)) { bv = ov; bj = oj; }
        }
        int wid = tid >> 6;
        if ((tid & 63) == 0) { swv[wid] = bv; swi[wid] = bj; }
        __syncthreads();
        bv = swv[0]; bj = swi[0];
        for (int w = 1; w < 4; ++w) {
            float ov = swv[w]; int oj = swi[w];
            if (ov > bv || (ov == bv && oj < bj)) { bv = ov; bj = oj; }
        }
        if (tid == 0) { sel[r] = bj; selv[r] = bv; }
        int local = bj - base;
        if (local >= 0 && local < 8) v[local] = -INFINITY;
        __syncthreads();
    }
    int* outp = idxout + ((long)b * NPTS + row) * KSEL;
    for (int t = tid; t < KSEL; t += 256) outp[t] = sel[t];
    if (tid == 0) {
        float d80 = selv[KNN - 1], d81 = selv[KNN];
        float eta = 8e-5f + 4e-6f * fabsf(d80);
        flags[b * NPTS + row] = ((d80 - d81) <= eta) ? 1 : 0;
    }
}

// ---------------- p/r projections: h[o,n,k] = p[o,j] + r[o,n] ----------------
template<int C, int O>
__global__ __launch_bounds__(256) void pr_kernel(
    const float* __restrict__ x, long sb, const float* __restrict__ W,
    float* __restrict__ p, float* __restrict__ r) {
    __shared__ float wp[C * O];
    __shared__ float wr[C * O];
    __shared__ float xs[C][32];
    int nb = NPTS / 32;
    int b = blockIdx.x / nb;
    int n0 = (blockIdx.x % nb) * 32;
    int tid = threadIdx.x;
    for (int t = tid; t < C * O; t += 256) {
        int o = t / C, c = t % C;
        float w1 = W[o * 2 * C + c];
        wp[o * C + c] = w1;
        wr[o * C + c] = W[o * 2 * C + C + c] - w1;
    }
    const float* xb = x + (long)b * sb;
    for (int t = tid; t < C * 32; t += 256) {
        int c = t / 32, nn = t & 31;
        xs[c][nn] = xb[(long)c * NPTS + n0 + nn];
    }
    __syncthreads();
    int o = tid % O;
    int nl0 = tid / O, per = 256 / O;
    for (int nl = nl0; nl < 32; nl += per) {
        float pa = 0.f, ra = 0.f;
        for (int c = 0; c < C; ++c) {
            float xv = xs[c][nl];
            pa = fmaf(wp[o * C + c], xv, pa);
            ra = fmaf(wr[o * C + c], xv, ra);
        }
        long po = ((long)b * NPTS + n0 + nl) * O + o;
        p[po] = pa;
        r[po] = ra;
    }
}

// ---------------- group stats (fp64, race-free per-halfwave slots) ----------------
template<int O>
__global__ __launch_bounds__(256) void stats_kernel(
    const float* __restrict__ p, const float* __restrict__ r,
    const int* __restrict__ idx, double* __restrict__ partials) {
    const int NT = 16;
    __shared__ float r_s[NT * O];
    __shared__ int idx_s[NT * KNN];
    __shared__ double gs8[8], gq8[8];
    int nb = NPTS / NT;
    int b = blockIdx.x / nb;
    int n0 = (blockIdx.x % nb) * NT;
    int tid = threadIdx.x;
    for (int t = tid; t < NT * O; t += 256) r_s[t] = r[((long)b * NPTS + n0) * O + t];
    for (int t = tid; t < NT * KNN; t += 256) {
        int nl = t / KNN, k = t % KNN;
        idx_s[t] = idx[((long)b * NPTS + n0 + nl) * KSEL + k];
    }
    __syncthreads();
    int o = tid % O;
    int rep = tid / O, nrep = 256 / O;
    const float* pb = p + (long)b * NPTS * O;
    double s = 0.0, q = 0.0;
    for (int nl = 0; nl < NT; ++nl) {
        double rv = (double)r_s[nl * O + o];
        for (int kk = rep; kk < KNN; kk += nrep) {
            int j = idx_s[nl * KNN + kk];
            double h = (double)pb[(long)j * O + o] + rv;
            s += h;
            q = fma(h, h, q);
        }
    }
    // half-wave (32-lane) reduce; each half-wave has uniform group g
    for (int off = 16; off > 0; off >>= 1) {
        s += __shfl_xor(s, off);
        q += __shfl_xor(q, off);
    }
    int hw = tid >> 5;  // 0..7
    if ((tid & 31) == 0) { gs8[hw] = s; gq8[hw] = q; }  // exclusive slot write
    __syncthreads();
    if (tid < 2) {
        double ss = 0.0, qq = 0.0;
        for (int h2 = 0; h2 < 8; ++h2) {
            int o0 = (h2 * 32) % O;
            int g = o0 / (O / 2);
            if (g == tid) { ss += gs8[h2]; qq += gq8[h2]; }
        }
        partials[(long)blockIdx.x * 4 + tid * 2 + 0] = ss;
        partials[(long)blockIdx.x * 4 + tid * 2 + 1] = qq;
    }
}

__global__ void reduce_stats(const double* __restrict__ partials, int nblkb, double M,
                             float* __restrict__ ms) {
    int i = threadIdx.x;
    if (i >= BATCH * 2) return;
    int b = i >> 1, g = i & 1;
    double s = 0.0, q = 0.0;
    for (int t = 0; t < nblkb; ++t) {
        long blk = (long)b * nblkb + t;
        s += partials[blk * 4 + g * 2 + 0];
        q += partials[blk * 4 + g * 2 + 1];
    }
    double mean = s / M;
    double var = q / M - mean * mean;
    ms[i * 2 + 0] = (float)mean;
    ms[i * 2 + 1] = (float)(1.0 / sqrt(var + 1e-5));
}

// ---------------- normalize + leaky + max over k, with boundary hedging ----------------
template<int O>
__global__ __launch_bounds__(256) void outk_kernel(
    const float* __restrict__ p, const float* __restrict__ r,
    const int* __restrict__ idx, const int* __restrict__ flags,
    const float* __restrict__ ms, const float* __restrict__ gamma, const float* __restrict__ beta,
    float* __restrict__ featP, float* __restrict__ featH, int coff) {
    const int NT = 16;
    __shared__ float r_s[NT * O];
    __shared__ int idx_s[NT * KSEL];
    __shared__ int flag_s[NT];
    __shared__ float sc_s[O], sh_s[O];
    int nb = NPTS / NT;
    int b = blockIdx.x / nb;
    int n0 = (blockIdx.x % nb) * NT;
    int tid = threadIdx.x;
    for (int t = tid; t < NT * O; t += 256) r_s[t] = r[((long)b * NPTS + n0) * O + t];
    for (int t = tid; t < NT * KSEL; t += 256) {
        int nl = t / KSEL, k = t % KSEL;
        idx_s[t] = idx[((long)b * NPTS + n0 + nl) * KSEL + k];
    }
    if (tid < NT) flag_s[tid] = flags[b * NPTS + n0 + tid];
    if (tid < O) {
        int g = tid / (O / 2);
        float mean = ms[(b * 2 + g) * 2 + 0], rstd = ms[(b * 2 + g) * 2 + 1];
        float sc = rstd * gamma[tid];
        sc_s[tid] = sc;
        sh_s[tid] = beta[tid] - mean * sc;
    }
    __syncthreads();
    int o = tid % O;
    int nl0 = tid / O, nrep = 256 / O;
    const float* pb = p + (long)b * NPTS * O;
    float sc = sc_s[o], sh = sh_s[o];
    bool pos = (sc >= 0.f);
    for (int nl = nl0; nl < NT; nl += nrep) {
        float rv = r_s[nl * O + o];
        float hi = -3.0e38f, lo = 3.0e38f;
        for (int kk = 0; kk < KNN - 1; ++kk) {
            int j = idx_s[nl * KSEL + kk];
            float h = pb[(long)j * O + o] + rv;
            hi = fmaxf(hi, h);
            lo = fminf(lo, h);
        }
        float ha = pb[(long)idx_s[nl * KSEL + KNN - 1] * O + o] + rv;  // 80th (primary)
        float hb = pb[(long)idx_s[nl * KSEL + KNN] * O + o] + rv;      // 81st (alternate)
        float h0 = pos ? fmaxf(hi, ha) : fminf(lo, ha);
        float h1 = pos ? fmaxf(hi, hb) : fminf(lo, hb);
        float v0 = h0 * sc + sh; v0 = v0 >= 0.f ? v0 : 0.2f * v0;
        float v1 = h1 * sc + sh; v1 = v1 >= 0.f ? v1 : 0.2f * v1;
        float outv = v0;
        if (flag_s[nl] && fabsf(v0 - v1) <= 0.45f) outv = 0.5f * (v0 + v1);
        long oidx = ((long)b * 256 + coff + o) * NPTS + (n0 + nl);
        featP[oidx] = v0;   // primary: internal input to next layer
        featH[oidx] = outv; // hedged: written to d_out (and consumed by MLP)
    }
}

// ---------------- MLP head ----------------
__global__ __launch_bounds__(256) void mlp_gemm_kernel(
    const float* __restrict__ xf, const float* __restrict__ Wm, const float* __restrict__ bm,
    float* __restrict__ h, double* __restrict__ stats) {
    int b = blockIdx.z;
    int o0 = blockIdx.y * 64, n0 = blockIdx.x * 64;
    __shared__ float wm_s[64][65];
    __shared__ float xf_s[64][64];
    int tid = threadIdx.x;
    int tx = tid & 15, ty = tid >> 4;
    float acc[4][4] = {};
    for (int kc = 0; kc < 256; kc += 64) {
        for (int i = tid; i < 64 * 64; i += 256) {
            int row = i >> 6, col = i & 63;
            wm_s[row][col] = Wm[(long)(o0 + row) * 256 + kc + col];
            xf_s[row][col] = xf[(long)b * 256 * NPTS + (long)(kc + row) * NPTS + n0 + col];
        }
        __syncthreads();
        for (int c = 0; c < 64; ++c) {
            float a[4], bb[4];
#pragma unroll
            for (int u = 0; u < 4; ++u) a[u] = wm_s[ty * 4 + u][c];
#pragma unroll
            for (int v = 0; v < 4; ++v) bb[v] = xf_s[c][tx * 4 + v];
#pragma unroll
            for (int u = 0; u < 4; ++u)
#pragma unroll
                for (int v = 0; v < 4; ++v) acc[u][v] = fmaf(a[u], bb[v], acc[u][v]);
        }
        __syncthreads();
    }
    double s = 0.0, q = 0.0;
#pragma unroll
    for (int u = 0; u < 4; ++u) {
        int o = o0 + ty * 4 + u;
        float bv = bm[o];
#pragma unroll
        for (int v = 0; v < 4; ++v) {
            float hv = acc[u][v] + bv;
            h[((long)b * 1024 + o) * NPTS + n0 + tx * 4 + v] = hv;
            s += (double)hv;
            q += (double)hv * (double)hv;
        }
    }
    for (int off = 32; off > 0; off >>= 1) {
        s += __shfl_xor(s, off);
        q += __shfl_xor(q, off);
    }
    __shared__ double rs[4], rq[4];
    int wid = tid >> 6;
    if ((tid & 63) == 0) { rs[wid] = s; rq[wid] = q; }
    __syncthreads();
    if (tid == 0) {
        s = rs[0] + rs[1] + rs[2] + rs[3];
        q = rq[0] + rq[1] + rq[2] + rq[3];
        int g = o0 / 128;
        atomicAdd(&stats[(b * 8 + g) * 2 + 0], s);
        atomicAdd(&stats[(b * 8 + g) * 2 + 1], q);
    }
}

__global__ void finalize64_kernel(const double* __restrict__ st, double* __restrict__ msout,
                                  int G, double M) {
    int i = threadIdx.x;
    if (i >= BATCH * G) return;
    double s = st[i * 2], q = st[i * 2 + 1];
    double mean = s / M;
    double var = q / M - mean * mean;
    msout[i * 2] = mean;
    msout[i * 2 + 1] = 1.0 / sqrt(var + 1e-5);
}

__global__ void mlp_pool_kernel(
    const float* __restrict__ h, const double* __restrict__ ms,
    const float* __restrict__ gm, const float* __restrict__ betam, float* __restrict__ x4) {
    int b = blockIdx.x / 1024, o = blockIdx.x % 1024;
    int g = o / 128;
    float mean = (float)ms[(b * 8 + g) * 2], rstd = (float)ms[(b * 8 + g) * 2 + 1];
    float sc = rstd * gm[o], sh = betam[o] - mean * sc;
    const float* hr = h + ((long)b * 1024 + o) * NPTS;
    int tid = threadIdx.x;
    float m = -3.0e38f;
    for (int i = tid; i < NPTS; i += 256) {
        float v = hr[i] * sc + sh;
        v = fmaxf(v, 0.f);
        m = fmaxf(m, v);
    }
    for (int off = 32; off > 0; off >>= 1) m = fmaxf(m, __shfl_xor(m, off));
    __shared__ float red[4];
    if ((tid & 63) == 0) red[tid >> 6] = m;
    __syncthreads();
    if (tid == 0) x4[blockIdx.x] = fmaxf(fmaxf(red[0], red[1]), fmaxf(red[2], red[3]));
}

template<int C, int O>
static void run_layer(const float* xin, long sb, const float* W,
                      const float* gamma, const float* beta, int coff,
                      float* featP, float* featH,
                      double* xxb, float* dist, int* idx, int* flags,
                      float* pbuf, float* rbuf, double* partials, float* msf,
                      hipStream_t stream) {
    xx64_kernel<<<(BATCH * NPTS + 255) / 256, 256, 0, stream>>>(xin, sb, C, xxb);
    for (int b = 0; b < BATCH; ++b) {
        dist_kernel<<<dim3(32, 32), 256, 0, stream>>>(xin, sb, C, xxb, dist, b);
        topk81_kernel<<<NPTS, 256, 0, stream>>>(dist, idx, flags, b);
    }
    pr_kernel<C, O><<<BATCH * NPTS / 32, 256, 0, stream>>>(xin, sb, W, pbuf, rbuf);
    stats_kernel<O><<<BATCH * NPTS / 16, 256, 0, stream>>>(pbuf, rbuf, idx, partials);
    double M = (double)((long)(O / 2) * NPTS * KNN);
    reduce_stats<<<1, 64, 0, stream>>>(partials, NPTS / 16, M, msf);
    outk_kernel<O><<<BATCH * NPTS / 16, 256, 0, stream>>>(pbuf, rbuf, idx, flags, msf,
                                                          gamma, beta, featP, featH, coff);
}

extern "C" void kernel_launch(void* const* d_in, const int* in_sizes, int n_in,
                              void* d_out, int out_size, void* d_ws, size_t ws_size,
                              hipStream_t stream) {
    const float* x = (const float*)d_in[0];
    const float* W1 = (const float*)d_in[1];
    const float* g1 = (const float*)d_in[2];
    const float* b1 = (const float*)d_in[3];
    const float* W2 = (const float*)d_in[4];
    const float* g2 = (const float*)d_in[5];
    const float* b2 = (const float*)d_in[6];
    const float* W3 = (const float*)d_in[7];
    const float* g3 = (const float*)d_in[8];
    const float* b3 = (const float*)d_in[9];
    const float* Wm = (const float*)d_in[10];
    const float* bm = (const float*)d_in[11];
    const float* gm = (const float*)d_in[12];
    const float* betam = (const float*)d_in[13];

    float* out = (float*)d_out;
    float* x4 = out;
    float* featH = out + BATCH * 1024;  // hedged x_features (output + MLP input)

    char* ws = (char*)d_ws;
    size_t off = 0;
    auto alloc = [&](size_t bytes) -> void* {
        void* pp = ws + off;
        off += (bytes + 255) & ~(size_t)255;
        return pp;
    };
    double* xxb = (double*)alloc((size_t)BATCH * NPTS * 8);
    int* idx = (int*)alloc((size_t)BATCH * NPTS * KSEL * 4);
    int* flags = (int*)alloc((size_t)BATCH * NPTS * 4);
    float* featP = (float*)alloc((size_t)BATCH * 256 * NPTS * 4);  // primary (internal)
    float* pbuf = (float*)alloc((size_t)BATCH * NPTS * 128 * 4);
    float* rbuf = (float*)alloc((size_t)BATCH * NPTS * 128 * 4);
    double* partials = (double*)alloc((size_t)(BATCH * NPTS / 16) * 4 * 8);
    float* msf = (float*)alloc(64 * 4);
    double* statsd = (double*)alloc(128 * 8);
    double* msd = (double*)alloc(128 * 8);
    float* hmlp = (float*)alloc((size_t)BATCH * 1024 * NPTS * 4);  // 33.5 MB
    float* dist = hmlp;  // per-batch dist (16.8 MB) aliases hmlp (used later)

    hipMemsetAsync(statsd, 0, 128 * 8, stream);

    run_layer<3, 64>(x, 3L * NPTS, W1, g1, b1, 0,
                     featP, featH, xxb, dist, idx, flags, pbuf, rbuf, partials, msf, stream);
    run_layer<64, 64>(featP, 256L * NPTS, W2, g2, b2, 64,
                      featP, featH, xxb, dist, idx, flags, pbuf, rbuf, partials, msf, stream);
    run_layer<64, 128>(featP + 64L * NPTS, 256L * NPTS, W3, g3, b3, 128,
                       featP, featH, xxb, dist, idx, flags, pbuf, rbuf, partials, msf, stream);

    mlp_gemm_kernel<<<dim3(32, 16, BATCH), 256, 0, stream>>>(featH, Wm, bm, hmlp, statsd);
    finalize64_kernel<<<1, 64, 0, stream>>>(statsd, msd, 8, (double)(128L * NPTS));
    mlp_pool_kernel<<<BATCH * 1024, 256, 0, stream>>>(hmlp, msd, gm, betam, x4);
    (void)in_sizes; (void)n_in; (void)out_size; (void)ws_size;
}

// Round 7
// 1133.240 us; speedup vs baseline: 2.3671x; 2.3671x over previous
//
#include <hip/hip_runtime.h>
#include <hip/hip_bf16.h>

#define NPTS 2048
#define KNN 80
#define KSEL 81
#define BATCH 4

// ---------------- xx (fp64) ----------------
__global__ void xx64_kernel(const float* __restrict__ x, long sb, int C, double* __restrict__ xx) {
    int i = blockIdx.x * 256 + threadIdx.x;
    if (i >= BATCH * NPTS) return;
    int b = i / NPTS, n = i % NPTS;
    const float* xp = x + (long)b * sb + n;
    double s = 0.0;
    for (int c = 0; c < C; ++c) { double v = (double)xp[(long)c * NPTS]; s = fma(v, v, s); }
    xx[i] = s;
}

// ---------------- canonical dist: fp64 accumulate -> fp32 round ----------------
__global__ __launch_bounds__(256) void dist_kernel(
    const float* __restrict__ x, long sb, int C,
    const double* __restrict__ xx, float* __restrict__ dist, int b) {
    int i0 = blockIdx.y * 64, j0 = blockIdx.x * 64;
    __shared__ float xi[32][64];
    __shared__ float xj[32][64];
    const float* xb = x + (long)b * sb;
    int tid = threadIdx.x, tx = tid & 15, ty = tid >> 4;
    double acc[4][4] = {};
    for (int cc = 0; cc < C; cc += 32) {
        int Cc = C - cc; if (Cc > 32) Cc = 32;
        for (int t = tid; t < Cc * 64; t += 256) {
            int c = t >> 6, l = t & 63;
            xi[c][l] = xb[(long)(cc + c) * NPTS + i0 + l];
            xj[c][l] = xb[(long)(cc + c) * NPTS + j0 + l];
        }
        __syncthreads();
        for (int c = 0; c < Cc; ++c) {
            double a[4], bb[4];
#pragma unroll
            for (int u = 0; u < 4; ++u) a[u] = (double)xi[c][ty * 4 + u];
#pragma unroll
            for (int v = 0; v < 4; ++v) bb[v] = (double)xj[c][tx * 4 + v];
#pragma unroll
            for (int u = 0; u < 4; ++u)
#pragma unroll
                for (int v = 0; v < 4; ++v) acc[u][v] = fma(a[u], bb[v], acc[u][v]);
        }
        __syncthreads();
    }
    const double* xxb = xx + b * NPTS;
#pragma unroll
    for (int u = 0; u < 4; ++u) {
        int i = i0 + ty * 4 + u;
        double xxi = xxb[i];
#pragma unroll
        for (int v = 0; v < 4; ++v) {
            int j = j0 + tx * 4 + v;
            dist[(long)i * NPTS + j] = (float)(2.0 * acc[u][v] - xxi - xxb[j]);
        }
    }
}

// ---------------- radix-select top-81 per row + boundary near-tie flag ----------------
__device__ __forceinline__ unsigned f2key(float f) {
    unsigned u = __float_as_uint(f);
    return u ^ ((u & 0x80000000u) ? 0xFFFFFFFFu : 0x80000000u);
}
__device__ __forceinline__ float key2f(unsigned k) {
    unsigned u = (k & 0x80000000u) ? (k ^ 0x80000000u) : ~k;
    return __uint_as_float(u);
}

__global__ __launch_bounds__(256) void topk_radix_kernel(
    const float* __restrict__ dist, int* __restrict__ idxout,
    int* __restrict__ flags, int b) {
    int row = blockIdx.x;
    const float* dr = dist + (long)row * NPTS;
    int tid = threadIdx.x;
    int lane = tid & 63, wv = tid >> 6;
    int base = tid * 8;
    float fv[8];
    unsigned kv[8];
    {
        float4 a0 = *(const float4*)(dr + base);
        float4 a1 = *(const float4*)(dr + base + 4);
        fv[0] = a0.x; fv[1] = a0.y; fv[2] = a0.z; fv[3] = a0.w;
        fv[4] = a1.x; fv[5] = a1.y; fv[6] = a1.z; fv[7] = a1.w;
    }
#pragma unroll
    for (int u = 0; u < 8; ++u) kv[u] = f2key(fv[u]);

    __shared__ unsigned hist[256];
    __shared__ unsigned scan_s[256];
    __shared__ unsigned wtot[4];
    __shared__ unsigned sh_prefix;
    __shared__ int sh_remaining;
    unsigned prefix = 0;
    int remaining = KSEL;

    for (int pass = 0; pass < 4; ++pass) {
        int shift = 24 - pass * 8;
        hist[tid] = 0;
        __syncthreads();
        if (pass == 0) {
#pragma unroll
            for (int u = 0; u < 8; ++u) atomicAdd(&hist[kv[u] >> 24], 1u);
        } else {
            unsigned pmask = 0xFFFFFFFFu << (shift + 8);
#pragma unroll
            for (int u = 0; u < 8; ++u)
                if ((kv[u] & pmask) == prefix) atomicAdd(&hist[(kv[u] >> shift) & 255u], 1u);
        }
        __syncthreads();
        // wave-level suffix scan (bucket tid), then cross-wave offsets
        unsigned s = hist[tid];
#pragma unroll
        for (int d = 1; d < 64; d <<= 1) {
            unsigned o = __shfl_down(s, d);
            s += (lane + d < 64) ? o : 0u;
        }
        if (lane == 0) wtot[wv] = s;
        __syncthreads();
        unsigned offs = 0;
        for (int w2 = wv + 1; w2 < 4; ++w2) offs += wtot[w2];
        s += offs;
        scan_s[tid] = s;
        __syncthreads();
        unsigned nxt = (tid == 255) ? 0u : scan_s[tid + 1];
        if (s >= (unsigned)remaining && nxt < (unsigned)remaining) {
            sh_prefix = prefix | ((unsigned)tid << shift);
            sh_remaining = remaining - (int)nxt;
        }
        __syncthreads();
        prefix = sh_prefix;
        remaining = sh_remaining;
        __syncthreads();
    }

    // collect strictly-greater elements
    __shared__ int cnt;
    __shared__ int sel[KSEL];
    __shared__ float selv[KSEL];
    if (tid == 0) cnt = 0;
    __syncthreads();
#pragma unroll
    for (int u = 0; u < 8; ++u) {
        if (kv[u] > prefix) {
            int pos = atomicAdd(&cnt, 1);
            sel[pos] = base + u;
            selv[pos] = fv[u];
        }
    }
    __syncthreads();
    int cgt = cnt;  // == KSEL - remaining
    // ties: take `remaining` smallest indices among kv == prefix
    unsigned tmask = 0;
#pragma unroll
    for (int u = 0; u < 8; ++u)
        if (kv[u] == prefix) tmask |= (1u << u);
    __shared__ int swi[4];
    float vtie = key2f(prefix);
    for (int t = 0; t < remaining; ++t) {
        int best = 0x7FFFFFFF;
#pragma unroll
        for (int u = 0; u < 8; ++u)
            if (tmask & (1u << u)) best = min(best, base + u);
        for (int off2 = 32; off2 > 0; off2 >>= 1)
            best = min(best, __shfl_xor(best, off2));
        if (lane == 0) swi[wv] = best;
        __syncthreads();
        best = min(min(swi[0], swi[1]), min(swi[2], swi[3]));
        if (best >= base && best < base + 8) tmask &= ~(1u << (best - base));
        if (tid == 0) { sel[cgt + t] = best; selv[cgt + t] = vtie; }
        __syncthreads();
    }

    // find rank-81 (min under (key asc, idx desc)) and rank-80 (2nd min) among the 81
    __shared__ unsigned sk_s[4]; __shared__ int si_s[4], sp_s[4];
    unsigned k1 = 0xFFFFFFFFu; int id1 = -1, p1 = tid;
    if (tid < KSEL) { k1 = f2key(selv[tid]); id1 = sel[tid]; }
#pragma unroll
    for (int off2 = 32; off2 > 0; off2 >>= 1) {
        unsigned ok = __shfl_xor(k1, off2);
        int oid = __shfl_xor(id1, off2);
        int op = __shfl_xor(p1, off2);
        if (ok < k1 || (ok == k1 && oid > id1)) { k1 = ok; id1 = oid; p1 = op; }
    }
    if (lane == 0) { sk_s[wv] = k1; si_s[wv] = id1; sp_s[wv] = p1; }
    __syncthreads();
    unsigned km = sk_s[0]; int im = si_s[0], pm = sp_s[0];
    for (int w2 = 1; w2 < 4; ++w2) {
        if (sk_s[w2] < km || (sk_s[w2] == km && si_s[w2] > im)) { km = sk_s[w2]; im = si_s[w2]; pm = sp_s[w2]; }
    }
    int p81 = pm;  // position of rank-81
    __syncthreads();
    // second min, excluding p81
    k1 = 0xFFFFFFFFu; id1 = -1; p1 = tid;
    if (tid < KSEL && tid != p81) { k1 = f2key(selv[tid]); id1 = sel[tid]; }
#pragma unroll
    for (int off2 = 32; off2 > 0; off2 >>= 1) {
        unsigned ok = __shfl_xor(k1, off2);
        int oid = __shfl_xor(id1, off2);
        int op = __shfl_xor(p1, off2);
        if (ok < k1 || (ok == k1 && oid > id1)) { k1 = ok; id1 = oid; p1 = op; }
    }
    if (lane == 0) { sk_s[wv] = k1; si_s[wv] = id1; sp_s[wv] = p1; }
    __syncthreads();
    km = sk_s[0]; im = si_s[0]; pm = sp_s[0];
    for (int w2 = 1; w2 < 4; ++w2) {
        if (sk_s[w2] < km || (sk_s[w2] == km && si_s[w2] > im)) { km = sk_s[w2]; im = si_s[w2]; pm = sp_s[w2]; }
    }
    int p80 = pm;  // position of rank-80
    __syncthreads();
    if (tid == 0) {
        // move rank-81 entry to slot 80, rank-80 entry to slot 79
        int ts; float tv;
        ts = sel[80]; sel[80] = sel[p81]; sel[p81] = ts;
        tv = selv[80]; selv[80] = selv[p81]; selv[p81] = tv;
        if (p80 == 80) p80 = p81;
        ts = sel[79]; sel[79] = sel[p80]; sel[p80] = ts;
        tv = selv[79]; selv[79] = selv[p80]; selv[p80] = tv;
        float d80f = selv[79], d81f = selv[80];
        float eta = 8e-5f + 4e-6f * fabsf(d80f);
        flags[b * NPTS + row] = ((d80f - d81f) <= eta) ? 1 : 0;
    }
    __syncthreads();
    int* outp = idxout + ((long)b * NPTS + row) * KSEL;
    for (int t = tid; t < KSEL; t += 256) outp[t] = sel[t];
}

// ---------------- p/r projections: h[o,n,k] = p[o,j] + r[o,n] ----------------
template<int C, int O>
__global__ __launch_bounds__(256) void pr_kernel(
    const float* __restrict__ x, long sb, const float* __restrict__ W,
    float* __restrict__ p, float* __restrict__ r) {
    __shared__ float wp[C * O];
    __shared__ float wr[C * O];
    __shared__ float xs[C][32];
    int nb = NPTS / 32;
    int b = blockIdx.x / nb;
    int n0 = (blockIdx.x % nb) * 32;
    int tid = threadIdx.x;
    for (int t = tid; t < C * O; t += 256) {
        int o = t / C, c = t % C;
        float w1 = W[o * 2 * C + c];
        wp[o * C + c] = w1;
        wr[o * C + c] = W[o * 2 * C + C + c] - w1;
    }
    const float* xb = x + (long)b * sb;
    for (int t = tid; t < C * 32; t += 256) {
        int c = t / 32, nn = t & 31;
        xs[c][nn] = xb[(long)c * NPTS + n0 + nn];
    }
    __syncthreads();
    int o = tid % O;
    int nl0 = tid / O, per = 256 / O;
    for (int nl = nl0; nl < 32; nl += per) {
        float pa = 0.f, ra = 0.f;
        for (int c = 0; c < C; ++c) {
            float xv = xs[c][nl];
            pa = fmaf(wp[o * C + c], xv, pa);
            ra = fmaf(wr[o * C + c], xv, ra);
        }
        long po = ((long)b * NPTS + n0 + nl) * O + o;
        p[po] = pa;
        r[po] = ra;
    }
}

// ---------------- group stats (fp64, race-free per-halfwave slots) ----------------
template<int O>
__global__ __launch_bounds__(256) void stats_kernel(
    const float* __restrict__ p, const float* __restrict__ r,
    const int* __restrict__ idx, double* __restrict__ partials) {
    const int NT = 16;
    __shared__ float r_s[NT * O];
    __shared__ int idx_s[NT * KNN];
    __shared__ double gs8[8], gq8[8];
    int nb = NPTS / NT;
    int b = blockIdx.x / nb;
    int n0 = (blockIdx.x % nb) * NT;
    int tid = threadIdx.x;
    for (int t = tid; t < NT * O; t += 256) r_s[t] = r[((long)b * NPTS + n0) * O + t];
    for (int t = tid; t < NT * KNN; t += 256) {
        int nl = t / KNN, k = t % KNN;
        idx_s[t] = idx[((long)b * NPTS + n0 + nl) * KSEL + k];
    }
    __syncthreads();
    int o = tid % O;
    int rep = tid / O, nrep = 256 / O;
    const float* pb = p + (long)b * NPTS * O;
    double s = 0.0, q = 0.0;
    for (int nl = 0; nl < NT; ++nl) {
        double rv = (double)r_s[nl * O + o];
        for (int kk = rep; kk < KNN; kk += nrep) {
            int j = idx_s[nl * KNN + kk];
            double h = (double)pb[(long)j * O + o] + rv;
            s += h;
            q = fma(h, h, q);
        }
    }
    for (int off = 16; off > 0; off >>= 1) {
        s += __shfl_xor(s, off);
        q += __shfl_xor(q, off);
    }
    int hw = tid >> 5;
    if ((tid & 31) == 0) { gs8[hw] = s; gq8[hw] = q; }
    __syncthreads();
    if (tid < 2) {
        double ss = 0.0, qq = 0.0;
        for (int h2 = 0; h2 < 8; ++h2) {
            int o0 = (h2 * 32) % O;
            int g = o0 / (O / 2);
            if (g == tid) { ss += gs8[h2]; qq += gq8[h2]; }
        }
        partials[(long)blockIdx.x * 4 + tid * 2 + 0] = ss;
        partials[(long)blockIdx.x * 4 + tid * 2 + 1] = qq;
    }
}

__global__ void reduce_stats(const double* __restrict__ partials, int nblkb, double M,
                             float* __restrict__ ms) {
    int i = threadIdx.x;
    if (i >= BATCH * 2) return;
    int b = i >> 1, g = i & 1;
    double s = 0.0, q = 0.0;
    for (int t = 0; t < nblkb; ++t) {
        long blk = (long)b * nblkb + t;
        s += partials[blk * 4 + g * 2 + 0];
        q += partials[blk * 4 + g * 2 + 1];
    }
    double mean = s / M;
    double var = q / M - mean * mean;
    ms[i * 2 + 0] = (float)mean;
    ms[i * 2 + 1] = (float)(1.0 / sqrt(var + 1e-5));
}

// ---------------- normalize + leaky + max over k, with boundary hedging ----------------
template<int O>
__global__ __launch_bounds__(256) void outk_kernel(
    const float* __restrict__ p, const float* __restrict__ r,
    const int* __restrict__ idx, const int* __restrict__ flags,
    const float* __restrict__ ms, const float* __restrict__ gamma, const float* __restrict__ beta,
    float* __restrict__ featP, float* __restrict__ featH, int coff) {
    const int NT = 16;
    __shared__ float r_s[NT * O];
    __shared__ int idx_s[NT * KSEL];
    __shared__ int flag_s[NT];
    __shared__ float sc_s[O], sh_s[O];
    int nb = NPTS / NT;
    int b = blockIdx.x / nb;
    int n0 = (blockIdx.x % nb) * NT;
    int tid = threadIdx.x;
    for (int t = tid; t < NT * O; t += 256) r_s[t] = r[((long)b * NPTS + n0) * O + t];
    for (int t = tid; t < NT * KSEL; t += 256) {
        int nl = t / KSEL, k = t % KSEL;
        idx_s[t] = idx[((long)b * NPTS + n0 + nl) * KSEL + k];
    }
    if (tid < NT) flag_s[tid] = flags[b * NPTS + n0 + tid];
    if (tid < O) {
        int g = tid / (O / 2);
        float mean = ms[(b * 2 + g) * 2 + 0], rstd = ms[(b * 2 + g) * 2 + 1];
        float sc = rstd * gamma[tid];
        sc_s[tid] = sc;
        sh_s[tid] = beta[tid] - mean * sc;
    }
    __syncthreads();
    int o = tid % O;
    int nl0 = tid / O, nrep = 256 / O;
    const float* pb = p + (long)b * NPTS * O;
    float sc = sc_s[o], sh = sh_s[o];
    bool pos = (sc >= 0.f);
    for (int nl = nl0; nl < NT; nl += nrep) {
        float rv = r_s[nl * O + o];
        float hi = -3.0e38f, lo = 3.0e38f;
        for (int kk = 0; kk < KNN - 1; ++kk) {
            int j = idx_s[nl * KSEL + kk];
            float h = pb[(long)j * O + o] + rv;
            hi = fmaxf(hi, h);
            lo = fminf(lo, h);
        }
        float ha = pb[(long)idx_s[nl * KSEL + KNN - 1] * O + o] + rv;  // 80th (primary)
        float hb = pb[(long)idx_s[nl * KSEL + KNN] * O + o] + rv;      // 81st (alternate)
        float h0 = pos ? fmaxf(hi, ha) : fminf(lo, ha);
        float h1 = pos ? fmaxf(hi, hb) : fminf(lo, hb);
        float v0 = h0 * sc + sh; v0 = v0 >= 0.f ? v0 : 0.2f * v0;
        float v1 = h1 * sc + sh; v1 = v1 >= 0.f ? v1 : 0.2f * v1;
        float outv = v0;
        if (flag_s[nl] && fabsf(v0 - v1) <= 0.45f) outv = 0.5f * (v0 + v1);
        long oidx = ((long)b * 256 + coff + o) * NPTS + (n0 + nl);
        featP[oidx] = v0;
        featH[oidx] = outv;
    }
}

// ---------------- MLP head ----------------
__global__ __launch_bounds__(256) void mlp_gemm_kernel(
    const float* __restrict__ xf, const float* __restrict__ Wm, const float* __restrict__ bm,
    float* __restrict__ h, double* __restrict__ stats) {
    int b = blockIdx.z;
    int o0 = blockIdx.y * 64, n0 = blockIdx.x * 64;
    __shared__ float wm_s[64][65];
    __shared__ float xf_s[64][64];
    int tid = threadIdx.x;
    int tx = tid & 15, ty = tid >> 4;
    float acc[4][4] = {};
    for (int kc = 0; kc < 256; kc += 64) {
        for (int i = tid; i < 64 * 64; i += 256) {
            int row = i >> 6, col = i & 63;
            wm_s[row][col] = Wm[(long)(o0 + row) * 256 + kc + col];
            xf_s[row][col] = xf[(long)b * 256 * NPTS + (long)(kc + row) * NPTS + n0 + col];
        }
        __syncthreads();
        for (int c = 0; c < 64; ++c) {
            float a[4], bb[4];
#pragma unroll
            for (int u = 0; u < 4; ++u) a[u] = wm_s[ty * 4 + u][c];
#pragma unroll
            for (int v = 0; v < 4; ++v) bb[v] = xf_s[c][tx * 4 + v];
#pragma unroll
            for (int u = 0; u < 4; ++u)
#pragma unroll
                for (int v = 0; v < 4; ++v) acc[u][v] = fmaf(a[u], bb[v], acc[u][v]);
        }
        __syncthreads();
    }
    double s = 0.0, q = 0.0;
#pragma unroll
    for (int u = 0; u < 4; ++u) {
        int o = o0 + ty * 4 + u;
        float bv = bm[o];
#pragma unroll
        for (int v = 0; v < 4; ++v) {
            float hv = acc[u][v] + bv;
            h[((long)b * 1024 + o) * NPTS + n0 + tx * 4 + v] = hv;
            s += (double)hv;
            q += (double)hv * (double)hv;
        }
    }
    for (int off = 32; off > 0; off >>= 1) {
        s += __shfl_xor(s, off);
        q += __shfl_xor(q, off);
    }
    __shared__ double rs[4], rq[4];
    int wid = tid >> 6;
    if ((tid & 63) == 0) { rs[wid] = s; rq[wid] = q; }
    __syncthreads();
    if (tid == 0) {
        s = rs[0] + rs[1] + rs[2] + rs[3];
        q = rq[0] + rq[1] + rq[2] + rq[3];
        int g = o0 / 128;
        atomicAdd(&stats[(b * 8 + g) * 2 + 0], s);
        atomicAdd(&stats[(b * 8 + g) * 2 + 1], q);
    }
}

__global__ void finalize64_kernel(const double* __restrict__ st, double* __restrict__ msout,
                                  int G, double M) {
    int i = threadIdx.x;
    if (i >= BATCH * G) return;
    double s = st[i * 2], q = st[i * 2 + 1];
    double mean = s / M;
    double var = q / M - mean * mean;
    msout[i * 2] = mean;
    msout[i * 2 + 1] = 1.0 / sqrt(var + 1e-5);
}

__global__ void mlp_pool_kernel(
    const float* __restrict__ h, const double* __restrict__ ms,
    const float* __restrict__ gm, const float* __restrict__ betam, float* __restrict__ x4) {
    int b = blockIdx.x / 1024, o = blockIdx.x % 1024;
    int g = o / 128;
    float mean = (float)ms[(b * 8 + g) * 2], rstd = (float)ms[(b * 8 + g) * 2 + 1];
    float sc = rstd * gm[o], sh = betam[o] - mean * sc;
    const float* hr = h + ((long)b * 1024 + o) * NPTS;
    int tid = threadIdx.x;
    float m = -3.0e38f;
    for (int i = tid; i < NPTS; i += 256) {
        float v = hr[i] * sc + sh;
        v = fmaxf(v, 0.f);
        m = fmaxf(m, v);
    }
    for (int off = 32; off > 0; off >>= 1) m = fmaxf(m, __shfl_xor(m, off));
    __shared__ float red[4];
    if ((tid & 63) == 0) red[tid >> 6] = m;
    __syncthreads();
    if (tid == 0) x4[blockIdx.x] = fmaxf(fmaxf(red[0], red[1]), fmaxf(red[2], red[3]));
}

template<int C, int O>
static void run_layer(const float* xin, long sb, const float* W,
                      const float* gamma, const float* beta, int coff,
                      float* featP, float* featH,
                      double* xxb, float* dist, int* idx, int* flags,
                      float* pbuf, float* rbuf, double* partials, float* msf,
                      hipStream_t stream) {
    xx64_kernel<<<(BATCH * NPTS + 255) / 256, 256, 0, stream>>>(xin, sb, C, xxb);
    for (int b = 0; b < BATCH; ++b) {
        dist_kernel<<<dim3(32, 32), 256, 0, stream>>>(xin, sb, C, xxb, dist, b);
        topk_radix_kernel<<<NPTS, 256, 0, stream>>>(dist, idx, flags, b);
    }
    pr_kernel<C, O><<<BATCH * NPTS / 32, 256, 0, stream>>>(xin, sb, W, pbuf, rbuf);
    stats_kernel<O><<<BATCH * NPTS / 16, 256, 0, stream>>>(pbuf, rbuf, idx, partials);
    double M = (double)((long)(O / 2) * NPTS * KNN);
    reduce_stats<<<1, 64, 0, stream>>>(partials, NPTS / 16, M, msf);
    outk_kernel<O><<<BATCH * NPTS / 16, 256, 0, stream>>>(pbuf, rbuf, idx, flags, msf,
                                                          gamma, beta, featP, featH, coff);
}

extern "C" void kernel_launch(void* const* d_in, const int* in_sizes, int n_in,
                              void* d_out, int out_size, void* d_ws, size_t ws_size,
                              hipStream_t stream) {
    const float* x = (const float*)d_in[0];
    const float* W1 = (const float*)d_in[1];
    const float* g1 = (const float*)d_in[2];
    const float* b1 = (const float*)d_in[3];
    const float* W2 = (const float*)d_in[4];
    const float* g2 = (const float*)d_in[5];
    const float* b2 = (const float*)d_in[6];
    const float* W3 = (const float*)d_in[7];
    const float* g3 = (const float*)d_in[8];
    const float* b3 = (const float*)d_in[9];
    const float* Wm = (const float*)d_in[10];
    const float* bm = (const float*)d_in[11];
    const float* gm = (const float*)d_in[12];
    const float* betam = (const float*)d_in[13];

    float* out = (float*)d_out;
    float* x4 = out;
    float* featH = out + BATCH * 1024;

    char* ws = (char*)d_ws;
    size_t off = 0;
    auto alloc = [&](size_t bytes) -> void* {
        void* pp = ws + off;
        off += (bytes + 255) & ~(size_t)255;
        return pp;
    };
    double* xxb = (double*)alloc((size_t)BATCH * NPTS * 8);
    int* idx = (int*)alloc((size_t)BATCH * NPTS * KSEL * 4);
    int* flags = (int*)alloc((size_t)BATCH * NPTS * 4);
    float* featP = (float*)alloc((size_t)BATCH * 256 * NPTS * 4);
    float* pbuf = (float*)alloc((size_t)BATCH * NPTS * 128 * 4);
    float* rbuf = (float*)alloc((size_t)BATCH * NPTS * 128 * 4);
    double* partials = (double*)alloc((size_t)(BATCH * NPTS / 16) * 4 * 8);
    float* msf = (float*)alloc(64 * 4);
    double* statsd = (double*)alloc(128 * 8);
    double* msd = (double*)alloc(128 * 8);
    float* hmlp = (float*)alloc((size_t)BATCH * 1024 * NPTS * 4);
    float* dist = hmlp;  // per-batch dist (16.8 MB) aliases hmlp (used later)

    hipMemsetAsync(statsd, 0, 128 * 8, stream);

    run_layer<3, 64>(x, 3L * NPTS, W1, g1, b1, 0,
                     featP, featH, xxb, dist, idx, flags, pbuf, rbuf, partials, msf, stream);
    run_layer<64, 64>(featP, 256L * NPTS, W2, g2, b2, 64,
                      featP, featH, xxb, dist, idx, flags, pbuf, rbuf, partials, msf, stream);
    run_layer<64, 128>(featP + 64L * NPTS, 256L * NPTS, W3, g3, b3, 128,
                       featP, featH, xxb, dist, idx, flags, pbuf, rbuf, partials, msf, stream);

    mlp_gemm_kernel<<<dim3(32, 16, BATCH), 256, 0, stream>>>(featH, Wm, bm, hmlp, statsd);
    finalize64_kernel<<<1, 64, 0, stream>>>(statsd, msd, 8, (double)(128L * NPTS));
    mlp_pool_kernel<<<BATCH * 1024, 256, 0, stream>>>(hmlp, msd, gm, betam, x4);
    (void)in_sizes; (void)n_in; (void)out_size; (void)ws_size;
}

// Round 8
// 906.122 us; speedup vs baseline: 2.9604x; 1.2506x over previous
//
#include <hip/hip_runtime.h>
#include <hip/hip_bf16.h>

#define NPTS 2048
#define KNN 80
#define KSEL 81
#define BATCH 4

// ---------------- xx (fp64) ----------------
__global__ void xx64_kernel(const float* __restrict__ x, long sb, int C, double* __restrict__ xx) {
    int i = blockIdx.x * 256 + threadIdx.x;
    if (i >= BATCH * NPTS) return;
    int b = i / NPTS, n = i % NPTS;
    const float* xp = x + (long)b * sb + n;
    double s = 0.0;
    for (int c = 0; c < C; ++c) { double v = (double)xp[(long)c * NPTS]; s = fma(v, v, s); }
    xx[i] = s;
}

// ---------------- canonical dist: fp64 accumulate -> fp32 round ----------------
__global__ __launch_bounds__(256) void dist_kernel(
    const float* __restrict__ x, long sb, int C,
    const double* __restrict__ xx, float* __restrict__ dist, int b) {
    int i0 = blockIdx.y * 64, j0 = blockIdx.x * 64;
    __shared__ float xi[32][64];
    __shared__ float xj[32][64];
    const float* xb = x + (long)b * sb;
    int tid = threadIdx.x, tx = tid & 15, ty = tid >> 4;
    double acc[4][4] = {};
    for (int cc = 0; cc < C; cc += 32) {
        int Cc = C - cc; if (Cc > 32) Cc = 32;
        for (int t = tid; t < Cc * 64; t += 256) {
            int c = t >> 6, l = t & 63;
            xi[c][l] = xb[(long)(cc + c) * NPTS + i0 + l];
            xj[c][l] = xb[(long)(cc + c) * NPTS + j0 + l];
        }
        __syncthreads();
        for (int c = 0; c < Cc; ++c) {
            double a[4], bb[4];
#pragma unroll
            for (int u = 0; u < 4; ++u) a[u] = (double)xi[c][ty * 4 + u];
#pragma unroll
            for (int v = 0; v < 4; ++v) bb[v] = (double)xj[c][tx * 4 + v];
#pragma unroll
            for (int u = 0; u < 4; ++u)
#pragma unroll
                for (int v = 0; v < 4; ++v) acc[u][v] = fma(a[u], bb[v], acc[u][v]);
        }
        __syncthreads();
    }
    const double* xxb = xx + b * NPTS;
#pragma unroll
    for (int u = 0; u < 4; ++u) {
        int i = i0 + ty * 4 + u;
        double xxi = xxb[i];
#pragma unroll
        for (int v = 0; v < 4; ++v) {
            int j = j0 + tx * 4 + v;
            dist[(long)i * NPTS + j] = (float)(2.0 * acc[u][v] - xxi - xxb[j]);
        }
    }
}

// ---------------- radix-select top-81 per row + boundary near-tie flag ----------------
__device__ __forceinline__ unsigned f2key(float f) {
    unsigned u = __float_as_uint(f);
    return u ^ ((u & 0x80000000u) ? 0xFFFFFFFFu : 0x80000000u);
}
__device__ __forceinline__ float key2f(unsigned k) {
    unsigned u = (k & 0x80000000u) ? (k ^ 0x80000000u) : ~k;
    return __uint_as_float(u);
}

__global__ __launch_bounds__(256) void topk_radix_kernel(
    const float* __restrict__ dist, int* __restrict__ idxout,
    int* __restrict__ flags, int b) {
    int row = blockIdx.x;
    const float* dr = dist + (long)row * NPTS;
    int tid = threadIdx.x;
    int lane = tid & 63, wv = tid >> 6;
    int base = tid * 8;
    float fv[8];
    unsigned kv[8];
    {
        float4 a0 = *(const float4*)(dr + base);
        float4 a1 = *(const float4*)(dr + base + 4);
        fv[0] = a0.x; fv[1] = a0.y; fv[2] = a0.z; fv[3] = a0.w;
        fv[4] = a1.x; fv[5] = a1.y; fv[6] = a1.z; fv[7] = a1.w;
    }
#pragma unroll
    for (int u = 0; u < 8; ++u) kv[u] = f2key(fv[u]);

    __shared__ unsigned hist[256];
    __shared__ unsigned scan_s[256];
    __shared__ unsigned wtot[4];
    __shared__ unsigned sh_prefix;
    __shared__ int sh_remaining;
    unsigned prefix = 0;
    int remaining = KSEL;

    for (int pass = 0; pass < 4; ++pass) {
        int shift = 24 - pass * 8;
        hist[tid] = 0;
        __syncthreads();
        if (pass == 0) {
#pragma unroll
            for (int u = 0; u < 8; ++u) atomicAdd(&hist[kv[u] >> 24], 1u);
        } else {
            unsigned pmask = 0xFFFFFFFFu << (shift + 8);
#pragma unroll
            for (int u = 0; u < 8; ++u)
                if ((kv[u] & pmask) == prefix) atomicAdd(&hist[(kv[u] >> shift) & 255u], 1u);
        }
        __syncthreads();
        unsigned s = hist[tid];
#pragma unroll
        for (int d = 1; d < 64; d <<= 1) {
            unsigned o = __shfl_down(s, d);
            s += (lane + d < 64) ? o : 0u;
        }
        if (lane == 0) wtot[wv] = s;
        __syncthreads();
        unsigned offs = 0;
        for (int w2 = wv + 1; w2 < 4; ++w2) offs += wtot[w2];
        s += offs;
        scan_s[tid] = s;
        __syncthreads();
        unsigned nxt = (tid == 255) ? 0u : scan_s[tid + 1];
        if (s >= (unsigned)remaining && nxt < (unsigned)remaining) {
            sh_prefix = prefix | ((unsigned)tid << shift);
            sh_remaining = remaining - (int)nxt;
        }
        __syncthreads();
        prefix = sh_prefix;
        remaining = sh_remaining;
        __syncthreads();
    }

    __shared__ int cnt;
    __shared__ int sel[KSEL];
    __shared__ float selv[KSEL];
    if (tid == 0) cnt = 0;
    __syncthreads();
#pragma unroll
    for (int u = 0; u < 8; ++u) {
        if (kv[u] > prefix) {
            int pos = atomicAdd(&cnt, 1);
            sel[pos] = base + u;
            selv[pos] = fv[u];
        }
    }
    __syncthreads();
    int cgt = cnt;
    unsigned tmask = 0;
#pragma unroll
    for (int u = 0; u < 8; ++u)
        if (kv[u] == prefix) tmask |= (1u << u);
    __shared__ int swi[4];
    float vtie = key2f(prefix);
    for (int t = 0; t < remaining; ++t) {
        int best = 0x7FFFFFFF;
#pragma unroll
        for (int u = 0; u < 8; ++u)
            if (tmask & (1u << u)) best = min(best, base + u);
        for (int off2 = 32; off2 > 0; off2 >>= 1)
            best = min(best, __shfl_xor(best, off2));
        if (lane == 0) swi[wv] = best;
        __syncthreads();
        best = min(min(swi[0], swi[1]), min(swi[2], swi[3]));
        if (best >= base && best < base + 8) tmask &= ~(1u << (best - base));
        if (tid == 0) { sel[cgt + t] = best; selv[cgt + t] = vtie; }
        __syncthreads();
    }

    __shared__ unsigned sk_s[4]; __shared__ int si_s[4], sp_s[4];
    unsigned k1 = 0xFFFFFFFFu; int id1 = -1, p1 = tid;
    if (tid < KSEL) { k1 = f2key(selv[tid]); id1 = sel[tid]; }
#pragma unroll
    for (int off2 = 32; off2 > 0; off2 >>= 1) {
        unsigned ok = __shfl_xor(k1, off2);
        int oid = __shfl_xor(id1, off2);
        int op = __shfl_xor(p1, off2);
        if (ok < k1 || (ok == k1 && oid > id1)) { k1 = ok; id1 = oid; p1 = op; }
    }
    if (lane == 0) { sk_s[wv] = k1; si_s[wv] = id1; sp_s[wv] = p1; }
    __syncthreads();
    unsigned km = sk_s[0]; int im = si_s[0], pm = sp_s[0];
    for (int w2 = 1; w2 < 4; ++w2) {
        if (sk_s[w2] < km || (sk_s[w2] == km && si_s[w2] > im)) { km = sk_s[w2]; im = si_s[w2]; pm = sp_s[w2]; }
    }
    int p81 = pm;
    __syncthreads();
    k1 = 0xFFFFFFFFu; id1 = -1; p1 = tid;
    if (tid < KSEL && tid != p81) { k1 = f2key(selv[tid]); id1 = sel[tid]; }
#pragma unroll
    for (int off2 = 32; off2 > 0; off2 >>= 1) {
        unsigned ok = __shfl_xor(k1, off2);
        int oid = __shfl_xor(id1, off2);
        int op = __shfl_xor(p1, off2);
        if (ok < k1 || (ok == k1 && oid > id1)) { k1 = ok; id1 = oid; p1 = op; }
    }
    if (lane == 0) { sk_s[wv] = k1; si_s[wv] = id1; sp_s[wv] = p1; }
    __syncthreads();
    km = sk_s[0]; im = si_s[0]; pm = sp_s[0];
    for (int w2 = 1; w2 < 4; ++w2) {
        if (sk_s[w2] < km || (sk_s[w2] == km && si_s[w2] > im)) { km = sk_s[w2]; im = si_s[w2]; pm = sp_s[w2]; }
    }
    int p80 = pm;
    __syncthreads();
    if (tid == 0) {
        int ts; float tv;
        ts = sel[80]; sel[80] = sel[p81]; sel[p81] = ts;
        tv = selv[80]; selv[80] = selv[p81]; selv[p81] = tv;
        if (p80 == 80) p80 = p81;
        ts = sel[79]; sel[79] = sel[p80]; sel[p80] = ts;
        tv = selv[79]; selv[79] = selv[p80]; selv[p80] = tv;
        float d80f = selv[79], d81f = selv[80];
        float eta = 8e-5f + 4e-6f * fabsf(d80f);
        flags[b * NPTS + row] = ((d80f - d81f) <= eta) ? 1 : 0;
    }
    __syncthreads();
    int* outp = idxout + ((long)b * NPTS + row) * KSEL;
    for (int t = tid; t < KSEL; t += 256) outp[t] = sel[t];
}

// ---------------- p/r projections ----------------
template<int C, int O>
__global__ __launch_bounds__(256) void pr_kernel(
    const float* __restrict__ x, long sb, const float* __restrict__ W,
    float* __restrict__ p, float* __restrict__ r) {
    __shared__ float wp[C * O];
    __shared__ float wr[C * O];
    __shared__ float xs[C][32];
    int nb = NPTS / 32;
    int b = blockIdx.x / nb;
    int n0 = (blockIdx.x % nb) * 32;
    int tid = threadIdx.x;
    for (int t = tid; t < C * O; t += 256) {
        int o = t / C, c = t % C;
        float w1 = W[o * 2 * C + c];
        wp[o * C + c] = w1;
        wr[o * C + c] = W[o * 2 * C + C + c] - w1;
    }
    const float* xb = x + (long)b * sb;
    for (int t = tid; t < C * 32; t += 256) {
        int c = t / 32, nn = t & 31;
        xs[c][nn] = xb[(long)c * NPTS + n0 + nn];
    }
    __syncthreads();
    int o = tid % O;
    int nl0 = tid / O, per = 256 / O;
    for (int nl = nl0; nl < 32; nl += per) {
        float pa = 0.f, ra = 0.f;
        for (int c = 0; c < C; ++c) {
            float xv = xs[c][nl];
            pa = fmaf(wp[o * C + c], xv, pa);
            ra = fmaf(wr[o * C + c], xv, ra);
        }
        long po = ((long)b * NPTS + n0 + nl) * O + o;
        p[po] = pa;
        r[po] = ra;
    }
}

// ---------------- FUSED gather: per-(n,o) {hi,lo,h80,h81} + fp64 stats partials ----------------
// NT=8 rows/block, R = NT*O/256 rows/thread, row-unrolled gathers for MLP.
template<int O>
__global__ __launch_bounds__(256) void gather_kernel(
    const float* __restrict__ p, const float* __restrict__ r,
    const int* __restrict__ idx, float4* __restrict__ hilo,
    double* __restrict__ partials) {
    const int NT = 8;
    const int R = (NT * O) / 256;
    const int STEP = 256 / O;
    __shared__ float r_s[NT * O];
    __shared__ int idx_s[NT * KSEL];
    __shared__ double gs8[8], gq8[8];
    int nb = NPTS / NT;
    int b = blockIdx.x / nb;
    int n0 = (blockIdx.x % nb) * NT;
    int tid = threadIdx.x;
    for (int t = tid; t < NT * O; t += 256) r_s[t] = r[((long)b * NPTS + n0) * O + t];
    for (int t = tid; t < NT * KSEL; t += 256) idx_s[t] = idx[((long)b * NPTS + n0) * KSEL + t];
    __syncthreads();
    int o = tid % O;
    int nlb = tid / O;
    const float* pb = p + (long)b * NPTS * O;
    float hi[R], lo[R], ha[R], hb[R], rv[R];
    int nlr[R];
#pragma unroll
    for (int u = 0; u < R; ++u) {
        nlr[u] = nlb + u * STEP;
        rv[u] = r_s[nlr[u] * O + o];
        hi[u] = -3.0e38f; lo[u] = 3.0e38f;
    }
    double s = 0.0, q = 0.0;
    for (int kk = 0; kk < KNN - 1; ++kk) {
#pragma unroll
        for (int u = 0; u < R; ++u) {
            int j = idx_s[nlr[u] * KSEL + kk];
            float h = pb[(long)j * O + o] + rv[u];
            hi[u] = fmaxf(hi[u], h);
            lo[u] = fminf(lo[u], h);
            s += (double)h;
            q = fma((double)h, (double)h, q);
        }
    }
#pragma unroll
    for (int u = 0; u < R; ++u) {
        int j = idx_s[nlr[u] * KSEL + (KNN - 1)];
        ha[u] = pb[(long)j * O + o] + rv[u];
        s += (double)ha[u];
        q = fma((double)ha[u], (double)ha[u], q);
        int j2 = idx_s[nlr[u] * KSEL + KNN];
        hb[u] = pb[(long)j2 * O + o] + rv[u];
    }
#pragma unroll
    for (int u = 0; u < R; ++u)
        hilo[((long)b * NPTS + n0 + nlr[u]) * O + o] = make_float4(hi[u], lo[u], ha[u], hb[u]);
    // stats reduce: half-wave uniform group
    for (int off = 16; off > 0; off >>= 1) {
        s += __shfl_xor(s, off);
        q += __shfl_xor(q, off);
    }
    int hw = tid >> 5;
    if ((tid & 31) == 0) { gs8[hw] = s; gq8[hw] = q; }
    __syncthreads();
    if (tid < 2) {
        double ss = 0.0, qq = 0.0;
        for (int h2 = 0; h2 < 8; ++h2) {
            int o0 = (h2 * 32) % O;
            int g = o0 / (O / 2);
            if (g == tid) { ss += gs8[h2]; qq += gq8[h2]; }
        }
        partials[(long)blockIdx.x * 4 + tid * 2 + 0] = ss;
        partials[(long)blockIdx.x * 4 + tid * 2 + 1] = qq;
    }
}

__global__ void reduce_stats(const double* __restrict__ partials, int nblkb, double M,
                             float* __restrict__ ms) {
    int i = threadIdx.x;
    if (i >= BATCH * 2) return;
    int b = i >> 1, g = i & 1;
    double s = 0.0, q = 0.0;
    for (int t = 0; t < nblkb; ++t) {
        long blk = (long)b * nblkb + t;
        s += partials[blk * 4 + g * 2 + 0];
        q += partials[blk * 4 + g * 2 + 1];
    }
    double mean = s / M;
    double var = q / M - mean * mean;
    ms[i * 2 + 0] = (float)mean;
    ms[i * 2 + 1] = (float)(1.0 / sqrt(var + 1e-5));
}

// ---------------- finalize: normalize extremes + leaky + hedge -> feat (LDS transpose) ----------------
template<int O>
__global__ __launch_bounds__(256) void finalize_kernel(
    const float4* __restrict__ hilo, const int* __restrict__ flags,
    const float* __restrict__ ms, const float* __restrict__ gamma, const float* __restrict__ beta,
    float* __restrict__ featP, float* __restrict__ featH, int coff) {
    const int NT = 16;
    __shared__ float smP[O * NT], smH[O * NT];
    __shared__ float sc_s[O], sh_s[O];
    __shared__ int flag_s[NT];
    int nb = NPTS / NT;
    int b = blockIdx.x / nb;
    int n0 = (blockIdx.x % nb) * NT;
    int tid = threadIdx.x;
    if (tid < NT) flag_s[tid] = flags[b * NPTS + n0 + tid];
    if (tid < O) {
        int g = tid / (O / 2);
        float mean = ms[(b * 2 + g) * 2 + 0], rstd = ms[(b * 2 + g) * 2 + 1];
        float sc = rstd * gamma[tid];
        sc_s[tid] = sc;
        sh_s[tid] = beta[tid] - mean * sc;
    }
    __syncthreads();
    int o = tid % O;
    int nl0 = tid / O, nrep = 256 / O;
    float sc = sc_s[o], sh = sh_s[o];
    bool pos = (sc >= 0.f);
    for (int nl = nl0; nl < NT; nl += nrep) {
        float4 v = hilo[((long)b * NPTS + n0 + nl) * O + o];
        float h0 = pos ? fmaxf(v.x, v.z) : fminf(v.y, v.z);
        float h1 = pos ? fmaxf(v.x, v.w) : fminf(v.y, v.w);
        float v0 = h0 * sc + sh; v0 = v0 >= 0.f ? v0 : 0.2f * v0;
        float v1 = h1 * sc + sh; v1 = v1 >= 0.f ? v1 : 0.2f * v1;
        float outv = v0;
        if (flag_s[nl] && fabsf(v0 - v1) <= 0.45f) outv = 0.5f * (v0 + v1);
        smP[o * NT + nl] = v0;
        smH[o * NT + nl] = outv;
    }
    __syncthreads();
    long obase = ((long)b * 256 + coff) * NPTS + n0;
    for (int i = tid; i < O * NT; i += 256) {
        int oo = i / NT, nl = i % NT;
        featP[obase + (long)oo * NPTS + nl] = smP[i];
        featH[obase + (long)oo * NPTS + nl] = smH[i];
    }
}

// ---------------- MLP head ----------------
__global__ __launch_bounds__(256) void mlp_gemm_kernel(
    const float* __restrict__ xf, const float* __restrict__ Wm, const float* __restrict__ bm,
    float* __restrict__ h, double* __restrict__ stats) {
    int b = blockIdx.z;
    int o0 = blockIdx.y * 64, n0 = blockIdx.x * 64;
    __shared__ float wm_s[64][65];
    __shared__ float xf_s[64][64];
    int tid = threadIdx.x;
    int tx = tid & 15, ty = tid >> 4;
    float acc[4][4] = {};
    for (int kc = 0; kc < 256; kc += 64) {
        for (int i = tid; i < 64 * 64; i += 256) {
            int row = i >> 6, col = i & 63;
            wm_s[row][col] = Wm[(long)(o0 + row) * 256 + kc + col];
            xf_s[row][col] = xf[(long)b * 256 * NPTS + (long)(kc + row) * NPTS + n0 + col];
        }
        __syncthreads();
        for (int c = 0; c < 64; ++c) {
            float a[4], bb[4];
#pragma unroll
            for (int u = 0; u < 4; ++u) a[u] = wm_s[ty * 4 + u][c];
#pragma unroll
            for (int v = 0; v < 4; ++v) bb[v] = xf_s[c][tx * 4 + v];
#pragma unroll
            for (int u = 0; u < 4; ++u)
#pragma unroll
                for (int v = 0; v < 4; ++v) acc[u][v] = fmaf(a[u], bb[v], acc[u][v]);
        }
        __syncthreads();
    }
    double s = 0.0, q = 0.0;
#pragma unroll
    for (int u = 0; u < 4; ++u) {
        int o = o0 + ty * 4 + u;
        float bv = bm[o];
#pragma unroll
        for (int v = 0; v < 4; ++v) {
            float hv = acc[u][v] + bv;
            h[((long)b * 1024 + o) * NPTS + n0 + tx * 4 + v] = hv;
            s += (double)hv;
            q += (double)hv * (double)hv;
        }
    }
    for (int off = 32; off > 0; off >>= 1) {
        s += __shfl_xor(s, off);
        q += __shfl_xor(q, off);
    }
    __shared__ double rs[4], rq[4];
    int wid = tid >> 6;
    if ((tid & 63) == 0) { rs[wid] = s; rq[wid] = q; }
    __syncthreads();
    if (tid == 0) {
        s = rs[0] + rs[1] + rs[2] + rs[3];
        q = rq[0] + rq[1] + rq[2] + rq[3];
        int g = o0 / 128;
        atomicAdd(&stats[(b * 8 + g) * 2 + 0], s);
        atomicAdd(&stats[(b * 8 + g) * 2 + 1], q);
    }
}

__global__ void finalize64_kernel(const double* __restrict__ st, double* __restrict__ msout,
                                  int G, double M) {
    int i = threadIdx.x;
    if (i >= BATCH * G) return;
    double s = st[i * 2], q = st[i * 2 + 1];
    double mean = s / M;
    double var = q / M - mean * mean;
    msout[i * 2] = mean;
    msout[i * 2 + 1] = 1.0 / sqrt(var + 1e-5);
}

__global__ void mlp_pool_kernel(
    const float* __restrict__ h, const double* __restrict__ ms,
    const float* __restrict__ gm, const float* __restrict__ betam, float* __restrict__ x4) {
    int b = blockIdx.x / 1024, o = blockIdx.x % 1024;
    int g = o / 128;
    float mean = (float)ms[(b * 8 + g) * 2], rstd = (float)ms[(b * 8 + g) * 2 + 1];
    float sc = rstd * gm[o], sh = betam[o] - mean * sc;
    const float* hr = h + ((long)b * 1024 + o) * NPTS;
    int tid = threadIdx.x;
    float m = -3.0e38f;
    for (int i = tid; i < NPTS; i += 256) {
        float v = hr[i] * sc + sh;
        v = fmaxf(v, 0.f);
        m = fmaxf(m, v);
    }
    for (int off = 32; off > 0; off >>= 1) m = fmaxf(m, __shfl_xor(m, off));
    __shared__ float red[4];
    if ((tid & 63) == 0) red[tid >> 6] = m;
    __syncthreads();
    if (tid == 0) x4[blockIdx.x] = fmaxf(fmaxf(red[0], red[1]), fmaxf(red[2], red[3]));
}

template<int C, int O>
static void run_layer(const float* xin, long sb, const float* W,
                      const float* gamma, const float* beta, int coff,
                      float* featP, float* featH,
                      double* xxb, float* dist, int* idx, int* flags,
                      float* pbuf, float* rbuf, float4* hilo,
                      double* partials, float* msf, hipStream_t stream) {
    xx64_kernel<<<(BATCH * NPTS + 255) / 256, 256, 0, stream>>>(xin, sb, C, xxb);
    for (int b = 0; b < BATCH; ++b) {
        dist_kernel<<<dim3(32, 32), 256, 0, stream>>>(xin, sb, C, xxb, dist, b);
        topk_radix_kernel<<<NPTS, 256, 0, stream>>>(dist, idx, flags, b);
    }
    pr_kernel<C, O><<<BATCH * NPTS / 32, 256, 0, stream>>>(xin, sb, W, pbuf, rbuf);
    gather_kernel<O><<<BATCH * NPTS / 8, 256, 0, stream>>>(pbuf, rbuf, idx, hilo, partials);
    double M = (double)((long)(O / 2) * NPTS * KNN);
    reduce_stats<<<1, 64, 0, stream>>>(partials, NPTS / 8, M, msf);
    finalize_kernel<O><<<BATCH * NPTS / 16, 256, 0, stream>>>(hilo, flags, msf,
                                                              gamma, beta, featP, featH, coff);
}

extern "C" void kernel_launch(void* const* d_in, const int* in_sizes, int n_in,
                              void* d_out, int out_size, void* d_ws, size_t ws_size,
                              hipStream_t stream) {
    const float* x = (const float*)d_in[0];
    const float* W1 = (const float*)d_in[1];
    const float* g1 = (const float*)d_in[2];
    const float* b1 = (const float*)d_in[3];
    const float* W2 = (const float*)d_in[4];
    const float* g2 = (const float*)d_in[5];
    const float* b2 = (const float*)d_in[6];
    const float* W3 = (const float*)d_in[7];
    const float* g3 = (const float*)d_in[8];
    const float* b3 = (const float*)d_in[9];
    const float* Wm = (const float*)d_in[10];
    const float* bm = (const float*)d_in[11];
    const float* gm = (const float*)d_in[12];
    const float* betam = (const float*)d_in[13];

    float* out = (float*)d_out;
    float* x4 = out;
    float* featH = out + BATCH * 1024;

    char* ws = (char*)d_ws;
    size_t off = 0;
    auto alloc = [&](size_t bytes) -> void* {
        void* pp = ws + off;
        off += (bytes + 255) & ~(size_t)255;
        return pp;
    };
    double* xxb = (double*)alloc((size_t)BATCH * NPTS * 8);
    int* idx = (int*)alloc((size_t)BATCH * NPTS * KSEL * 4);
    int* flags = (int*)alloc((size_t)BATCH * NPTS * 4);
    float* featP = (float*)alloc((size_t)BATCH * 256 * NPTS * 4);
    float* pbuf = (float*)alloc((size_t)BATCH * NPTS * 128 * 4);
    float* rbuf = (float*)alloc((size_t)BATCH * NPTS * 128 * 4);
    float4* hilo = (float4*)alloc((size_t)BATCH * NPTS * 128 * 16);
    double* partials = (double*)alloc((size_t)(BATCH * NPTS / 8) * 4 * 8);
    float* msf = (float*)alloc(64 * 4);
    double* statsd = (double*)alloc(128 * 8);
    double* msd = (double*)alloc(128 * 8);
    float* hmlp = (float*)alloc((size_t)BATCH * 1024 * NPTS * 4);
    float* dist = hmlp;  // per-batch dist (16.8 MB) aliases hmlp (used later)

    hipMemsetAsync(statsd, 0, 128 * 8, stream);

    run_layer<3, 64>(x, 3L * NPTS, W1, g1, b1, 0,
                     featP, featH, xxb, dist, idx, flags, pbuf, rbuf, hilo, partials, msf, stream);
    run_layer<64, 64>(featP, 256L * NPTS, W2, g2, b2, 64,
                      featP, featH, xxb, dist, idx, flags, pbuf, rbuf, hilo, partials, msf, stream);
    run_layer<64, 128>(featP + 64L * NPTS, 256L * NPTS, W3, g3, b3, 128,
                       featP, featH, xxb, dist, idx, flags, pbuf, rbuf, hilo, partials, msf, stream);

    mlp_gemm_kernel<<<dim3(32, 16, BATCH), 256, 0, stream>>>(featH, Wm, bm, hmlp, statsd);
    finalize64_kernel<<<1, 64, 0, stream>>>(statsd, msd, 8, (double)(128L * NPTS));
    mlp_pool_kernel<<<BATCH * 1024, 256, 0, stream>>>(hmlp, msd, gm, betam, x4);
    (void)in_sizes; (void)n_in; (void)out_size; (void)ws_size;
}

// Round 9
// 755.100 us; speedup vs baseline: 3.5525x; 1.2000x over previous
//
#include <hip/hip_runtime.h>
#include <hip/hip_bf16.h>

#define NPTS 2048
#define KNN 80
#define KSEL 81
#define BATCH 4

__device__ __forceinline__ unsigned f2key(float f) {
    unsigned u = __float_as_uint(f);
    return u ^ ((u & 0x80000000u) ? 0xFFFFFFFFu : 0x80000000u);
}
__device__ __forceinline__ float key2f(unsigned k) {
    unsigned u = (k & 0x80000000u) ? (k ^ 0x80000000u) : ~k;
    return __uint_as_float(u);
}

// ---------------- xx (fp64) ----------------
__global__ void xx64_kernel(const float* __restrict__ x, long sb, int C, double* __restrict__ xx) {
    int i = blockIdx.x * 256 + threadIdx.x;
    if (i >= BATCH * NPTS) return;
    int b = i / NPTS, n = i % NPTS;
    const float* xp = x + (long)b * sb + n;
    double s = 0.0;
    for (int c = 0; c < C; ++c) { double v = (double)xp[(long)c * NPTS]; s = fma(v, v, s); }
    xx[i] = s;
}

// ---------------- dist: fp32 accumulate, fp64 final combine -> fp32 ----------------
__global__ __launch_bounds__(256) void dist_kernel(
    const float* __restrict__ x, long sb, int C,
    const double* __restrict__ xx, float* __restrict__ dist, int b_base) {
    int bz = blockIdx.z;
    int b = b_base + bz;
    int i0 = blockIdx.y * 64, j0 = blockIdx.x * 64;
    __shared__ float xi[32][64];
    __shared__ float xj[32][64];
    const float* xb = x + (long)b * sb;
    int tid = threadIdx.x, tx = tid & 15, ty = tid >> 4;
    float acc[4][4] = {};
    for (int cc = 0; cc < C; cc += 32) {
        int Cc = C - cc; if (Cc > 32) Cc = 32;
        for (int t = tid; t < Cc * 64; t += 256) {
            int c = t >> 6, l = t & 63;
            xi[c][l] = xb[(long)(cc + c) * NPTS + i0 + l];
            xj[c][l] = xb[(long)(cc + c) * NPTS + j0 + l];
        }
        __syncthreads();
        for (int c = 0; c < Cc; ++c) {
            float a[4], bb[4];
#pragma unroll
            for (int u = 0; u < 4; ++u) a[u] = xi[c][ty * 4 + u];
#pragma unroll
            for (int v = 0; v < 4; ++v) bb[v] = xj[c][tx * 4 + v];
#pragma unroll
            for (int u = 0; u < 4; ++u)
#pragma unroll
                for (int v = 0; v < 4; ++v) acc[u][v] = fmaf(a[u], bb[v], acc[u][v]);
        }
        __syncthreads();
    }
    const double* xxb = xx + b * NPTS;
    float* drow = dist + (long)bz * NPTS * NPTS;
#pragma unroll
    for (int u = 0; u < 4; ++u) {
        int i = i0 + ty * 4 + u;
        double xxi = xxb[i];
#pragma unroll
        for (int v = 0; v < 4; ++v) {
            int j = j0 + tx * 4 + v;
            drow[(long)i * NPTS + j] = (float)(2.0 * (double)acc[u][v] - xxi - xxb[j]);
        }
    }
}

// ---------------- radix-select top-81 per row + boundary near-tie flag ----------------
__global__ __launch_bounds__(256) void topk_radix_kernel(
    const float* __restrict__ dist, int* __restrict__ idxout,
    int* __restrict__ flags, int b_base) {
    int bz = blockIdx.z;
    int b = b_base + bz;
    int row = blockIdx.x;
    const float* dr = dist + ((long)bz * NPTS + row) * NPTS;
    int tid = threadIdx.x;
    int lane = tid & 63, wv = tid >> 6;
    int base = tid * 8;
    float fv[8];
    unsigned kv[8];
    {
        float4 a0 = *(const float4*)(dr + base);
        float4 a1 = *(const float4*)(dr + base + 4);
        fv[0] = a0.x; fv[1] = a0.y; fv[2] = a0.z; fv[3] = a0.w;
        fv[4] = a1.x; fv[5] = a1.y; fv[6] = a1.z; fv[7] = a1.w;
    }
#pragma unroll
    for (int u = 0; u < 8; ++u) kv[u] = f2key(fv[u]);

    __shared__ unsigned hist[256];
    __shared__ unsigned scan_s[256];
    __shared__ unsigned wtot[4];
    __shared__ unsigned sh_prefix;
    __shared__ int sh_remaining;
    unsigned prefix = 0;
    int remaining = KSEL;

    for (int pass = 0; pass < 4; ++pass) {
        int shift = 24 - pass * 8;
        hist[tid] = 0;
        __syncthreads();
        if (pass == 0) {
#pragma unroll
            for (int u = 0; u < 8; ++u) atomicAdd(&hist[kv[u] >> 24], 1u);
        } else {
            unsigned pmask = 0xFFFFFFFFu << (shift + 8);
#pragma unroll
            for (int u = 0; u < 8; ++u)
                if ((kv[u] & pmask) == prefix) atomicAdd(&hist[(kv[u] >> shift) & 255u], 1u);
        }
        __syncthreads();
        unsigned s = hist[tid];
#pragma unroll
        for (int d = 1; d < 64; d <<= 1) {
            unsigned o = __shfl_down(s, d);
            s += (lane + d < 64) ? o : 0u;
        }
        if (lane == 0) wtot[wv] = s;
        __syncthreads();
        unsigned offs = 0;
        for (int w2 = wv + 1; w2 < 4; ++w2) offs += wtot[w2];
        s += offs;
        scan_s[tid] = s;
        __syncthreads();
        unsigned nxt = (tid == 255) ? 0u : scan_s[tid + 1];
        if (s >= (unsigned)remaining && nxt < (unsigned)remaining) {
            sh_prefix = prefix | ((unsigned)tid << shift);
            sh_remaining = remaining - (int)nxt;
        }
        __syncthreads();
        prefix = sh_prefix;
        remaining = sh_remaining;
        __syncthreads();
    }

    __shared__ int cnt;
    __shared__ int sel[KSEL];
    __shared__ float selv[KSEL];
    if (tid == 0) cnt = 0;
    __syncthreads();
#pragma unroll
    for (int u = 0; u < 8; ++u) {
        if (kv[u] > prefix) {
            int pos = atomicAdd(&cnt, 1);
            sel[pos] = base + u;
            selv[pos] = fv[u];
        }
    }
    __syncthreads();
    int cgt = cnt;
    unsigned tmask = 0;
#pragma unroll
    for (int u = 0; u < 8; ++u)
        if (kv[u] == prefix) tmask |= (1u << u);
    __shared__ int swi[4];
    float vtie = key2f(prefix);
    for (int t = 0; t < remaining; ++t) {
        int best = 0x7FFFFFFF;
#pragma unroll
        for (int u = 0; u < 8; ++u)
            if (tmask & (1u << u)) best = min(best, base + u);
        for (int off2 = 32; off2 > 0; off2 >>= 1)
            best = min(best, __shfl_xor(best, off2));
        if (lane == 0) swi[wv] = best;
        __syncthreads();
        best = min(min(swi[0], swi[1]), min(swi[2], swi[3]));
        if (best >= base && best < base + 8) tmask &= ~(1u << (best - base));
        if (tid == 0) { sel[cgt + t] = best; selv[cgt + t] = vtie; }
        __syncthreads();
    }

    __shared__ unsigned sk_s[4]; __shared__ int si_s[4], sp_s[4];
    unsigned k1 = 0xFFFFFFFFu; int id1 = -1, p1 = tid;
    if (tid < KSEL) { k1 = f2key(selv[tid]); id1 = sel[tid]; }
#pragma unroll
    for (int off2 = 32; off2 > 0; off2 >>= 1) {
        unsigned ok = __shfl_xor(k1, off2);
        int oid = __shfl_xor(id1, off2);
        int op = __shfl_xor(p1, off2);
        if (ok < k1 || (ok == k1 && oid > id1)) { k1 = ok; id1 = oid; p1 = op; }
    }
    if (lane == 0) { sk_s[wv] = k1; si_s[wv] = id1; sp_s[wv] = p1; }
    __syncthreads();
    unsigned km = sk_s[0]; int im = si_s[0], pm = sp_s[0];
    for (int w2 = 1; w2 < 4; ++w2) {
        if (sk_s[w2] < km || (sk_s[w2] == km && si_s[w2] > im)) { km = sk_s[w2]; im = si_s[w2]; pm = sp_s[w2]; }
    }
    int p81 = pm;
    __syncthreads();
    k1 = 0xFFFFFFFFu; id1 = -1; p1 = tid;
    if (tid < KSEL && tid != p81) { k1 = f2key(selv[tid]); id1 = sel[tid]; }
#pragma unroll
    for (int off2 = 32; off2 > 0; off2 >>= 1) {
        unsigned ok = __shfl_xor(k1, off2);
        int oid = __shfl_xor(id1, off2);
        int op = __shfl_xor(p1, off2);
        if (ok < k1 || (ok == k1 && oid > id1)) { k1 = ok; id1 = oid; p1 = op; }
    }
    if (lane == 0) { sk_s[wv] = k1; si_s[wv] = id1; sp_s[wv] = p1; }
    __syncthreads();
    km = sk_s[0]; im = si_s[0]; pm = sp_s[0];
    for (int w2 = 1; w2 < 4; ++w2) {
        if (sk_s[w2] < km || (sk_s[w2] == km && si_s[w2] > im)) { km = sk_s[w2]; im = si_s[w2]; pm = sp_s[w2]; }
    }
    int p80 = pm;
    __syncthreads();
    if (tid == 0) {
        int ts; float tv;
        ts = sel[80]; sel[80] = sel[p81]; sel[p81] = ts;
        tv = selv[80]; selv[80] = selv[p81]; selv[p81] = tv;
        if (p80 == 80) p80 = p81;
        ts = sel[79]; sel[79] = sel[p80]; sel[p80] = ts;
        tv = selv[79]; selv[79] = selv[p80]; selv[p80] = tv;
        float d80f = selv[79], d81f = selv[80];
        float eta = 8e-5f + 4e-6f * fabsf(d80f);
        flags[b * NPTS + row] = ((d80f - d81f) <= eta) ? 1 : 0;
    }
    __syncthreads();
    int* outp = idxout + ((long)b * NPTS + row) * KSEL;
    for (int t = tid; t < KSEL; t += 256) outp[t] = sel[t];
}

// ---------------- p/r projections ----------------
template<int C, int O>
__global__ __launch_bounds__(256) void pr_kernel(
    const float* __restrict__ x, long sb, const float* __restrict__ W,
    float* __restrict__ p, float* __restrict__ r) {
    __shared__ float wp[C * O];
    __shared__ float wr[C * O];
    __shared__ float xs[C][32];
    int nb = NPTS / 32;
    int b = blockIdx.x / nb;
    int n0 = (blockIdx.x % nb) * 32;
    int tid = threadIdx.x;
    for (int t = tid; t < C * O; t += 256) {
        int o = t / C, c = t % C;
        float w1 = W[o * 2 * C + c];
        wp[o * C + c] = w1;
        wr[o * C + c] = W[o * 2 * C + C + c] - w1;
    }
    const float* xb = x + (long)b * sb;
    for (int t = tid; t < C * 32; t += 256) {
        int c = t / 32, nn = t & 31;
        xs[c][nn] = xb[(long)c * NPTS + n0 + nn];
    }
    __syncthreads();
    int o = tid % O;
    int nl0 = tid / O, per = 256 / O;
    for (int nl = nl0; nl < 32; nl += per) {
        float pa = 0.f, ra = 0.f;
        for (int c = 0; c < C; ++c) {
            float xv = xs[c][nl];
            pa = fmaf(wp[o * C + c], xv, pa);
            ra = fmaf(wr[o * C + c], xv, ra);
        }
        long po = ((long)b * NPTS + n0 + nl) * O + o;
        p[po] = pa;
        r[po] = ra;
    }
}

// ---------------- FUSED gather: per-(n,o) {hi,lo,h80,h81} + fp64 stats partials ----------------
// NT=4 rows/block -> 2048 blocks (8/CU), kk-loop unrolled x2 for MLP.
template<int O>
__global__ __launch_bounds__(256) void gather_kernel(
    const float* __restrict__ p, const float* __restrict__ r,
    const int* __restrict__ idx, float4* __restrict__ hilo,
    double* __restrict__ partials) {
    const int NT = 4;
    const int R = (NT * O) / 256;
    const int STEP = 256 / O;
    __shared__ float r_s[NT * O];
    __shared__ int idx_s[NT * KSEL];
    __shared__ double gs8[8], gq8[8];
    int nb = NPTS / NT;
    int b = blockIdx.x / nb;
    int n0 = (blockIdx.x % nb) * NT;
    int tid = threadIdx.x;
    for (int t = tid; t < NT * O; t += 256) r_s[t] = r[((long)b * NPTS + n0) * O + t];
    for (int t = tid; t < NT * KSEL; t += 256) idx_s[t] = idx[((long)b * NPTS + n0) * KSEL + t];
    __syncthreads();
    int o = tid % O;
    int nlb = tid / O;
    const float* pb = p + (long)b * NPTS * O;
    float hi[R], lo[R], ha[R], hb[R], rv[R];
    int nlr[R];
#pragma unroll
    for (int u = 0; u < R; ++u) {
        nlr[u] = nlb + u * STEP;
        rv[u] = r_s[nlr[u] * O + o];
        hi[u] = -3.0e38f; lo[u] = 3.0e38f;
    }
    double s = 0.0, q = 0.0;
    int kk = 0;
    for (; kk + 1 < KNN - 1; kk += 2) {
        int ja[R], jb2[R];
#pragma unroll
        for (int u = 0; u < R; ++u) {
            ja[u] = idx_s[nlr[u] * KSEL + kk];
            jb2[u] = idx_s[nlr[u] * KSEL + kk + 1];
        }
#pragma unroll
        for (int u = 0; u < R; ++u) {
            float h0 = pb[(long)ja[u] * O + o] + rv[u];
            float h1 = pb[(long)jb2[u] * O + o] + rv[u];
            hi[u] = fmaxf(hi[u], fmaxf(h0, h1));
            lo[u] = fminf(lo[u], fminf(h0, h1));
            s += (double)h0 + (double)h1;
            q = fma((double)h0, (double)h0, q);
            q = fma((double)h1, (double)h1, q);
        }
    }
    for (; kk < KNN - 1; ++kk) {
#pragma unroll
        for (int u = 0; u < R; ++u) {
            int j = idx_s[nlr[u] * KSEL + kk];
            float h = pb[(long)j * O + o] + rv[u];
            hi[u] = fmaxf(hi[u], h);
            lo[u] = fminf(lo[u], h);
            s += (double)h;
            q = fma((double)h, (double)h, q);
        }
    }
#pragma unroll
    for (int u = 0; u < R; ++u) {
        int j = idx_s[nlr[u] * KSEL + (KNN - 1)];
        ha[u] = pb[(long)j * O + o] + rv[u];
        s += (double)ha[u];
        q = fma((double)ha[u], (double)ha[u], q);
        int j2 = idx_s[nlr[u] * KSEL + KNN];
        hb[u] = pb[(long)j2 * O + o] + rv[u];
    }
#pragma unroll
    for (int u = 0; u < R; ++u)
        hilo[((long)b * NPTS + n0 + nlr[u]) * O + o] = make_float4(hi[u], lo[u], ha[u], hb[u]);
    for (int off = 16; off > 0; off >>= 1) {
        s += __shfl_xor(s, off);
        q += __shfl_xor(q, off);
    }
    int hw = tid >> 5;
    if ((tid & 31) == 0) { gs8[hw] = s; gq8[hw] = q; }
    __syncthreads();
    if (tid < 2) {
        double ss = 0.0, qq = 0.0;
        for (int h2 = 0; h2 < 8; ++h2) {
            int o0 = (h2 * 32) % O;
            int g = o0 / (O / 2);
            if (g == tid) { ss += gs8[h2]; qq += gq8[h2]; }
        }
        partials[(long)blockIdx.x * 4 + tid * 2 + 0] = ss;
        partials[(long)blockIdx.x * 4 + tid * 2 + 1] = qq;
    }
}

__global__ void reduce_stats(const double* __restrict__ partials, int nblkb, double M,
                             float* __restrict__ ms) {
    int i = threadIdx.x;
    if (i >= BATCH * 2) return;
    int b = i >> 1, g = i & 1;
    double s = 0.0, q = 0.0;
    for (int t = 0; t < nblkb; ++t) {
        long blk = (long)b * nblkb + t;
        s += partials[blk * 4 + g * 2 + 0];
        q += partials[blk * 4 + g * 2 + 1];
    }
    double mean = s / M;
    double var = q / M - mean * mean;
    ms[i * 2 + 0] = (float)mean;
    ms[i * 2 + 1] = (float)(1.0 / sqrt(var + 1e-5));
}

// ---------------- finalize: normalize extremes + leaky + hedge -> feat ----------------
template<int O>
__global__ __launch_bounds__(256) void finalize_kernel(
    const float4* __restrict__ hilo, const int* __restrict__ flags,
    const float* __restrict__ ms, const float* __restrict__ gamma, const float* __restrict__ beta,
    float* __restrict__ featP, float* __restrict__ featH, int coff) {
    const int NT = 16;
    __shared__ float smP[O * NT], smH[O * NT];
    __shared__ float sc_s[O], sh_s[O];
    __shared__ int flag_s[NT];
    int nb = NPTS / NT;
    int b = blockIdx.x / nb;
    int n0 = (blockIdx.x % nb) * NT;
    int tid = threadIdx.x;
    if (tid < NT) flag_s[tid] = flags[b * NPTS + n0 + tid];
    if (tid < O) {
        int g = tid / (O / 2);
        float mean = ms[(b * 2 + g) * 2 + 0], rstd = ms[(b * 2 + g) * 2 + 1];
        float sc = rstd * gamma[tid];
        sc_s[tid] = sc;
        sh_s[tid] = beta[tid] - mean * sc;
    }
    __syncthreads();
    int o = tid % O;
    int nl0 = tid / O, nrep = 256 / O;
    float sc = sc_s[o], sh = sh_s[o];
    bool pos = (sc >= 0.f);
    for (int nl = nl0; nl < NT; nl += nrep) {
        float4 v = hilo[((long)b * NPTS + n0 + nl) * O + o];
        float h0 = pos ? fmaxf(v.x, v.z) : fminf(v.y, v.z);
        float h1 = pos ? fmaxf(v.x, v.w) : fminf(v.y, v.w);
        float v0 = h0 * sc + sh; v0 = v0 >= 0.f ? v0 : 0.2f * v0;
        float v1 = h1 * sc + sh; v1 = v1 >= 0.f ? v1 : 0.2f * v1;
        float outv = v0;
        if (flag_s[nl] && fabsf(v0 - v1) <= 0.45f) outv = 0.5f * (v0 + v1);
        smP[o * NT + nl] = v0;
        smH[o * NT + nl] = outv;
    }
    __syncthreads();
    long obase = ((long)b * 256 + coff) * NPTS + n0;
    for (int i = tid; i < O * NT; i += 256) {
        int oo = i / NT, nl = i % NT;
        featP[obase + (long)oo * NPTS + nl] = smP[i];
        featH[obase + (long)oo * NPTS + nl] = smH[i];
    }
}

// ---------------- MLP GEMM fused with per-(b,o) hmax/hmin + stats (no h buffer) ----------------
__global__ __launch_bounds__(256) void mlp_gemm_kernel(
    const float* __restrict__ xf, const float* __restrict__ Wm, const float* __restrict__ bm,
    unsigned* __restrict__ mmax, unsigned* __restrict__ mmin, double* __restrict__ stats) {
    int b = blockIdx.z;
    int o0 = blockIdx.y * 64, n0 = blockIdx.x * 64;
    __shared__ float wm_s[64][65];
    __shared__ float xf_s[64][64];
    int tid = threadIdx.x;
    int tx = tid & 15, ty = tid >> 4;
    float acc[4][4] = {};
    for (int kc = 0; kc < 256; kc += 64) {
        for (int i = tid; i < 64 * 64; i += 256) {
            int row = i >> 6, col = i & 63;
            wm_s[row][col] = Wm[(long)(o0 + row) * 256 + kc + col];
            xf_s[row][col] = xf[(long)b * 256 * NPTS + (long)(kc + row) * NPTS + n0 + col];
        }
        __syncthreads();
        for (int c = 0; c < 64; ++c) {
            float a[4], bb[4];
#pragma unroll
            for (int u = 0; u < 4; ++u) a[u] = wm_s[ty * 4 + u][c];
#pragma unroll
            for (int v = 0; v < 4; ++v) bb[v] = xf_s[c][tx * 4 + v];
#pragma unroll
            for (int u = 0; u < 4; ++u)
#pragma unroll
                for (int v = 0; v < 4; ++v) acc[u][v] = fmaf(a[u], bb[v], acc[u][v]);
        }
        __syncthreads();
    }
    double s = 0.0, q = 0.0;
#pragma unroll
    for (int u = 0; u < 4; ++u) {
        int o = o0 + ty * 4 + u;
        float bv = bm[o];
        float mx = -3.0e38f, mn = 3.0e38f;
#pragma unroll
        for (int v = 0; v < 4; ++v) {
            float hv = acc[u][v] + bv;
            mx = fmaxf(mx, hv);
            mn = fminf(mn, hv);
            s += (double)hv;
            q += (double)hv * (double)hv;
        }
        // reduce max/min across the 16-lane tx group (lanes of one ty are contiguous in a wave)
        for (int d = 1; d < 16; d <<= 1) {
            mx = fmaxf(mx, __shfl_xor(mx, d));
            mn = fminf(mn, __shfl_xor(mn, d));
        }
        if (tx == 0) {
            atomicMax(&mmax[((long)b << 10) + o], f2key(mx));
            atomicMin(&mmin[((long)b << 10) + o], f2key(mn));
        }
    }
    for (int off = 32; off > 0; off >>= 1) {
        s += __shfl_xor(s, off);
        q += __shfl_xor(q, off);
    }
    __shared__ double rs[4], rq[4];
    int wid = tid >> 6;
    if ((tid & 63) == 0) { rs[wid] = s; rq[wid] = q; }
    __syncthreads();
    if (tid == 0) {
        s = rs[0] + rs[1] + rs[2] + rs[3];
        q = rq[0] + rq[1] + rq[2] + rq[3];
        int g = o0 / 128;
        atomicAdd(&stats[(b * 8 + g) * 2 + 0], s);
        atomicAdd(&stats[(b * 8 + g) * 2 + 1], q);
    }
}

__global__ void finalize64_kernel(const double* __restrict__ st, double* __restrict__ msout,
                                  int G, double M) {
    int i = threadIdx.x;
    if (i >= BATCH * G) return;
    double s = st[i * 2], q = st[i * 2 + 1];
    double mean = s / M;
    double var = q / M - mean * mean;
    msout[i * 2] = mean;
    msout[i * 2 + 1] = 1.0 / sqrt(var + 1e-5);
}

// x4[b,o] = relu(g(hmax)) if sc>=0 else relu(g(hmin))  (== max_n relu(g(h_n)))
__global__ void mlp_final_kernel(
    const unsigned* __restrict__ mmax, const unsigned* __restrict__ mmin,
    const double* __restrict__ ms, const float* __restrict__ gm,
    const float* __restrict__ betam, float* __restrict__ x4) {
    int i = blockIdx.x * 256 + threadIdx.x;
    if (i >= BATCH * 1024) return;
    int b = i >> 10, o = i & 1023;
    int g = o >> 7;
    float mean = (float)ms[(b * 8 + g) * 2], rstd = (float)ms[(b * 8 + g) * 2 + 1];
    float sc = rstd * gm[o], sh = betam[o] - mean * sc;
    float hsel = (sc >= 0.f) ? key2f(mmax[i]) : key2f(mmin[i]);
    x4[i] = fmaxf(hsel * sc + sh, 0.f);
}

template<int C, int O>
static void run_layer(const float* xin, long sb, const float* W,
                      const float* gamma, const float* beta, int coff,
                      float* featP, float* featH,
                      double* xxb, float* dist, bool full, int* idx, int* flags,
                      float* pbuf, float* rbuf, float4* hilo,
                      double* partials, float* msf, hipStream_t stream) {
    xx64_kernel<<<(BATCH * NPTS + 255) / 256, 256, 0, stream>>>(xin, sb, C, xxb);
    if (full) {
        dist_kernel<<<dim3(32, 32, BATCH), 256, 0, stream>>>(xin, sb, C, xxb, dist, 0);
        topk_radix_kernel<<<dim3(NPTS, 1, BATCH), 256, 0, stream>>>(dist, idx, flags, 0);
    } else {
        for (int b = 0; b < BATCH; ++b) {
            dist_kernel<<<dim3(32, 32, 1), 256, 0, stream>>>(xin, sb, C, xxb, dist, b);
            topk_radix_kernel<<<dim3(NPTS, 1, 1), 256, 0, stream>>>(dist, idx, flags, b);
        }
    }
    pr_kernel<C, O><<<BATCH * NPTS / 32, 256, 0, stream>>>(xin, sb, W, pbuf, rbuf);
    gather_kernel<O><<<BATCH * NPTS / 4, 256, 0, stream>>>(pbuf, rbuf, idx, hilo, partials);
    double M = (double)((long)(O / 2) * NPTS * KNN);
    reduce_stats<<<1, 64, 0, stream>>>(partials, NPTS / 4, M, msf);
    finalize_kernel<O><<<BATCH * NPTS / 16, 256, 0, stream>>>(hilo, flags, msf,
                                                              gamma, beta, featP, featH, coff);
}

extern "C" void kernel_launch(void* const* d_in, const int* in_sizes, int n_in,
                              void* d_out, int out_size, void* d_ws, size_t ws_size,
                              hipStream_t stream) {
    const float* x = (const float*)d_in[0];
    const float* W1 = (const float*)d_in[1];
    const float* g1 = (const float*)d_in[2];
    const float* b1 = (const float*)d_in[3];
    const float* W2 = (const float*)d_in[4];
    const float* g2 = (const float*)d_in[5];
    const float* b2 = (const float*)d_in[6];
    const float* W3 = (const float*)d_in[7];
    const float* g3 = (const float*)d_in[8];
    const float* b3 = (const float*)d_in[9];
    const float* Wm = (const float*)d_in[10];
    const float* bm = (const float*)d_in[11];
    const float* gm = (const float*)d_in[12];
    const float* betam = (const float*)d_in[13];

    float* out = (float*)d_out;
    float* x4 = out;
    float* featH = out + BATCH * 1024;

    char* ws = (char*)d_ws;
    size_t off = 0;
    auto alloc = [&](size_t bytes) -> void* {
        void* pp = ws + off;
        off += (bytes + 255) & ~(size_t)255;
        return pp;
    };
    double* xxb = (double*)alloc((size_t)BATCH * NPTS * 8);
    int* idx = (int*)alloc((size_t)BATCH * NPTS * KSEL * 4);
    int* flags = (int*)alloc((size_t)BATCH * NPTS * 4);
    float* featP = (float*)alloc((size_t)BATCH * 256 * NPTS * 4);
    float* pbuf = (float*)alloc((size_t)BATCH * NPTS * 128 * 4);
    float* rbuf = (float*)alloc((size_t)BATCH * NPTS * 128 * 4);
    float4* hilo = (float4*)alloc((size_t)BATCH * NPTS * 128 * 16);
    double* partials = (double*)alloc((size_t)(BATCH * NPTS / 4) * 4 * 8);
    float* msf = (float*)alloc(64 * 4);
    double* statsd = (double*)alloc(128 * 8);
    double* msd = (double*)alloc(128 * 8);
    unsigned* mmax = (unsigned*)alloc((size_t)BATCH * 1024 * 4);
    unsigned* mmin = (unsigned*)alloc((size_t)BATCH * 1024 * 4);
    size_t base = off;
    bool full = (ws_size >= base + (size_t)BATCH * NPTS * NPTS * 4);
    float* dist = (float*)alloc(full ? (size_t)BATCH * NPTS * NPTS * 4
                                     : (size_t)NPTS * NPTS * 4);

    hipMemsetAsync(statsd, 0, 128 * 8, stream);
    hipMemsetAsync(mmax, 0x00, (size_t)BATCH * 1024 * 4, stream);
    hipMemsetAsync(mmin, 0xFF, (size_t)BATCH * 1024 * 4, stream);

    run_layer<3, 64>(x, 3L * NPTS, W1, g1, b1, 0,
                     featP, featH, xxb, dist, full, idx, flags, pbuf, rbuf, hilo, partials, msf, stream);
    run_layer<64, 64>(featP, 256L * NPTS, W2, g2, b2, 64,
                      featP, featH, xxb, dist, full, idx, flags, pbuf, rbuf, hilo, partials, msf, stream);
    run_layer<64, 128>(featP + 64L * NPTS, 256L * NPTS, W3, g3, b3, 128,
                       featP, featH, xxb, dist, full, idx, flags, pbuf, rbuf, hilo, partials, msf, stream);

    mlp_gemm_kernel<<<dim3(32, 16, BATCH), 256, 0, stream>>>(featH, Wm, bm, mmax, mmin, statsd);
    finalize64_kernel<<<1, 64, 0, stream>>>(statsd, msd, 8, (double)(128L * NPTS));
    mlp_final_kernel<<<(BATCH * 1024 + 255) / 256, 256, 0, stream>>>(mmax, mmin, msd, gm, betam, x4);
    (void)in_sizes; (void)n_in; (void)out_size; (void)ws_size;
}

// Round 10
// 754.572 us; speedup vs baseline: 3.5549x; 1.0007x over previous
//
#include <hip/hip_runtime.h>
#include <hip/hip_bf16.h>

#define NPTS 2048
#define KNN 80
#define KSEL 81
#define BATCH 4

__device__ __forceinline__ unsigned f2key(float f) {
    unsigned u = __float_as_uint(f);
    return u ^ ((u & 0x80000000u) ? 0xFFFFFFFFu : 0x80000000u);
}
__device__ __forceinline__ float key2f(unsigned k) {
    unsigned u = (k & 0x80000000u) ? (k ^ 0x80000000u) : ~k;
    return __uint_as_float(u);
}

// ---------------- xx (fp64) ----------------
__global__ void xx64_kernel(const float* __restrict__ x, long sb, int C, double* __restrict__ xx) {
    int i = blockIdx.x * 256 + threadIdx.x;
    if (i >= BATCH * NPTS) return;
    int b = i / NPTS, n = i % NPTS;
    const float* xp = x + (long)b * sb + n;
    double s = 0.0;
    for (int c = 0; c < C; ++c) { double v = (double)xp[(long)c * NPTS]; s = fma(v, v, s); }
    xx[i] = s;
}

// ---------------- dist: fp32 accumulate, fp64 final combine -> fp32 ----------------
__global__ __launch_bounds__(256) void dist_kernel(
    const float* __restrict__ x, long sb, int C,
    const double* __restrict__ xx, float* __restrict__ dist, int b_base) {
    int bz = blockIdx.z;
    int b = b_base + bz;
    int i0 = blockIdx.y * 64, j0 = blockIdx.x * 64;
    __shared__ float xi[32][64];
    __shared__ float xj[32][64];
    const float* xb = x + (long)b * sb;
    int tid = threadIdx.x, tx = tid & 15, ty = tid >> 4;
    float acc[4][4] = {};
    for (int cc = 0; cc < C; cc += 32) {
        int Cc = C - cc; if (Cc > 32) Cc = 32;
        for (int t = tid; t < Cc * 64; t += 256) {
            int c = t >> 6, l = t & 63;
            xi[c][l] = xb[(long)(cc + c) * NPTS + i0 + l];
            xj[c][l] = xb[(long)(cc + c) * NPTS + j0 + l];
        }
        __syncthreads();
        for (int c = 0; c < Cc; ++c) {
            float a[4], bb[4];
#pragma unroll
            for (int u = 0; u < 4; ++u) a[u] = xi[c][ty * 4 + u];
#pragma unroll
            for (int v = 0; v < 4; ++v) bb[v] = xj[c][tx * 4 + v];
#pragma unroll
            for (int u = 0; u < 4; ++u)
#pragma unroll
                for (int v = 0; v < 4; ++v) acc[u][v] = fmaf(a[u], bb[v], acc[u][v]);
        }
        __syncthreads();
    }
    const double* xxb = xx + b * NPTS;
    float* drow = dist + (long)bz * NPTS * NPTS;
#pragma unroll
    for (int u = 0; u < 4; ++u) {
        int i = i0 + ty * 4 + u;
        double xxi = xxb[i];
#pragma unroll
        for (int v = 0; v < 4; ++v) {
            int j = j0 + tx * 4 + v;
            drow[(long)i * NPTS + j] = (float)(2.0 * (double)acc[u][v] - xxi - xxb[j]);
        }
    }
}

// ---------------- radix-select top-81 per row (privatized histograms) ----------------
__global__ __launch_bounds__(256) void topk_radix_kernel(
    const float* __restrict__ dist, int* __restrict__ idxout,
    int* __restrict__ flags, int b_base) {
    int bz = blockIdx.z;
    int b = b_base + bz;
    int row = blockIdx.x;
    const float* dr = dist + ((long)bz * NPTS + row) * NPTS;
    int tid = threadIdx.x;
    int lane = tid & 63, wv = tid >> 6;
    int base = tid * 8;
    float fv[8];
    unsigned kv[8];
    {
        float4 a0 = *(const float4*)(dr + base);
        float4 a1 = *(const float4*)(dr + base + 4);
        fv[0] = a0.x; fv[1] = a0.y; fv[2] = a0.z; fv[3] = a0.w;
        fv[4] = a1.x; fv[5] = a1.y; fv[6] = a1.z; fv[7] = a1.w;
    }
#pragma unroll
    for (int u = 0; u < 8; ++u) kv[u] = f2key(fv[u]);

    __shared__ unsigned hist4[4][256];
    __shared__ unsigned scan_s[256];
    __shared__ unsigned wtot[4];
    __shared__ unsigned sh_prefix;
    __shared__ int sh_remaining;
    unsigned prefix = 0;
    int remaining = KSEL;

    for (int pass = 0; pass < 4; ++pass) {
        int shift = 24 - pass * 8;
        {
            unsigned* hflat = &hist4[0][0];
            for (int t = tid; t < 1024; t += 256) hflat[t] = 0;
        }
        __syncthreads();
        if (pass == 0) {
#pragma unroll
            for (int u = 0; u < 8; ++u) atomicAdd(&hist4[wv][kv[u] >> 24], 1u);
        } else {
            unsigned pmask = 0xFFFFFFFFu << (shift + 8);
#pragma unroll
            for (int u = 0; u < 8; ++u)
                if ((kv[u] & pmask) == prefix) atomicAdd(&hist4[wv][(kv[u] >> shift) & 255u], 1u);
        }
        __syncthreads();
        unsigned s = hist4[0][tid] + hist4[1][tid] + hist4[2][tid] + hist4[3][tid];
#pragma unroll
        for (int d = 1; d < 64; d <<= 1) {
            unsigned o = __shfl_down(s, d);
            s += (lane + d < 64) ? o : 0u;
        }
        if (lane == 0) wtot[wv] = s;
        __syncthreads();
        unsigned offs = 0;
        for (int w2 = wv + 1; w2 < 4; ++w2) offs += wtot[w2];
        s += offs;
        scan_s[tid] = s;
        __syncthreads();
        unsigned nxt = (tid == 255) ? 0u : scan_s[tid + 1];
        if (s >= (unsigned)remaining && nxt < (unsigned)remaining) {
            sh_prefix = prefix | ((unsigned)tid << shift);
            sh_remaining = remaining - (int)nxt;
        }
        __syncthreads();
        prefix = sh_prefix;
        remaining = sh_remaining;
        __syncthreads();
    }

    __shared__ int cnt;
    __shared__ int sel[KSEL];
    __shared__ float selv[KSEL];
    if (tid == 0) cnt = 0;
    __syncthreads();
#pragma unroll
    for (int u = 0; u < 8; ++u) {
        if (kv[u] > prefix) {
            int pos = atomicAdd(&cnt, 1);
            sel[pos] = base + u;
            selv[pos] = fv[u];
        }
    }
    __syncthreads();
    int cgt = cnt;
    unsigned tmask = 0;
#pragma unroll
    for (int u = 0; u < 8; ++u)
        if (kv[u] == prefix) tmask |= (1u << u);
    __shared__ int swi[4];
    float vtie = key2f(prefix);
    for (int t = 0; t < remaining; ++t) {
        int best = 0x7FFFFFFF;
#pragma unroll
        for (int u = 0; u < 8; ++u)
            if (tmask & (1u << u)) best = min(best, base + u);
        for (int off2 = 32; off2 > 0; off2 >>= 1)
            best = min(best, __shfl_xor(best, off2));
        if (lane == 0) swi[wv] = best;
        __syncthreads();
        best = min(min(swi[0], swi[1]), min(swi[2], swi[3]));
        if (best >= base && best < base + 8) tmask &= ~(1u << (best - base));
        if (tid == 0) { sel[cgt + t] = best; selv[cgt + t] = vtie; }
        __syncthreads();
    }

    __shared__ unsigned sk_s[4]; __shared__ int si_s[4], sp_s[4];
    unsigned k1 = 0xFFFFFFFFu; int id1 = -1, p1 = tid;
    if (tid < KSEL) { k1 = f2key(selv[tid]); id1 = sel[tid]; }
#pragma unroll
    for (int off2 = 32; off2 > 0; off2 >>= 1) {
        unsigned ok = __shfl_xor(k1, off2);
        int oid = __shfl_xor(id1, off2);
        int op = __shfl_xor(p1, off2);
        if (ok < k1 || (ok == k1 && oid > id1)) { k1 = ok; id1 = oid; p1 = op; }
    }
    if (lane == 0) { sk_s[wv] = k1; si_s[wv] = id1; sp_s[wv] = p1; }
    __syncthreads();
    unsigned km = sk_s[0]; int im = si_s[0], pm = sp_s[0];
    for (int w2 = 1; w2 < 4; ++w2) {
        if (sk_s[w2] < km || (sk_s[w2] == km && si_s[w2] > im)) { km = sk_s[w2]; im = si_s[w2]; pm = sp_s[w2]; }
    }
    int p81 = pm;
    __syncthreads();
    k1 = 0xFFFFFFFFu; id1 = -1; p1 = tid;
    if (tid < KSEL && tid != p81) { k1 = f2key(selv[tid]); id1 = sel[tid]; }
#pragma unroll
    for (int off2 = 32; off2 > 0; off2 >>= 1) {
        unsigned ok = __shfl_xor(k1, off2);
        int oid = __shfl_xor(id1, off2);
        int op = __shfl_xor(p1, off2);
        if (ok < k1 || (ok == k1 && oid > id1)) { k1 = ok; id1 = oid; p1 = op; }
    }
    if (lane == 0) { sk_s[wv] = k1; si_s[wv] = id1; sp_s[wv] = p1; }
    __syncthreads();
    km = sk_s[0]; im = si_s[0]; pm = sp_s[0];
    for (int w2 = 1; w2 < 4; ++w2) {
        if (sk_s[w2] < km || (sk_s[w2] == km && si_s[w2] > im)) { km = sk_s[w2]; im = si_s[w2]; pm = sp_s[w2]; }
    }
    int p80 = pm;
    __syncthreads();
    if (tid == 0) {
        int ts; float tv;
        ts = sel[80]; sel[80] = sel[p81]; sel[p81] = ts;
        tv = selv[80]; selv[80] = selv[p81]; selv[p81] = tv;
        if (p80 == 80) p80 = p81;
        ts = sel[79]; sel[79] = sel[p80]; sel[p80] = ts;
        tv = selv[79]; selv[79] = selv[p80]; selv[p80] = tv;
        float d80f = selv[79], d81f = selv[80];
        float eta = 8e-5f + 4e-6f * fabsf(d80f);
        flags[b * NPTS + row] = ((d80f - d81f) <= eta) ? 1 : 0;
    }
    __syncthreads();
    int* outp = idxout + ((long)b * NPTS + row) * KSEL;
    for (int t = tid; t < KSEL; t += 256) outp[t] = sel[t];
}

// ---------------- p/r projections ----------------
template<int C, int O>
__global__ __launch_bounds__(256) void pr_kernel(
    const float* __restrict__ x, long sb, const float* __restrict__ W,
    float* __restrict__ p, float* __restrict__ r) {
    __shared__ float wp[C * O];
    __shared__ float wr[C * O];
    __shared__ float xs[C][32];
    int nb = NPTS / 32;
    int b = blockIdx.x / nb;
    int n0 = (blockIdx.x % nb) * 32;
    int tid = threadIdx.x;
    for (int t = tid; t < C * O; t += 256) {
        int o = t / C, c = t % C;
        float w1 = W[o * 2 * C + c];
        wp[o * C + c] = w1;
        wr[o * C + c] = W[o * 2 * C + C + c] - w1;
    }
    const float* xb = x + (long)b * sb;
    for (int t = tid; t < C * 32; t += 256) {
        int c = t / 32, nn = t & 31;
        xs[c][nn] = xb[(long)c * NPTS + n0 + nn];
    }
    __syncthreads();
    int o = tid % O;
    int nl0 = tid / O, per = 256 / O;
    for (int nl = nl0; nl < 32; nl += per) {
        float pa = 0.f, ra = 0.f;
        for (int c = 0; c < C; ++c) {
            float xv = xs[c][nl];
            pa = fmaf(wp[o * C + c], xv, pa);
            ra = fmaf(wr[o * C + c], xv, ra);
        }
        long po = ((long)b * NPTS + n0 + nl) * O + o;
        p[po] = pa;
        r[po] = ra;
    }
}

// ---------------- FUSED gather: fp32 dual accumulators, kk unrolled x4 ----------------
template<int O>
__global__ __launch_bounds__(256) void gather_kernel(
    const float* __restrict__ p, const float* __restrict__ r,
    const int* __restrict__ idx, float4* __restrict__ hilo,
    double* __restrict__ partials) {
    const int NT = 4;
    const int R = (NT * O) / 256;
    const int STEP = 256 / O;
    __shared__ float r_s[NT * O];
    __shared__ int idx_s[NT * KSEL];
    __shared__ double gs8[8], gq8[8];
    int nb = NPTS / NT;
    int b = blockIdx.x / nb;
    int n0 = (blockIdx.x % nb) * NT;
    int tid = threadIdx.x;
    for (int t = tid; t < NT * O; t += 256) r_s[t] = r[((long)b * NPTS + n0) * O + t];
    for (int t = tid; t < NT * KSEL; t += 256) idx_s[t] = idx[((long)b * NPTS + n0) * KSEL + t];
    __syncthreads();
    int o = tid % O;
    int nlb = tid / O;
    const float* pb = p + (long)b * NPTS * O;
    float hi[R], lo[R], ha[R], hb[R], rv[R];
    int nlr[R];
#pragma unroll
    for (int u = 0; u < R; ++u) {
        nlr[u] = nlb + u * STEP;
        rv[u] = r_s[nlr[u] * O + o];
        hi[u] = -3.0e38f; lo[u] = 3.0e38f;
    }
    float s0 = 0.f, s1 = 0.f, q0 = 0.f, q1 = 0.f;
    int kk = 0;
    for (; kk + 3 < KNN - 1; kk += 4) {
        int j0[R], j1[R], j2[R], j3[R];
#pragma unroll
        for (int u = 0; u < R; ++u) {
            const int* ip = &idx_s[nlr[u] * KSEL + kk];
            j0[u] = ip[0]; j1[u] = ip[1]; j2[u] = ip[2]; j3[u] = ip[3];
        }
#pragma unroll
        for (int u = 0; u < R; ++u) {
            float h0 = pb[(long)j0[u] * O + o] + rv[u];
            float h1 = pb[(long)j1[u] * O + o] + rv[u];
            float h2 = pb[(long)j2[u] * O + o] + rv[u];
            float h3 = pb[(long)j3[u] * O + o] + rv[u];
            hi[u] = fmaxf(hi[u], fmaxf(fmaxf(h0, h1), fmaxf(h2, h3)));
            lo[u] = fminf(lo[u], fminf(fminf(h0, h1), fminf(h2, h3)));
            s0 += h0 + h2;
            s1 += h1 + h3;
            q0 = fmaf(h0, h0, q0); q0 = fmaf(h2, h2, q0);
            q1 = fmaf(h1, h1, q1); q1 = fmaf(h3, h3, q1);
        }
    }
    for (; kk < KNN - 1; ++kk) {
#pragma unroll
        for (int u = 0; u < R; ++u) {
            int j = idx_s[nlr[u] * KSEL + kk];
            float h = pb[(long)j * O + o] + rv[u];
            hi[u] = fmaxf(hi[u], h);
            lo[u] = fminf(lo[u], h);
            s0 += h;
            q0 = fmaf(h, h, q0);
        }
    }
#pragma unroll
    for (int u = 0; u < R; ++u) {
        int j = idx_s[nlr[u] * KSEL + (KNN - 1)];
        ha[u] = pb[(long)j * O + o] + rv[u];
        s0 += ha[u];
        q0 = fmaf(ha[u], ha[u], q0);
        int j2 = idx_s[nlr[u] * KSEL + KNN];
        hb[u] = pb[(long)j2 * O + o] + rv[u];
    }
#pragma unroll
    for (int u = 0; u < R; ++u)
        hilo[((long)b * NPTS + n0 + nlr[u]) * O + o] = make_float4(hi[u], lo[u], ha[u], hb[u]);
    double s = (double)s0 + (double)s1;
    double q = (double)q0 + (double)q1;
    for (int off = 16; off > 0; off >>= 1) {
        s += __shfl_xor(s, off);
        q += __shfl_xor(q, off);
    }
    int hw = tid >> 5;
    if ((tid & 31) == 0) { gs8[hw] = s; gq8[hw] = q; }
    __syncthreads();
    if (tid < 2) {
        double ss = 0.0, qq = 0.0;
        for (int h2 = 0; h2 < 8; ++h2) {
            int o0 = (h2 * 32) % O;
            int g = o0 / (O / 2);
            if (g == tid) { ss += gs8[h2]; qq += gq8[h2]; }
        }
        partials[(long)blockIdx.x * 4 + tid * 2 + 0] = ss;
        partials[(long)blockIdx.x * 4 + tid * 2 + 1] = qq;
    }
}

__global__ void reduce_stats(const double* __restrict__ partials, int nblkb, double M,
                             float* __restrict__ ms) {
    int i = threadIdx.x;
    if (i >= BATCH * 2) return;
    int b = i >> 1, g = i & 1;
    double s = 0.0, q = 0.0;
    for (int t = 0; t < nblkb; ++t) {
        long blk = (long)b * nblkb + t;
        s += partials[blk * 4 + g * 2 + 0];
        q += partials[blk * 4 + g * 2 + 1];
    }
    double mean = s / M;
    double var = q / M - mean * mean;
    ms[i * 2 + 0] = (float)mean;
    ms[i * 2 + 1] = (float)(1.0 / sqrt(var + 1e-5));
}

// ---------------- finalize: normalize extremes + leaky + hedge -> feat ----------------
template<int O>
__global__ __launch_bounds__(256) void finalize_kernel(
    const float4* __restrict__ hilo, const int* __restrict__ flags,
    const float* __restrict__ ms, const float* __restrict__ gamma, const float* __restrict__ beta,
    float* __restrict__ featP, float* __restrict__ featH, int coff) {
    const int NT = 16;
    __shared__ float smP[O * NT], smH[O * NT];
    __shared__ float sc_s[O], sh_s[O];
    __shared__ int flag_s[NT];
    int nb = NPTS / NT;
    int b = blockIdx.x / nb;
    int n0 = (blockIdx.x % nb) * NT;
    int tid = threadIdx.x;
    if (tid < NT) flag_s[tid] = flags[b * NPTS + n0 + tid];
    if (tid < O) {
        int g = tid / (O / 2);
        float mean = ms[(b * 2 + g) * 2 + 0], rstd = ms[(b * 2 + g) * 2 + 1];
        float sc = rstd * gamma[tid];
        sc_s[tid] = sc;
        sh_s[tid] = beta[tid] - mean * sc;
    }
    __syncthreads();
    int o = tid % O;
    int nl0 = tid / O, nrep = 256 / O;
    float sc = sc_s[o], sh = sh_s[o];
    bool pos = (sc >= 0.f);
    for (int nl = nl0; nl < NT; nl += nrep) {
        float4 v = hilo[((long)b * NPTS + n0 + nl) * O + o];
        float h0 = pos ? fmaxf(v.x, v.z) : fminf(v.y, v.z);
        float h1 = pos ? fmaxf(v.x, v.w) : fminf(v.y, v.w);
        float v0 = h0 * sc + sh; v0 = v0 >= 0.f ? v0 : 0.2f * v0;
        float v1 = h1 * sc + sh; v1 = v1 >= 0.f ? v1 : 0.2f * v1;
        float outv = v0;
        if (flag_s[nl] && fabsf(v0 - v1) <= 0.45f) outv = 0.5f * (v0 + v1);
        smP[o * NT + nl] = v0;
        smH[o * NT + nl] = outv;
    }
    __syncthreads();
    long obase = ((long)b * 256 + coff) * NPTS + n0;
    for (int i = tid; i < O * NT; i += 256) {
        int oo = i / NT, nl = i % NT;
        featP[obase + (long)oo * NPTS + nl] = smP[i];
        featH[obase + (long)oo * NPTS + nl] = smH[i];
    }
}

// ---------------- MLP GEMM (W transposed in LDS) fused max/min + stats ----------------
__global__ __launch_bounds__(256) void mlp_gemm_kernel(
    const float* __restrict__ xf, const float* __restrict__ Wm, const float* __restrict__ bm,
    unsigned* __restrict__ mmax, unsigned* __restrict__ mmin, double* __restrict__ stats) {
    int b = blockIdx.z;
    int o0 = blockIdx.y * 64, n0 = blockIdx.x * 64;
    __shared__ float wm_sT[64][68];  // [c][o], row stride 272B (16B aligned)
    __shared__ float xf_s[64][64];
    int tid = threadIdx.x;
    int tx = tid & 15, ty = tid >> 4;
    float acc[4][4] = {};
    for (int kc = 0; kc < 256; kc += 64) {
        for (int i = tid; i < 64 * 64; i += 256) {
            int row = i >> 6, col = i & 63;
            wm_sT[col][row] = Wm[(long)(o0 + row) * 256 + kc + col];
            xf_s[row][col] = xf[(long)b * 256 * NPTS + (long)(kc + row) * NPTS + n0 + col];
        }
        __syncthreads();
        for (int c = 0; c < 64; ++c) {
            float a[4], bb[4];
#pragma unroll
            for (int u = 0; u < 4; ++u) a[u] = wm_sT[c][ty * 4 + u];
#pragma unroll
            for (int v = 0; v < 4; ++v) bb[v] = xf_s[c][tx * 4 + v];
#pragma unroll
            for (int u = 0; u < 4; ++u)
#pragma unroll
                for (int v = 0; v < 4; ++v) acc[u][v] = fmaf(a[u], bb[v], acc[u][v]);
        }
        __syncthreads();
    }
    double s = 0.0, q = 0.0;
#pragma unroll
    for (int u = 0; u < 4; ++u) {
        int o = o0 + ty * 4 + u;
        float bv = bm[o];
        float mx = -3.0e38f, mn = 3.0e38f;
#pragma unroll
        for (int v = 0; v < 4; ++v) {
            float hv = acc[u][v] + bv;
            mx = fmaxf(mx, hv);
            mn = fminf(mn, hv);
            s += (double)hv;
            q += (double)hv * (double)hv;
        }
        for (int d = 1; d < 16; d <<= 1) {
            mx = fmaxf(mx, __shfl_xor(mx, d));
            mn = fminf(mn, __shfl_xor(mn, d));
        }
        if (tx == 0) {
            atomicMax(&mmax[((long)b << 10) + o], f2key(mx));
            atomicMin(&mmin[((long)b << 10) + o], f2key(mn));
        }
    }
    for (int off = 32; off > 0; off >>= 1) {
        s += __shfl_xor(s, off);
        q += __shfl_xor(q, off);
    }
    __shared__ double rs[4], rq[4];
    int wid = tid >> 6;
    if ((tid & 63) == 0) { rs[wid] = s; rq[wid] = q; }
    __syncthreads();
    if (tid == 0) {
        s = rs[0] + rs[1] + rs[2] + rs[3];
        q = rq[0] + rq[1] + rq[2] + rq[3];
        int g = o0 / 128;
        atomicAdd(&stats[(b * 8 + g) * 2 + 0], s);
        atomicAdd(&stats[(b * 8 + g) * 2 + 1], q);
    }
}

__global__ void finalize64_kernel(const double* __restrict__ st, double* __restrict__ msout,
                                  int G, double M) {
    int i = threadIdx.x;
    if (i >= BATCH * G) return;
    double s = st[i * 2], q = st[i * 2 + 1];
    double mean = s / M;
    double var = q / M - mean * mean;
    msout[i * 2] = mean;
    msout[i * 2 + 1] = 1.0 / sqrt(var + 1e-5);
}

__global__ void mlp_final_kernel(
    const unsigned* __restrict__ mmax, const unsigned* __restrict__ mmin,
    const double* __restrict__ ms, const float* __restrict__ gm,
    const float* __restrict__ betam, float* __restrict__ x4) {
    int i = blockIdx.x * 256 + threadIdx.x;
    if (i >= BATCH * 1024) return;
    int b = i >> 10, o = i & 1023;
    int g = o >> 7;
    float mean = (float)ms[(b * 8 + g) * 2], rstd = (float)ms[(b * 8 + g) * 2 + 1];
    float sc = rstd * gm[o], sh = betam[o] - mean * sc;
    float hsel = (sc >= 0.f) ? key2f(mmax[i]) : key2f(mmin[i]);
    x4[i] = fmaxf(hsel * sc + sh, 0.f);
}

template<int C, int O>
static void run_layer(const float* xin, long sb, const float* W,
                      const float* gamma, const float* beta, int coff,
                      float* featP, float* featH,
                      double* xxb, float* dist, bool full, int* idx, int* flags,
                      float* pbuf, float* rbuf, float4* hilo,
                      double* partials, float* msf, hipStream_t stream) {
    xx64_kernel<<<(BATCH * NPTS + 255) / 256, 256, 0, stream>>>(xin, sb, C, xxb);
    if (full) {
        dist_kernel<<<dim3(32, 32, BATCH), 256, 0, stream>>>(xin, sb, C, xxb, dist, 0);
        topk_radix_kernel<<<dim3(NPTS, 1, BATCH), 256, 0, stream>>>(dist, idx, flags, 0);
    } else {
        for (int b = 0; b < BATCH; ++b) {
            dist_kernel<<<dim3(32, 32, 1), 256, 0, stream>>>(xin, sb, C, xxb, dist, b);
            topk_radix_kernel<<<dim3(NPTS, 1, 1), 256, 0, stream>>>(dist, idx, flags, b);
        }
    }
    pr_kernel<C, O><<<BATCH * NPTS / 32, 256, 0, stream>>>(xin, sb, W, pbuf, rbuf);
    gather_kernel<O><<<BATCH * NPTS / 4, 256, 0, stream>>>(pbuf, rbuf, idx, hilo, partials);
    double M = (double)((long)(O / 2) * NPTS * KNN);
    reduce_stats<<<1, 64, 0, stream>>>(partials, NPTS / 4, M, msf);
    finalize_kernel<O><<<BATCH * NPTS / 16, 256, 0, stream>>>(hilo, flags, msf,
                                                              gamma, beta, featP, featH, coff);
}

extern "C" void kernel_launch(void* const* d_in, const int* in_sizes, int n_in,
                              void* d_out, int out_size, void* d_ws, size_t ws_size,
                              hipStream_t stream) {
    const float* x = (const float*)d_in[0];
    const float* W1 = (const float*)d_in[1];
    const float* g1 = (const float*)d_in[2];
    const float* b1 = (const float*)d_in[3];
    const float* W2 = (const float*)d_in[4];
    const float* g2 = (const float*)d_in[5];
    const float* b2 = (const float*)d_in[6];
    const float* W3 = (const float*)d_in[7];
    const float* g3 = (const float*)d_in[8];
    const float* b3 = (const float*)d_in[9];
    const float* Wm = (const float*)d_in[10];
    const float* bm = (const float*)d_in[11];
    const float* gm = (const float*)d_in[12];
    const float* betam = (const float*)d_in[13];

    float* out = (float*)d_out;
    float* x4 = out;
    float* featH = out + BATCH * 1024;

    char* ws = (char*)d_ws;
    size_t off = 0;
    auto alloc = [&](size_t bytes) -> void* {
        void* pp = ws + off;
        off += (bytes + 255) & ~(size_t)255;
        return pp;
    };
    double* xxb = (double*)alloc((size_t)BATCH * NPTS * 8);
    int* idx = (int*)alloc((size_t)BATCH * NPTS * KSEL * 4);
    int* flags = (int*)alloc((size_t)BATCH * NPTS * 4);
    float* featP = (float*)alloc((size_t)BATCH * 256 * NPTS * 4);
    float* pbuf = (float*)alloc((size_t)BATCH * NPTS * 128 * 4);
    float* rbuf = (float*)alloc((size_t)BATCH * NPTS * 128 * 4);
    float4* hilo = (float4*)alloc((size_t)BATCH * NPTS * 128 * 16);
    double* partials = (double*)alloc((size_t)(BATCH * NPTS / 4) * 4 * 8);
    float* msf = (float*)alloc(64 * 4);
    double* statsd = (double*)alloc(128 * 8);
    double* msd = (double*)alloc(128 * 8);
    unsigned* mmax = (unsigned*)alloc((size_t)BATCH * 1024 * 4);
    unsigned* mmin = (unsigned*)alloc((size_t)BATCH * 1024 * 4);
    size_t base = off;
    bool full = (ws_size >= base + (size_t)BATCH * NPTS * NPTS * 4);
    float* dist = (float*)alloc(full ? (size_t)BATCH * NPTS * NPTS * 4
                                     : (size_t)NPTS * NPTS * 4);

    hipMemsetAsync(statsd, 0, 128 * 8, stream);
    hipMemsetAsync(mmax, 0x00, (size_t)BATCH * 1024 * 4, stream);
    hipMemsetAsync(mmin, 0xFF, (size_t)BATCH * 1024 * 4, stream);

    run_layer<3, 64>(x, 3L * NPTS, W1, g1, b1, 0,
                     featP, featH, xxb, dist, full, idx, flags, pbuf, rbuf, hilo, partials, msf, stream);
    run_layer<64, 64>(featP, 256L * NPTS, W2, g2, b2, 64,
                      featP, featH, xxb, dist, full, idx, flags, pbuf, rbuf, hilo, partials, msf, stream);
    run_layer<64, 128>(featP + 64L * NPTS, 256L * NPTS, W3, g3, b3, 128,
                       featP, featH, xxb, dist, full, idx, flags, pbuf, rbuf, hilo, partials, msf, stream);

    mlp_gemm_kernel<<<dim3(32, 16, BATCH), 256, 0, stream>>>(featH, Wm, bm, mmax, mmin, statsd);
    finalize64_kernel<<<1, 64, 0, stream>>>(statsd, msd, 8, (double)(128L * NPTS));
    mlp_final_kernel<<<(BATCH * 1024 + 255) / 256, 256, 0, stream>>>(mmax, mmin, msd, gm, betam, x4);
    (void)in_sizes; (void)n_in; (void)out_size; (void)ws_size;
}

// Round 12
// 676.038 us; speedup vs baseline: 3.9679x; 1.1162x over previous
//
#include <hip/hip_runtime.h>
#include <hip/hip_bf16.h>

#define NPTS 2048
#define KNN 80
#define KSEL 81
#define BATCH 4

__device__ __forceinline__ unsigned f2key(float f) {
    unsigned u = __float_as_uint(f);
    return u ^ ((u & 0x80000000u) ? 0xFFFFFFFFu : 0x80000000u);
}
__device__ __forceinline__ float key2f(unsigned k) {
    unsigned u = (k & 0x80000000u) ? (k ^ 0x80000000u) : ~k;
    return __uint_as_float(u);
}

// ---------------- xx (fp64) ----------------
__global__ void xx64_kernel(const float* __restrict__ x, long sb, int C, double* __restrict__ xx) {
    int i = blockIdx.x * 256 + threadIdx.x;
    if (i >= BATCH * NPTS) return;
    int b = i / NPTS, n = i % NPTS;
    const float* xp = x + (long)b * sb + n;
    double s = 0.0;
    for (int c = 0; c < C; ++c) { double v = (double)xp[(long)c * NPTS]; s = fma(v, v, s); }
    xx[i] = s;
}

// ---------------- dist: fp32 accumulate, fp64 final combine -> fp32 ----------------
__global__ __launch_bounds__(256) void dist_kernel(
    const float* __restrict__ x, long sb, int C,
    const double* __restrict__ xx, float* __restrict__ dist, int b_base) {
    int bz = blockIdx.z;
    int b = b_base + bz;
    int i0 = blockIdx.y * 64, j0 = blockIdx.x * 64;
    __shared__ float xi[32][64];
    __shared__ float xj[32][64];
    const float* xb = x + (long)b * sb;
    int tid = threadIdx.x, tx = tid & 15, ty = tid >> 4;
    float acc[4][4] = {};
    for (int cc = 0; cc < C; cc += 32) {
        int Cc = C - cc; if (Cc > 32) Cc = 32;
        for (int t = tid; t < Cc * 64; t += 256) {
            int c = t >> 6, l = t & 63;
            xi[c][l] = xb[(long)(cc + c) * NPTS + i0 + l];
            xj[c][l] = xb[(long)(cc + c) * NPTS + j0 + l];
        }
        __syncthreads();
        for (int c = 0; c < Cc; ++c) {
            float a[4], bb[4];
#pragma unroll
            for (int u = 0; u < 4; ++u) a[u] = xi[c][ty * 4 + u];
#pragma unroll
            for (int v = 0; v < 4; ++v) bb[v] = xj[c][tx * 4 + v];
#pragma unroll
            for (int u = 0; u < 4; ++u)
#pragma unroll
                for (int v = 0; v < 4; ++v) acc[u][v] = fmaf(a[u], bb[v], acc[u][v]);
        }
        __syncthreads();
    }
    const double* xxb = xx + b * NPTS;
    float* drow = dist + (long)bz * NPTS * NPTS;
#pragma unroll
    for (int u = 0; u < 4; ++u) {
        int i = i0 + ty * 4 + u;
        double xxi = xxb[i];
#pragma unroll
        for (int v = 0; v < 4; ++v) {
            int j = j0 + tx * 4 + v;
            drow[(long)i * NPTS + j] = (float)(2.0 * (double)acc[u][v] - xxi - xxb[j]);
        }
    }
}

// ---------------- top-81: WAVE-PER-ROW radix select, zero block barriers ----------------
// Each of the 4 waves owns one row. All histogram/scan/collect state is per-wave;
// cross-lane via shfl/ballot only. Selection semantics identical to rounds 6-10.
__global__ __launch_bounds__(256) void topk_wave_kernel(
    const float* __restrict__ dist, int* __restrict__ idxout,
    int* __restrict__ flags, int b_base) {
    int bz = blockIdx.z;
    int b = b_base + bz;
    int tid = threadIdx.x;
    int lane = tid & 63, w = tid >> 6;
    int row = blockIdx.x * 4 + w;
    const float* dr = dist + ((long)bz * NPTS + row) * NPTS;

    // element e = i*256 + lane*4 + c  (i=0..7, c=0..3): each float4 load is wave-contiguous
    unsigned kv[32];
#pragma unroll
    for (int i = 0; i < 8; ++i) {
        float4 a = *(const float4*)(dr + i * 256 + lane * 4);
        kv[i * 4 + 0] = f2key(a.x);
        kv[i * 4 + 1] = f2key(a.y);
        kv[i * 4 + 2] = f2key(a.z);
        kv[i * 4 + 3] = f2key(a.w);
    }

    __shared__ unsigned hist[4][256];
    __shared__ int sel_s[4][KSEL];
    __shared__ float selv_s[4][KSEL];

    unsigned prefix = 0;
    int rem = KSEL;

    for (int pass = 0; pass < 4; ++pass) {
        int shift = 24 - pass * 8;
        hist[w][lane] = 0;
        hist[w][lane + 64] = 0;
        hist[w][lane + 128] = 0;
        hist[w][lane + 192] = 0;
        unsigned pm = (pass == 0) ? 0u : (0xFFFFFFFFu << (shift + 8));
#pragma unroll
        for (int u = 0; u < 32; ++u) {
            if ((kv[u] & pm) == prefix)
                atomicAdd(&hist[w][(kv[u] >> shift) & 255u], 1u);
        }
        // scan: lane owns bins [lane*4, lane*4+4)
        unsigned b0 = hist[w][lane * 4 + 0], b1 = hist[w][lane * 4 + 1];
        unsigned b2 = hist[w][lane * 4 + 2], b3 = hist[w][lane * 4 + 3];
        unsigned loc3 = b3, loc2 = b3 + b2, loc1 = b3 + b2 + b1, loc0 = b3 + b2 + b1 + b0;
        unsigned tot = loc0;
        unsigned suf = tot;
#pragma unroll
        for (int d = 1; d < 64; d <<= 1) {
            unsigned o = __shfl_down(suf, d);
            suf += (lane + d < 64) ? o : 0u;
        }
        unsigned after = suf - tot;  // counts in buckets beyond my 4
        int fdig = -1, frem = 0;
        unsigned ge, gt;
        ge = loc0 + after; gt = loc1 + after;
        if (ge >= (unsigned)rem && gt < (unsigned)rem) { fdig = lane * 4 + 0; frem = rem - (int)gt; }
        ge = loc1 + after; gt = loc2 + after;
        if (ge >= (unsigned)rem && gt < (unsigned)rem) { fdig = lane * 4 + 1; frem = rem - (int)gt; }
        ge = loc2 + after; gt = loc3 + after;
        if (ge >= (unsigned)rem && gt < (unsigned)rem) { fdig = lane * 4 + 2; frem = rem - (int)gt; }
        ge = loc3 + after; gt = after;
        if (ge >= (unsigned)rem && gt < (unsigned)rem) { fdig = lane * 4 + 3; frem = rem - (int)gt; }
        unsigned long long bal = __ballot(fdig >= 0);
        int src = __ffsll((unsigned long long)bal) - 1;
        fdig = __shfl(fdig, src);
        frem = __shfl(frem, src);
        prefix |= ((unsigned)fdig) << shift;
        rem = frem;
    }

    // collection: strictly-greater keys, lane-major deterministic order
    int myc = 0;
#pragma unroll
    for (int u = 0; u < 32; ++u) myc += (kv[u] > prefix) ? 1 : 0;
    int inc = myc;
#pragma unroll
    for (int d = 1; d < 64; d <<= 1) {
        int o = __shfl_up(inc, d);
        inc += (lane >= d) ? o : 0;
    }
    int off = inc - myc;  // exclusive prefix
    int pos = off;
#pragma unroll
    for (int u = 0; u < 32; ++u) {
        if (kv[u] > prefix) {
            int e = (u >> 2) * 256 + lane * 4 + (u & 3);
            sel_s[w][pos] = e;
            selv_s[w][pos] = key2f(kv[u]);
            ++pos;
        }
    }
    int cgt = __shfl(inc, 63);  // total strictly-greater

    // ties: rem smallest element-indices among kv == prefix (iterative wave-min)
    unsigned tmask = 0;
#pragma unroll
    for (int u = 0; u < 32; ++u)
        if (kv[u] == prefix) tmask |= (1u << u);
    float vtie = key2f(prefix);
    for (int t = 0; t < rem; ++t) {
        int best = 0x7FFFFFFF;
        unsigned m = tmask;
        while (m) {
            int u = __ffs(m) - 1;
            m &= m - 1;
            int e = (u >> 2) * 256 + lane * 4 + (u & 3);
            best = min(best, e);
        }
#pragma unroll
        for (int d = 32; d > 0; d >>= 1) best = min(best, __shfl_xor(best, d));
        if (((best >> 2) & 63) == lane) {
            int u = ((best >> 8) << 2) | (best & 3);
            tmask &= ~(1u << u);
        }
        if (lane == 0) { sel_s[w][cgt + t] = best; selv_s[w][cgt + t] = vtie; }
    }

    // rank-81 = min under (key asc, idx desc); rank-80 = 2nd min
    unsigned bk = 0xFFFFFFFFu; int bi = -1, bp = -1;
    if (lane < KSEL) { bk = f2key(selv_s[w][lane]); bi = sel_s[w][lane]; bp = lane; }
    int l2 = lane + 64;
    if (l2 < KSEL) {
        unsigned k2 = f2key(selv_s[w][l2]); int i2 = sel_s[w][l2];
        if (k2 < bk || (k2 == bk && i2 > bi)) { bk = k2; bi = i2; bp = l2; }
    }
#pragma unroll
    for (int d = 32; d > 0; d >>= 1) {
        unsigned ok = __shfl_xor(bk, d);
        int oi = __shfl_xor(bi, d);
        int op = __shfl_xor(bp, d);
        if (ok < bk || (ok == bk && oi > bi)) { bk = ok; bi = oi; bp = op; }
    }
    int p81 = bp;
    bk = 0xFFFFFFFFu; bi = -1; bp = -1;
    if (lane < KSEL && lane != p81) { bk = f2key(selv_s[w][lane]); bi = sel_s[w][lane]; bp = lane; }
    if (l2 < KSEL && l2 != p81) {
        unsigned k2 = f2key(selv_s[w][l2]); int i2 = sel_s[w][l2];
        if (k2 < bk || (k2 == bk && i2 > bi)) { bk = k2; bi = i2; bp = l2; }
    }
#pragma unroll
    for (int d = 32; d > 0; d >>= 1) {
        unsigned ok = __shfl_xor(bk, d);
        int oi = __shfl_xor(bi, d);
        int op = __shfl_xor(bp, d);
        if (ok < bk || (ok == bk && oi > bi)) { bk = ok; bi = oi; bp = op; }
    }
    int p80 = bp;

    if (lane == 0) {
        int ts; float tv;
        ts = sel_s[w][80]; sel_s[w][80] = sel_s[w][p81]; sel_s[w][p81] = ts;
        tv = selv_s[w][80]; selv_s[w][80] = selv_s[w][p81]; selv_s[w][p81] = tv;
        if (p80 == 80) p80 = p81;
        ts = sel_s[w][79]; sel_s[w][79] = sel_s[w][p80]; sel_s[w][p80] = ts;
        tv = selv_s[w][79]; selv_s[w][79] = selv_s[w][p80]; selv_s[w][p80] = tv;
        float d80f = selv_s[w][79], d81f = selv_s[w][80];
        float eta = 8e-5f + 4e-6f * fabsf(d80f);
        flags[b * NPTS + row] = ((d80f - d81f) <= eta) ? 1 : 0;
    }
    int* outp = idxout + ((long)b * NPTS + row) * KSEL;
    for (int t = lane; t < KSEL; t += 64) outp[t] = sel_s[w][t];
}

// ---------------- p/r projections ----------------
template<int C, int O>
__global__ __launch_bounds__(256) void pr_kernel(
    const float* __restrict__ x, long sb, const float* __restrict__ W,
    float* __restrict__ p, float* __restrict__ r) {
    __shared__ float wp[C * O];
    __shared__ float wr[C * O];
    __shared__ float xs[C][32];
    int nb = NPTS / 32;
    int b = blockIdx.x / nb;
    int n0 = (blockIdx.x % nb) * 32;
    int tid = threadIdx.x;
    for (int t = tid; t < C * O; t += 256) {
        int o = t / C, c = t % C;
        float w1 = W[o * 2 * C + c];
        wp[o * C + c] = w1;
        wr[o * C + c] = W[o * 2 * C + C + c] - w1;
    }
    const float* xb = x + (long)b * sb;
    for (int t = tid; t < C * 32; t += 256) {
        int c = t / 32, nn = t & 31;
        xs[c][nn] = xb[(long)c * NPTS + n0 + nn];
    }
    __syncthreads();
    int o = tid % O;
    int nl0 = tid / O, per = 256 / O;
    for (int nl = nl0; nl < 32; nl += per) {
        float pa = 0.f, ra = 0.f;
        for (int c = 0; c < C; ++c) {
            float xv = xs[c][nl];
            pa = fmaf(wp[o * C + c], xv, pa);
            ra = fmaf(wr[o * C + c], xv, ra);
        }
        long po = ((long)b * NPTS + n0 + nl) * O + o;
        p[po] = pa;
        r[po] = ra;
    }
}

// ---------------- FUSED gather: fp32 dual accumulators, kk unrolled x4 ----------------
template<int O>
__global__ __launch_bounds__(256) void gather_kernel(
    const float* __restrict__ p, const float* __restrict__ r,
    const int* __restrict__ idx, float4* __restrict__ hilo,
    double* __restrict__ partials) {
    const int NT = 4;
    const int R = (NT * O) / 256;
    const int STEP = 256 / O;
    __shared__ float r_s[NT * O];
    __shared__ int idx_s[NT * KSEL];
    __shared__ double gs8[8], gq8[8];
    int nb = NPTS / NT;
    int b = blockIdx.x / nb;
    int n0 = (blockIdx.x % nb) * NT;
    int tid = threadIdx.x;
    for (int t = tid; t < NT * O; t += 256) r_s[t] = r[((long)b * NPTS + n0) * O + t];
    for (int t = tid; t < NT * KSEL; t += 256) idx_s[t] = idx[((long)b * NPTS + n0) * KSEL + t];
    __syncthreads();
    int o = tid % O;
    int nlb = tid / O;
    const float* pb = p + (long)b * NPTS * O;
    float hi[R], lo[R], ha[R], hb[R], rv[R];
    int nlr[R];
#pragma unroll
    for (int u = 0; u < R; ++u) {
        nlr[u] = nlb + u * STEP;
        rv[u] = r_s[nlr[u] * O + o];
        hi[u] = -3.0e38f; lo[u] = 3.0e38f;
    }
    float s0 = 0.f, s1 = 0.f, q0 = 0.f, q1 = 0.f;
    int kk = 0;
    for (; kk + 3 < KNN - 1; kk += 4) {
        int j0[R], j1[R], j2[R], j3[R];
#pragma unroll
        for (int u = 0; u < R; ++u) {
            const int* ip = &idx_s[nlr[u] * KSEL + kk];
            j0[u] = ip[0]; j1[u] = ip[1]; j2[u] = ip[2]; j3[u] = ip[3];
        }
#pragma unroll
        for (int u = 0; u < R; ++u) {
            float h0 = pb[(long)j0[u] * O + o] + rv[u];
            float h1 = pb[(long)j1[u] * O + o] + rv[u];
            float h2 = pb[(long)j2[u] * O + o] + rv[u];
            float h3 = pb[(long)j3[u] * O + o] + rv[u];
            hi[u] = fmaxf(hi[u], fmaxf(fmaxf(h0, h1), fmaxf(h2, h3)));
            lo[u] = fminf(lo[u], fminf(fminf(h0, h1), fminf(h2, h3)));
            s0 += h0 + h2;
            s1 += h1 + h3;
            q0 = fmaf(h0, h0, q0); q0 = fmaf(h2, h2, q0);
            q1 = fmaf(h1, h1, q1); q1 = fmaf(h3, h3, q1);
        }
    }
    for (; kk < KNN - 1; ++kk) {
#pragma unroll
        for (int u = 0; u < R; ++u) {
            int j = idx_s[nlr[u] * KSEL + kk];
            float h = pb[(long)j * O + o] + rv[u];
            hi[u] = fmaxf(hi[u], h);
            lo[u] = fminf(lo[u], h);
            s0 += h;
            q0 = fmaf(h, h, q0);
        }
    }
#pragma unroll
    for (int u = 0; u < R; ++u) {
        int j = idx_s[nlr[u] * KSEL + (KNN - 1)];
        ha[u] = pb[(long)j * O + o] + rv[u];
        s0 += ha[u];
        q0 = fmaf(ha[u], ha[u], q0);
        int j2 = idx_s[nlr[u] * KSEL + KNN];
        hb[u] = pb[(long)j2 * O + o] + rv[u];
    }
#pragma unroll
    for (int u = 0; u < R; ++u)
        hilo[((long)b * NPTS + n0 + nlr[u]) * O + o] = make_float4(hi[u], lo[u], ha[u], hb[u]);
    double s = (double)s0 + (double)s1;
    double q = (double)q0 + (double)q1;
    for (int off = 16; off > 0; off >>= 1) {
        s += __shfl_xor(s, off);
        q += __shfl_xor(q, off);
    }
    int hw = tid >> 5;
    if ((tid & 31) == 0) { gs8[hw] = s; gq8[hw] = q; }
    __syncthreads();
    if (tid < 2) {
        double ss = 0.0, qq = 0.0;
        for (int h2 = 0; h2 < 8; ++h2) {
            int o0 = (h2 * 32) % O;
            int g = o0 / (O / 2);
            if (g == tid) { ss += gs8[h2]; qq += gq8[h2]; }
        }
        partials[(long)blockIdx.x * 4 + tid * 2 + 0] = ss;
        partials[(long)blockIdx.x * 4 + tid * 2 + 1] = qq;
    }
}

__global__ void reduce_stats(const double* __restrict__ partials, int nblkb, double M,
                             float* __restrict__ ms) {
    int i = threadIdx.x;
    if (i >= BATCH * 2) return;
    int b = i >> 1, g = i & 1;
    double s = 0.0, q = 0.0;
    for (int t = 0; t < nblkb; ++t) {
        long blk = (long)b * nblkb + t;
        s += partials[blk * 4 + g * 2 + 0];
        q += partials[blk * 4 + g * 2 + 1];
    }
    double mean = s / M;
    double var = q / M - mean * mean;
    ms[i * 2 + 0] = (float)mean;
    ms[i * 2 + 1] = (float)(1.0 / sqrt(var + 1e-5));
}

// ---------------- finalize: normalize extremes + leaky + hedge -> feat ----------------
template<int O>
__global__ __launch_bounds__(256) void finalize_kernel(
    const float4* __restrict__ hilo, const int* __restrict__ flags,
    const float* __restrict__ ms, const float* __restrict__ gamma, const float* __restrict__ beta,
    float* __restrict__ featP, float* __restrict__ featH, int coff) {
    const int NT = 16;
    __shared__ float smP[O * NT], smH[O * NT];
    __shared__ float sc_s[O], sh_s[O];
    __shared__ int flag_s[NT];
    int nb = NPTS / NT;
    int b = blockIdx.x / nb;
    int n0 = (blockIdx.x % nb) * NT;
    int tid = threadIdx.x;
    if (tid < NT) flag_s[tid] = flags[b * NPTS + n0 + tid];
    if (tid < O) {
        int g = tid / (O / 2);
        float mean = ms[(b * 2 + g) * 2 + 0], rstd = ms[(b * 2 + g) * 2 + 1];
        float sc = rstd * gamma[tid];
        sc_s[tid] = sc;
        sh_s[tid] = beta[tid] - mean * sc;
    }
    __syncthreads();
    int o = tid % O;
    int nl0 = tid / O, nrep = 256 / O;
    float sc = sc_s[o], sh = sh_s[o];
    bool pos = (sc >= 0.f);
    for (int nl = nl0; nl < NT; nl += nrep) {
        float4 v = hilo[((long)b * NPTS + n0 + nl) * O + o];
        float h0 = pos ? fmaxf(v.x, v.z) : fminf(v.y, v.z);
        float h1 = pos ? fmaxf(v.x, v.w) : fminf(v.y, v.w);
        float v0 = h0 * sc + sh; v0 = v0 >= 0.f ? v0 : 0.2f * v0;
        float v1 = h1 * sc + sh; v1 = v1 >= 0.f ? v1 : 0.2f * v1;
        float outv = v0;
        if (flag_s[nl] && fabsf(v0 - v1) <= 0.45f) outv = 0.5f * (v0 + v1);
        smP[o * NT + nl] = v0;
        smH[o * NT + nl] = outv;
    }
    __syncthreads();
    long obase = ((long)b * 256 + coff) * NPTS + n0;
    for (int i = tid; i < O * NT; i += 256) {
        int oo = i / NT, nl = i % NT;
        featP[obase + (long)oo * NPTS + nl] = smP[i];
        featH[obase + (long)oo * NPTS + nl] = smH[i];
    }
}

// ---------------- MLP GEMM (W transposed in LDS) fused max/min + stats ----------------
__global__ __launch_bounds__(256) void mlp_gemm_kernel(
    const float* __restrict__ xf, const float* __restrict__ Wm, const float* __restrict__ bm,
    unsigned* __restrict__ mmax, unsigned* __restrict__ mmin, double* __restrict__ stats) {
    int b = blockIdx.z;
    int o0 = blockIdx.y * 64, n0 = blockIdx.x * 64;
    __shared__ float wm_sT[64][68];
    __shared__ float xf_s[64][64];
    int tid = threadIdx.x;
    int tx = tid & 15, ty = tid >> 4;
    float acc[4][4] = {};
    for (int kc = 0; kc < 256; kc += 64) {
        for (int i = tid; i < 64 * 64; i += 256) {
            int row = i >> 6, col = i & 63;
            wm_sT[col][row] = Wm[(long)(o0 + row) * 256 + kc + col];
            xf_s[row][col] = xf[(long)b * 256 * NPTS + (long)(kc + row) * NPTS + n0 + col];
        }
        __syncthreads();
        for (int c = 0; c < 64; ++c) {
            float a[4], bb[4];
#pragma unroll
            for (int u = 0; u < 4; ++u) a[u] = wm_sT[c][ty * 4 + u];
#pragma unroll
            for (int v = 0; v < 4; ++v) bb[v] = xf_s[c][tx * 4 + v];
#pragma unroll
            for (int u = 0; u < 4; ++u)
#pragma unroll
                for (int v = 0; v < 4; ++v) acc[u][v] = fmaf(a[u], bb[v], acc[u][v]);
        }
        __syncthreads();
    }
    double s = 0.0, q = 0.0;
#pragma unroll
    for (int u = 0; u < 4; ++u) {
        int o = o0 + ty * 4 + u;
        float bv = bm[o];
        float mx = -3.0e38f, mn = 3.0e38f;
#pragma unroll
        for (int v = 0; v < 4; ++v) {
            float hv = acc[u][v] + bv;
            mx = fmaxf(mx, hv);
            mn = fminf(mn, hv);
            s += (double)hv;
            q += (double)hv * (double)hv;
        }
        for (int d = 1; d < 16; d <<= 1) {
            mx = fmaxf(mx, __shfl_xor(mx, d));
            mn = fminf(mn, __shfl_xor(mn, d));
        }
        if (tx == 0) {
            atomicMax(&mmax[((long)b << 10) + o], f2key(mx));
            atomicMin(&mmin[((long)b << 10) + o], f2key(mn));
        }
    }
    for (int off = 32; off > 0; off >>= 1) {
        s += __shfl_xor(s, off);
        q += __shfl_xor(q, off);
    }
    __shared__ double rs[4], rq[4];
    int wid = tid >> 6;
    if ((tid & 63) == 0) { rs[wid] = s; rq[wid] = q; }
    __syncthreads();
    if (tid == 0) {
        s = rs[0] + rs[1] + rs[2] + rs[3];
        q = rq[0] + rq[1] + rq[2] + rq[3];
        int g = o0 / 128;
        atomicAdd(&stats[(b * 8 + g) * 2 + 0], s);
        atomicAdd(&stats[(b * 8 + g) * 2 + 1], q);
    }
}

__global__ void finalize64_kernel(const double* __restrict__ st, double* __restrict__ msout,
                                  int G, double M) {
    int i = threadIdx.x;
    if (i >= BATCH * G) return;
    double s = st[i * 2], q = st[i * 2 + 1];
    double mean = s / M;
    double var = q / M - mean * mean;
    msout[i * 2] = mean;
    msout[i * 2 + 1] = 1.0 / sqrt(var + 1e-5);
}

__global__ void mlp_final_kernel(
    const unsigned* __restrict__ mmax, const unsigned* __restrict__ mmin,
    const double* __restrict__ ms, const float* __restrict__ gm,
    const float* __restrict__ betam, float* __restrict__ x4) {
    int i = blockIdx.x * 256 + threadIdx.x;
    if (i >= BATCH * 1024) return;
    int b = i >> 10, o = i & 1023;
    int g = o >> 7;
    float mean = (float)ms[(b * 8 + g) * 2], rstd = (float)ms[(b * 8 + g) * 2 + 1];
    float sc = rstd * gm[o], sh = betam[o] - mean * sc;
    float hsel = (sc >= 0.f) ? key2f(mmax[i]) : key2f(mmin[i]);
    x4[i] = fmaxf(hsel * sc + sh, 0.f);
}

template<int C, int O>
static void run_layer(const float* xin, long sb, const float* W,
                      const float* gamma, const float* beta, int coff,
                      float* featP, float* featH,
                      double* xxb, float* dist, bool full, int* idx, int* flags,
                      float* pbuf, float* rbuf, float4* hilo,
                      double* partials, float* msf, hipStream_t stream) {
    xx64_kernel<<<(BATCH * NPTS + 255) / 256, 256, 0, stream>>>(xin, sb, C, xxb);
    if (full) {
        dist_kernel<<<dim3(32, 32, BATCH), 256, 0, stream>>>(xin, sb, C, xxb, dist, 0);
        topk_wave_kernel<<<dim3(NPTS / 4, 1, BATCH), 256, 0, stream>>>(dist, idx, flags, 0);
    } else {
        for (int b = 0; b < BATCH; ++b) {
            dist_kernel<<<dim3(32, 32, 1), 256, 0, stream>>>(xin, sb, C, xxb, dist, b);
            topk_wave_kernel<<<dim3(NPTS / 4, 1, 1), 256, 0, stream>>>(dist, idx, flags, b);
        }
    }
    pr_kernel<C, O><<<BATCH * NPTS / 32, 256, 0, stream>>>(xin, sb, W, pbuf, rbuf);
    gather_kernel<O><<<BATCH * NPTS / 4, 256, 0, stream>>>(pbuf, rbuf, idx, hilo, partials);
    double M = (double)((long)(O / 2) * NPTS * KNN);
    reduce_stats<<<1, 64, 0, stream>>>(partials, NPTS / 4, M, msf);
    finalize_kernel<O><<<BATCH * NPTS / 16, 256, 0, stream>>>(hilo, flags, msf,
                                                              gamma, beta, featP, featH, coff);
}

extern "C" void kernel_launch(void* const* d_in, const int* in_sizes, int n_in,
                              void* d_out, int out_size, void* d_ws, size_t ws_size,
                              hipStream_t stream) {
    const float* x = (const float*)d_in[0];
    const float* W1 = (const float*)d_in[1];
    const float* g1 = (const float*)d_in[2];
    const float* b1 = (const float*)d_in[3];
    const float* W2 = (const float*)d_in[4];
    const float* g2 = (const float*)d_in[5];
    const float* b2 = (const float*)d_in[6];
    const float* W3 = (const float*)d_in[7];
    const float* g3 = (const float*)d_in[8];
    const float* b3 = (const float*)d_in[9];
    const float* Wm = (const float*)d_in[10];
    const float* bm = (const float*)d_in[11];
    const float* gm = (const float*)d_in[12];
    const float* betam = (const float*)d_in[13];

    float* out = (float*)d_out;
    float* x4 = out;
    float* featH = out + BATCH * 1024;

    char* ws = (char*)d_ws;
    size_t off = 0;
    auto alloc = [&](size_t bytes) -> void* {
        void* pp = ws + off;
        off += (bytes + 255) & ~(size_t)255;
        return pp;
    };
    double* xxb = (double*)alloc((size_t)BATCH * NPTS * 8);
    int* idx = (int*)alloc((size_t)BATCH * NPTS * KSEL * 4);
    int* flags = (int*)alloc((size_t)BATCH * NPTS * 4);
    float* featP = (float*)alloc((size_t)BATCH * 256 * NPTS * 4);
    float* pbuf = (float*)alloc((size_t)BATCH * NPTS * 128 * 4);
    float* rbuf = (float*)alloc((size_t)BATCH * NPTS * 128 * 4);
    float4* hilo = (float4*)alloc((size_t)BATCH * NPTS * 128 * 16);
    double* partials = (double*)alloc((size_t)(BATCH * NPTS / 4) * 4 * 8);
    float* msf = (float*)alloc(64 * 4);
    double* statsd = (double*)alloc(128 * 8);
    double* msd = (double*)alloc(128 * 8);
    unsigned* mmax = (unsigned*)alloc((size_t)BATCH * 1024 * 4);
    unsigned* mmin = (unsigned*)alloc((size_t)BATCH * 1024 * 4);
    size_t base = off;
    bool full = (ws_size >= base + (size_t)BATCH * NPTS * NPTS * 4);
    float* dist = (float*)alloc(full ? (size_t)BATCH * NPTS * NPTS * 4
                                     : (size_t)NPTS * NPTS * 4);

    hipMemsetAsync(statsd, 0, 128 * 8, stream);
    hipMemsetAsync(mmax, 0x00, (size_t)BATCH * 1024 * 4, stream);
    hipMemsetAsync(mmin, 0xFF, (size_t)BATCH * 1024 * 4, stream);

    run_layer<3, 64>(x, 3L * NPTS, W1, g1, b1, 0,
                     featP, featH, xxb, dist, full, idx, flags, pbuf, rbuf, hilo, partials, msf, stream);
    run_layer<64, 64>(featP, 256L * NPTS, W2, g2, b2, 64,
                      featP, featH, xxb, dist, full, idx, flags, pbuf, rbuf, hilo, partials, msf, stream);
    run_layer<64, 128>(featP + 64L * NPTS, 256L * NPTS, W3, g3, b3, 128,
                       featP, featH, xxb, dist, full, idx, flags, pbuf, rbuf, hilo, partials, msf, stream);

    mlp_gemm_kernel<<<dim3(32, 16, BATCH), 256, 0, stream>>>(featH, Wm, bm, mmax, mmin, statsd);
    finalize64_kernel<<<1, 64, 0, stream>>>(statsd, msd, 8, (double)(128L * NPTS));
    mlp_final_kernel<<<(BATCH * 1024 + 255) / 256, 256, 0, stream>>>(mmax, mmin, msd, gm, betam, x4);
    (void)in_sizes; (void)n_in; (void)out_size; (void)ws_size;
}

// Round 13
// 605.503 us; speedup vs baseline: 4.4301x; 1.1165x over previous
//
#include <hip/hip_runtime.h>
#include <hip/hip_bf16.h>

#define NPTS 2048
#define KNN 80
#define KSEL 81
#define BATCH 4

__device__ __forceinline__ unsigned f2key(float f) {
    unsigned u = __float_as_uint(f);
    return u ^ ((u & 0x80000000u) ? 0xFFFFFFFFu : 0x80000000u);
}
__device__ __forceinline__ float key2f(unsigned k) {
    unsigned u = (k & 0x80000000u) ? (k ^ 0x80000000u) : ~k;
    return __uint_as_float(u);
}

// ---------------- xx (fp64) ----------------
__global__ void xx64_kernel(const float* __restrict__ x, long sb, int C, double* __restrict__ xx) {
    int i = blockIdx.x * 256 + threadIdx.x;
    if (i >= BATCH * NPTS) return;
    int b = i / NPTS, n = i % NPTS;
    const float* xp = x + (long)b * sb + n;
    double s = 0.0;
    for (int c = 0; c < C; ++c) { double v = (double)xp[(long)c * NPTS]; s = fma(v, v, s); }
    xx[i] = s;
}

// ---------------- dist: fp32 accumulate, fp64 final combine -> fp32 ----------------
__global__ __launch_bounds__(256) void dist_kernel(
    const float* __restrict__ x, long sb, int C,
    const double* __restrict__ xx, float* __restrict__ dist, int b_base) {
    int bz = blockIdx.z;
    int b = b_base + bz;
    int i0 = blockIdx.y * 64, j0 = blockIdx.x * 64;
    __shared__ float xi[32][64];
    __shared__ float xj[32][64];
    const float* xb = x + (long)b * sb;
    int tid = threadIdx.x, tx = tid & 15, ty = tid >> 4;
    float acc[4][4] = {};
    for (int cc = 0; cc < C; cc += 32) {
        int Cc = C - cc; if (Cc > 32) Cc = 32;
        for (int t = tid; t < Cc * 64; t += 256) {
            int c = t >> 6, l = t & 63;
            xi[c][l] = xb[(long)(cc + c) * NPTS + i0 + l];
            xj[c][l] = xb[(long)(cc + c) * NPTS + j0 + l];
        }
        __syncthreads();
        for (int c = 0; c < Cc; ++c) {
            float a[4], bb[4];
#pragma unroll
            for (int u = 0; u < 4; ++u) a[u] = xi[c][ty * 4 + u];
#pragma unroll
            for (int v = 0; v < 4; ++v) bb[v] = xj[c][tx * 4 + v];
#pragma unroll
            for (int u = 0; u < 4; ++u)
#pragma unroll
                for (int v = 0; v < 4; ++v) acc[u][v] = fmaf(a[u], bb[v], acc[u][v]);
        }
        __syncthreads();
    }
    const double* xxb = xx + b * NPTS;
    float* drow = dist + (long)bz * NPTS * NPTS;
#pragma unroll
    for (int u = 0; u < 4; ++u) {
        int i = i0 + ty * 4 + u;
        double xxi = xxb[i];
#pragma unroll
        for (int v = 0; v < 4; ++v) {
            int j = j0 + tx * 4 + v;
            drow[(long)i * NPTS + j] = (float)(2.0 * (double)acc[u][v] - xxi - xxb[j]);
        }
    }
}

// ---------------- top-81: wave-per-row radix select, 4-copy histogram ----------------
__global__ __launch_bounds__(256) void topk_wave_kernel(
    const float* __restrict__ dist, int* __restrict__ idxout,
    int* __restrict__ flags, int b_base) {
    int bz = blockIdx.z;
    int b = b_base + bz;
    int tid = threadIdx.x;
    int lane = tid & 63, w = tid >> 6;
    int row = blockIdx.x * 4 + w;
    const float* dr = dist + ((long)bz * NPTS + row) * NPTS;

    unsigned kv[32];
#pragma unroll
    for (int i = 0; i < 8; ++i) {
        float4 a = *(const float4*)(dr + i * 256 + lane * 4);
        kv[i * 4 + 0] = f2key(a.x);
        kv[i * 4 + 1] = f2key(a.y);
        kv[i * 4 + 2] = f2key(a.z);
        kv[i * 4 + 3] = f2key(a.w);
    }

    __shared__ unsigned hist[4][256][4];   // [wave][bin][copy]
    __shared__ int sel_s[4][KSEL];
    __shared__ float selv_s[4][KSEL];

    unsigned prefix = 0;
    int rem = KSEL;
    int cp = lane & 3;

    for (int pass = 0; pass < 4; ++pass) {
        int shift = 24 - pass * 8;
        uint4* h4 = (uint4*)&hist[w][0][0];
#pragma unroll
        for (int t = 0; t < 4; ++t) h4[lane + t * 64] = make_uint4(0u, 0u, 0u, 0u);
        unsigned pm = (pass == 0) ? 0u : (0xFFFFFFFFu << (shift + 8));
#pragma unroll
        for (int u = 0; u < 32; ++u) {
            if ((kv[u] & pm) == prefix)
                atomicAdd(&hist[w][(kv[u] >> shift) & 255u][cp], 1u);
        }
        // scan: lane owns bins [lane*4, lane*4+4), each = sum of 4 copies
        uint4 c0 = h4[lane * 4 + 0];
        uint4 c1 = h4[lane * 4 + 1];
        uint4 c2 = h4[lane * 4 + 2];
        uint4 c3 = h4[lane * 4 + 3];
        unsigned b0 = c0.x + c0.y + c0.z + c0.w;
        unsigned b1 = c1.x + c1.y + c1.z + c1.w;
        unsigned b2 = c2.x + c2.y + c2.z + c2.w;
        unsigned b3 = c3.x + c3.y + c3.z + c3.w;
        unsigned loc3 = b3, loc2 = b3 + b2, loc1 = b3 + b2 + b1, loc0 = b3 + b2 + b1 + b0;
        unsigned tot = loc0;
        unsigned suf = tot;
#pragma unroll
        for (int d = 1; d < 64; d <<= 1) {
            unsigned o = __shfl_down(suf, d);
            suf += (lane + d < 64) ? o : 0u;
        }
        unsigned after = suf - tot;
        int fdig = -1, frem = 0;
        unsigned ge, gt;
        ge = loc0 + after; gt = loc1 + after;
        if (ge >= (unsigned)rem && gt < (unsigned)rem) { fdig = lane * 4 + 0; frem = rem - (int)gt; }
        ge = loc1 + after; gt = loc2 + after;
        if (ge >= (unsigned)rem && gt < (unsigned)rem) { fdig = lane * 4 + 1; frem = rem - (int)gt; }
        ge = loc2 + after; gt = loc3 + after;
        if (ge >= (unsigned)rem && gt < (unsigned)rem) { fdig = lane * 4 + 2; frem = rem - (int)gt; }
        ge = loc3 + after; gt = after;
        if (ge >= (unsigned)rem && gt < (unsigned)rem) { fdig = lane * 4 + 3; frem = rem - (int)gt; }
        unsigned long long bal = __ballot(fdig >= 0);
        int src = __ffsll((unsigned long long)bal) - 1;
        fdig = __shfl(fdig, src);
        frem = __shfl(frem, src);
        prefix |= ((unsigned)fdig) << shift;
        rem = frem;
    }

    // collection: strictly-greater keys, lane-major deterministic order
    int myc = 0;
#pragma unroll
    for (int u = 0; u < 32; ++u) myc += (kv[u] > prefix) ? 1 : 0;
    int inc = myc;
#pragma unroll
    for (int d = 1; d < 64; d <<= 1) {
        int o = __shfl_up(inc, d);
        inc += (lane >= d) ? o : 0;
    }
    int off = inc - myc;
    int pos = off;
#pragma unroll
    for (int u = 0; u < 32; ++u) {
        if (kv[u] > prefix) {
            int e = (u >> 2) * 256 + lane * 4 + (u & 3);
            sel_s[w][pos] = e;
            selv_s[w][pos] = key2f(kv[u]);
            ++pos;
        }
    }
    int cgt = __shfl(inc, 63);

    // ties: rem smallest element-indices among kv == prefix
    unsigned tmask = 0;
#pragma unroll
    for (int u = 0; u < 32; ++u)
        if (kv[u] == prefix) tmask |= (1u << u);
    float vtie = key2f(prefix);
    for (int t = 0; t < rem; ++t) {
        int best = 0x7FFFFFFF;
        unsigned m = tmask;
        while (m) {
            int u = __ffs(m) - 1;
            m &= m - 1;
            int e = (u >> 2) * 256 + lane * 4 + (u & 3);
            best = min(best, e);
        }
#pragma unroll
        for (int d = 32; d > 0; d >>= 1) best = min(best, __shfl_xor(best, d));
        if (((best >> 2) & 63) == lane) {
            int u = ((best >> 8) << 2) | (best & 3);
            tmask &= ~(1u << u);
        }
        if (lane == 0) { sel_s[w][cgt + t] = best; selv_s[w][cgt + t] = vtie; }
    }

    // rank-81 = min under (key asc, idx desc); rank-80 = 2nd min
    unsigned bk = 0xFFFFFFFFu; int bi = -1, bp = -1;
    if (lane < KSEL) { bk = f2key(selv_s[w][lane]); bi = sel_s[w][lane]; bp = lane; }
    int l2 = lane + 64;
    if (l2 < KSEL) {
        unsigned k2 = f2key(selv_s[w][l2]); int i2 = sel_s[w][l2];
        if (k2 < bk || (k2 == bk && i2 > bi)) { bk = k2; bi = i2; bp = l2; }
    }
#pragma unroll
    for (int d = 32; d > 0; d >>= 1) {
        unsigned ok = __shfl_xor(bk, d);
        int oi = __shfl_xor(bi, d);
        int op = __shfl_xor(bp, d);
        if (ok < bk || (ok == bk && oi > bi)) { bk = ok; bi = oi; bp = op; }
    }
    int p81 = bp;
    bk = 0xFFFFFFFFu; bi = -1; bp = -1;
    if (lane < KSEL && lane != p81) { bk = f2key(selv_s[w][lane]); bi = sel_s[w][lane]; bp = lane; }
    if (l2 < KSEL && l2 != p81) {
        unsigned k2 = f2key(selv_s[w][l2]); int i2 = sel_s[w][l2];
        if (k2 < bk || (k2 == bk && i2 > bi)) { bk = k2; bi = i2; bp = l2; }
    }
#pragma unroll
    for (int d = 32; d > 0; d >>= 1) {
        unsigned ok = __shfl_xor(bk, d);
        int oi = __shfl_xor(bi, d);
        int op = __shfl_xor(bp, d);
        if (ok < bk || (ok == bk && oi > bi)) { bk = ok; bi = oi; bp = op; }
    }
    int p80 = bp;

    if (lane == 0) {
        int ts; float tv;
        ts = sel_s[w][80]; sel_s[w][80] = sel_s[w][p81]; sel_s[w][p81] = ts;
        tv = selv_s[w][80]; selv_s[w][80] = selv_s[w][p81]; selv_s[w][p81] = tv;
        if (p80 == 80) p80 = p81;
        ts = sel_s[w][79]; sel_s[w][79] = sel_s[w][p80]; sel_s[w][p80] = ts;
        tv = selv_s[w][79]; selv_s[w][79] = selv_s[w][p80]; selv_s[w][p80] = tv;
        float d80f = selv_s[w][79], d81f = selv_s[w][80];
        float eta = 8e-5f + 4e-6f * fabsf(d80f);
        flags[b * NPTS + row] = ((d80f - d81f) <= eta) ? 1 : 0;
    }
    int* outp = idxout + ((long)b * NPTS + row) * KSEL;
    for (int t = lane; t < KSEL; t += 64) outp[t] = sel_s[w][t];
}

// ---------------- p/r projections ----------------
template<int C, int O>
__global__ __launch_bounds__(256) void pr_kernel(
    const float* __restrict__ x, long sb, const float* __restrict__ W,
    float* __restrict__ p, float* __restrict__ r) {
    __shared__ float wp[C * O];
    __shared__ float wr[C * O];
    __shared__ float xs[C][32];
    int nb = NPTS / 32;
    int b = blockIdx.x / nb;
    int n0 = (blockIdx.x % nb) * 32;
    int tid = threadIdx.x;
    for (int t = tid; t < C * O; t += 256) {
        int o = t / C, c = t % C;
        float w1 = W[o * 2 * C + c];
        wp[o * C + c] = w1;
        wr[o * C + c] = W[o * 2 * C + C + c] - w1;
    }
    const float* xb = x + (long)b * sb;
    for (int t = tid; t < C * 32; t += 256) {
        int c = t / 32, nn = t & 31;
        xs[c][nn] = xb[(long)c * NPTS + n0 + nn];
    }
    __syncthreads();
    int o = tid % O;
    int nl0 = tid / O, per = 256 / O;
    for (int nl = nl0; nl < 32; nl += per) {
        float pa = 0.f, ra = 0.f;
        for (int c = 0; c < C; ++c) {
            float xv = xs[c][nl];
            pa = fmaf(wp[o * C + c], xv, pa);
            ra = fmaf(wr[o * C + c], xv, ra);
        }
        long po = ((long)b * NPTS + n0 + nl) * O + o;
        p[po] = pa;
        r[po] = ra;
    }
}

// ---------------- FUSED gather: fp32 dual accumulators, kk unrolled x4 ----------------
template<int O>
__global__ __launch_bounds__(256) void gather_kernel(
    const float* __restrict__ p, const float* __restrict__ r,
    const int* __restrict__ idx, float4* __restrict__ hilo,
    double* __restrict__ partials) {
    const int NT = 4;
    const int R = (NT * O) / 256;
    const int STEP = 256 / O;
    __shared__ float r_s[NT * O];
    __shared__ int idx_s[NT * KSEL];
    __shared__ double gs8[8], gq8[8];
    int nb = NPTS / NT;
    int b = blockIdx.x / nb;
    int n0 = (blockIdx.x % nb) * NT;
    int tid = threadIdx.x;
    for (int t = tid; t < NT * O; t += 256) r_s[t] = r[((long)b * NPTS + n0) * O + t];
    for (int t = tid; t < NT * KSEL; t += 256) idx_s[t] = idx[((long)b * NPTS + n0) * KSEL + t];
    __syncthreads();
    int o = tid % O;
    int nlb = tid / O;
    const float* pb = p + (long)b * NPTS * O;
    float hi[R], lo[R], ha[R], hb[R], rv[R];
    int nlr[R];
#pragma unroll
    for (int u = 0; u < R; ++u) {
        nlr[u] = nlb + u * STEP;
        rv[u] = r_s[nlr[u] * O + o];
        hi[u] = -3.0e38f; lo[u] = 3.0e38f;
    }
    float s0 = 0.f, s1 = 0.f, q0 = 0.f, q1 = 0.f;
    int kk = 0;
    for (; kk + 3 < KNN - 1; kk += 4) {
        int j0[R], j1[R], j2[R], j3[R];
#pragma unroll
        for (int u = 0; u < R; ++u) {
            const int* ip = &idx_s[nlr[u] * KSEL + kk];
            j0[u] = ip[0]; j1[u] = ip[1]; j2[u] = ip[2]; j3[u] = ip[3];
        }
#pragma unroll
        for (int u = 0; u < R; ++u) {
            float h0 = pb[(long)j0[u] * O + o] + rv[u];
            float h1 = pb[(long)j1[u] * O + o] + rv[u];
            float h2 = pb[(long)j2[u] * O + o] + rv[u];
            float h3 = pb[(long)j3[u] * O + o] + rv[u];
            hi[u] = fmaxf(hi[u], fmaxf(fmaxf(h0, h1), fmaxf(h2, h3)));
            lo[u] = fminf(lo[u], fminf(fminf(h0, h1), fminf(h2, h3)));
            s0 += h0 + h2;
            s1 += h1 + h3;
            q0 = fmaf(h0, h0, q0); q0 = fmaf(h2, h2, q0);
            q1 = fmaf(h1, h1, q1); q1 = fmaf(h3, h3, q1);
        }
    }
    for (; kk < KNN - 1; ++kk) {
#pragma unroll
        for (int u = 0; u < R; ++u) {
            int j = idx_s[nlr[u] * KSEL + kk];
            float h = pb[(long)j * O + o] + rv[u];
            hi[u] = fmaxf(hi[u], h);
            lo[u] = fminf(lo[u], h);
            s0 += h;
            q0 = fmaf(h, h, q0);
        }
    }
#pragma unroll
    for (int u = 0; u < R; ++u) {
        int j = idx_s[nlr[u] * KSEL + (KNN - 1)];
        ha[u] = pb[(long)j * O + o] + rv[u];
        s0 += ha[u];
        q0 = fmaf(ha[u], ha[u], q0);
        int j2 = idx_s[nlr[u] * KSEL + KNN];
        hb[u] = pb[(long)j2 * O + o] + rv[u];
    }
#pragma unroll
    for (int u = 0; u < R; ++u)
        hilo[((long)b * NPTS + n0 + nlr[u]) * O + o] = make_float4(hi[u], lo[u], ha[u], hb[u]);
    double s = (double)s0 + (double)s1;
    double q = (double)q0 + (double)q1;
    for (int off = 16; off > 0; off >>= 1) {
        s += __shfl_xor(s, off);
        q += __shfl_xor(q, off);
    }
    int hw = tid >> 5;
    if ((tid & 31) == 0) { gs8[hw] = s; gq8[hw] = q; }
    __syncthreads();
    if (tid < 2) {
        double ss = 0.0, qq = 0.0;
        for (int h2 = 0; h2 < 8; ++h2) {
            int o0 = (h2 * 32) % O;
            int g = o0 / (O / 2);
            if (g == tid) { ss += gs8[h2]; qq += gq8[h2]; }
        }
        partials[(long)blockIdx.x * 4 + tid * 2 + 0] = ss;
        partials[(long)blockIdx.x * 4 + tid * 2 + 1] = qq;
    }
}

__global__ void reduce_stats(const double* __restrict__ partials, int nblkb, double M,
                             float* __restrict__ ms) {
    int i = threadIdx.x;
    if (i >= BATCH * 2) return;
    int b = i >> 1, g = i & 1;
    double s = 0.0, q = 0.0;
    for (int t = 0; t < nblkb; ++t) {
        long blk = (long)b * nblkb + t;
        s += partials[blk * 4 + g * 2 + 0];
        q += partials[blk * 4 + g * 2 + 1];
    }
    double mean = s / M;
    double var = q / M - mean * mean;
    ms[i * 2 + 0] = (float)mean;
    ms[i * 2 + 1] = (float)(1.0 / sqrt(var + 1e-5));
}

// ---------------- finalize: normalize extremes + leaky + hedge -> feat ----------------
template<int O>
__global__ __launch_bounds__(256) void finalize_kernel(
    const float4* __restrict__ hilo, const int* __restrict__ flags,
    const float* __restrict__ ms, const float* __restrict__ gamma, const float* __restrict__ beta,
    float* __restrict__ featP, float* __restrict__ featH, int coff) {
    const int NT = 16;
    __shared__ float smP[O * NT], smH[O * NT];
    __shared__ float sc_s[O], sh_s[O];
    __shared__ int flag_s[NT];
    int nb = NPTS / NT;
    int b = blockIdx.x / nb;
    int n0 = (blockIdx.x % nb) * NT;
    int tid = threadIdx.x;
    if (tid < NT) flag_s[tid] = flags[b * NPTS + n0 + tid];
    if (tid < O) {
        int g = tid / (O / 2);
        float mean = ms[(b * 2 + g) * 2 + 0], rstd = ms[(b * 2 + g) * 2 + 1];
        float sc = rstd * gamma[tid];
        sc_s[tid] = sc;
        sh_s[tid] = beta[tid] - mean * sc;
    }
    __syncthreads();
    int o = tid % O;
    int nl0 = tid / O, nrep = 256 / O;
    float sc = sc_s[o], sh = sh_s[o];
    bool pos = (sc >= 0.f);
    for (int nl = nl0; nl < NT; nl += nrep) {
        float4 v = hilo[((long)b * NPTS + n0 + nl) * O + o];
        float h0 = pos ? fmaxf(v.x, v.z) : fminf(v.y, v.z);
        float h1 = pos ? fmaxf(v.x, v.w) : fminf(v.y, v.w);
        float v0 = h0 * sc + sh; v0 = v0 >= 0.f ? v0 : 0.2f * v0;
        float v1 = h1 * sc + sh; v1 = v1 >= 0.f ? v1 : 0.2f * v1;
        float outv = v0;
        if (flag_s[nl] && fabsf(v0 - v1) <= 0.45f) outv = 0.5f * (v0 + v1);
        smP[o * NT + nl] = v0;
        smH[o * NT + nl] = outv;
    }
    __syncthreads();
    long obase = ((long)b * 256 + coff) * NPTS + n0;
    for (int i = tid; i < O * NT; i += 256) {
        int oo = i / NT, nl = i % NT;
        featP[obase + (long)oo * NPTS + nl] = smP[i];
        featH[obase + (long)oo * NPTS + nl] = smH[i];
    }
}

// ---------------- MLP GEMM: 64o x 128n tile, 4x8/thread, kc=32, fused max/min+stats ----------------
__global__ __launch_bounds__(256) void mlp_gemm_kernel(
    const float* __restrict__ xf, const float* __restrict__ Wm, const float* __restrict__ bm,
    unsigned* __restrict__ mmax, unsigned* __restrict__ mmin, double* __restrict__ stats) {
    int b = blockIdx.z;
    int o0 = blockIdx.y * 64, n0 = blockIdx.x * 128;
    __shared__ float wm_sT[32][68];   // [c][o]
    __shared__ float xf_s[32][128];   // [c][n]
    int tid = threadIdx.x;
    int tx = tid & 15, ty = tid >> 4;
    float acc[4][8] = {};
    for (int kc = 0; kc < 256; kc += 32) {
        for (int i = tid; i < 64 * 32; i += 256) {
            int row = i >> 5, col = i & 31;  // row=o, col=c
            wm_sT[col][row] = Wm[(long)(o0 + row) * 256 + kc + col];
        }
        for (int i = tid; i < 32 * 128; i += 256) {
            int row = i >> 7, col = i & 127;  // row=c, col=n
            xf_s[row][col] = xf[(long)b * 256 * NPTS + (long)(kc + row) * NPTS + n0 + col];
        }
        __syncthreads();
        for (int c = 0; c < 32; ++c) {
            float a[4];
#pragma unroll
            for (int u = 0; u < 4; ++u) a[u] = wm_sT[c][ty * 4 + u];
            float4 bA = *(const float4*)&xf_s[c][tx * 4];
            float4 bB = *(const float4*)&xf_s[c][64 + tx * 4];
            float bb[8] = {bA.x, bA.y, bA.z, bA.w, bB.x, bB.y, bB.z, bB.w};
#pragma unroll
            for (int u = 0; u < 4; ++u)
#pragma unroll
                for (int v = 0; v < 8; ++v) acc[u][v] = fmaf(a[u], bb[v], acc[u][v]);
        }
        __syncthreads();
    }
    double s = 0.0, q = 0.0;
#pragma unroll
    for (int u = 0; u < 4; ++u) {
        int o = o0 + ty * 4 + u;
        float bv = bm[o];
        float mx = -3.0e38f, mn = 3.0e38f;
#pragma unroll
        for (int v = 0; v < 8; ++v) {
            float hv = acc[u][v] + bv;
            mx = fmaxf(mx, hv);
            mn = fminf(mn, hv);
            s += (double)hv;
            q += (double)hv * (double)hv;
        }
        for (int d = 1; d < 16; d <<= 1) {
            mx = fmaxf(mx, __shfl_xor(mx, d));
            mn = fminf(mn, __shfl_xor(mn, d));
        }
        if (tx == 0) {
            atomicMax(&mmax[((long)b << 10) + o], f2key(mx));
            atomicMin(&mmin[((long)b << 10) + o], f2key(mn));
        }
    }
    for (int off = 32; off > 0; off >>= 1) {
        s += __shfl_xor(s, off);
        q += __shfl_xor(q, off);
    }
    __shared__ double rs[4], rq[4];
    int wid = tid >> 6;
    if ((tid & 63) == 0) { rs[wid] = s; rq[wid] = q; }
    __syncthreads();
    if (tid == 0) {
        s = rs[0] + rs[1] + rs[2] + rs[3];
        q = rq[0] + rq[1] + rq[2] + rq[3];
        int g = o0 / 128;
        atomicAdd(&stats[(b * 8 + g) * 2 + 0], s);
        atomicAdd(&stats[(b * 8 + g) * 2 + 1], q);
    }
}

__global__ void finalize64_kernel(const double* __restrict__ st, double* __restrict__ msout,
                                  int G, double M) {
    int i = threadIdx.x;
    if (i >= BATCH * G) return;
    double s = st[i * 2], q = st[i * 2 + 1];
    double mean = s / M;
    double var = q / M - mean * mean;
    msout[i * 2] = mean;
    msout[i * 2 + 1] = 1.0 / sqrt(var + 1e-5);
}

__global__ void mlp_final_kernel(
    const unsigned* __restrict__ mmax, const unsigned* __restrict__ mmin,
    const double* __restrict__ ms, const float* __restrict__ gm,
    const float* __restrict__ betam, float* __restrict__ x4) {
    int i = blockIdx.x * 256 + threadIdx.x;
    if (i >= BATCH * 1024) return;
    int b = i >> 10, o = i & 1023;
    int g = o >> 7;
    float mean = (float)ms[(b * 8 + g) * 2], rstd = (float)ms[(b * 8 + g) * 2 + 1];
    float sc = rstd * gm[o], sh = betam[o] - mean * sc;
    float hsel = (sc >= 0.f) ? key2f(mmax[i]) : key2f(mmin[i]);
    x4[i] = fmaxf(hsel * sc + sh, 0.f);
}

template<int C, int O>
static void run_layer(const float* xin, long sb, const float* W,
                      const float* gamma, const float* beta, int coff,
                      float* featP, float* featH,
                      double* xxb, float* dist, bool full, int* idx, int* flags,
                      float* pbuf, float* rbuf, float4* hilo,
                      double* partials, float* msf, hipStream_t stream) {
    xx64_kernel<<<(BATCH * NPTS + 255) / 256, 256, 0, stream>>>(xin, sb, C, xxb);
    if (full) {
        dist_kernel<<<dim3(32, 32, BATCH), 256, 0, stream>>>(xin, sb, C, xxb, dist, 0);
        topk_wave_kernel<<<dim3(NPTS / 4, 1, BATCH), 256, 0, stream>>>(dist, idx, flags, 0);
    } else {
        for (int b = 0; b < BATCH; ++b) {
            dist_kernel<<<dim3(32, 32, 1), 256, 0, stream>>>(xin, sb, C, xxb, dist, b);
            topk_wave_kernel<<<dim3(NPTS / 4, 1, 1), 256, 0, stream>>>(dist, idx, flags, b);
        }
    }
    pr_kernel<C, O><<<BATCH * NPTS / 32, 256, 0, stream>>>(xin, sb, W, pbuf, rbuf);
    gather_kernel<O><<<BATCH * NPTS / 4, 256, 0, stream>>>(pbuf, rbuf, idx, hilo, partials);
    double M = (double)((long)(O / 2) * NPTS * KNN);
    reduce_stats<<<1, 64, 0, stream>>>(partials, NPTS / 4, M, msf);
    finalize_kernel<O><<<BATCH * NPTS / 16, 256, 0, stream>>>(hilo, flags, msf,
                                                              gamma, beta, featP, featH, coff);
}

extern "C" void kernel_launch(void* const* d_in, const int* in_sizes, int n_in,
                              void* d_out, int out_size, void* d_ws, size_t ws_size,
                              hipStream_t stream) {
    const float* x = (const float*)d_in[0];
    const float* W1 = (const float*)d_in[1];
    const float* g1 = (const float*)d_in[2];
    const float* b1 = (const float*)d_in[3];
    const float* W2 = (const float*)d_in[4];
    const float* g2 = (const float*)d_in[5];
    const float* b2 = (const float*)d_in[6];
    const float* W3 = (const float*)d_in[7];
    const float* g3 = (const float*)d_in[8];
    const float* b3 = (const float*)d_in[9];
    const float* Wm = (const float*)d_in[10];
    const float* bm = (const float*)d_in[11];
    const float* gm = (const float*)d_in[12];
    const float* betam = (const float*)d_in[13];

    float* out = (float*)d_out;
    float* x4 = out;
    float* featH = out + BATCH * 1024;

    char* ws = (char*)d_ws;
    size_t off = 0;
    auto alloc = [&](size_t bytes) -> void* {
        void* pp = ws + off;
        off += (bytes + 255) & ~(size_t)255;
        return pp;
    };
    double* xxb = (double*)alloc((size_t)BATCH * NPTS * 8);
    int* idx = (int*)alloc((size_t)BATCH * NPTS * KSEL * 4);
    int* flags = (int*)alloc((size_t)BATCH * NPTS * 4);
    float* featP = (float*)alloc((size_t)BATCH * 256 * NPTS * 4);
    float* pbuf = (float*)alloc((size_t)BATCH * NPTS * 128 * 4);
    float* rbuf = (float*)alloc((size_t)BATCH * NPTS * 128 * 4);
    float4* hilo = (float4*)alloc((size_t)BATCH * NPTS * 128 * 16);
    double* partials = (double*)alloc((size_t)(BATCH * NPTS / 4) * 4 * 8);
    float* msf = (float*)alloc(64 * 4);
    double* statsd = (double*)alloc(128 * 8);
    double* msd = (double*)alloc(128 * 8);
    unsigned* mmax = (unsigned*)alloc((size_t)BATCH * 1024 * 4);
    unsigned* mmin = (unsigned*)alloc((size_t)BATCH * 1024 * 4);
    size_t base = off;
    bool full = (ws_size >= base + (size_t)BATCH * NPTS * NPTS * 4);
    float* dist = (float*)alloc(full ? (size_t)BATCH * NPTS * NPTS * 4
                                     : (size_t)NPTS * NPTS * 4);

    hipMemsetAsync(statsd, 0, 128 * 8, stream);
    hipMemsetAsync(mmax, 0x00, (size_t)BATCH * 1024 * 4, stream);
    hipMemsetAsync(mmin, 0xFF, (size_t)BATCH * 1024 * 4, stream);

    run_layer<3, 64>(x, 3L * NPTS, W1, g1, b1, 0,
                     featP, featH, xxb, dist, full, idx, flags, pbuf, rbuf, hilo, partials, msf, stream);
    run_layer<64, 64>(featP, 256L * NPTS, W2, g2, b2, 64,
                      featP, featH, xxb, dist, full, idx, flags, pbuf, rbuf, hilo, partials, msf, stream);
    run_layer<64, 128>(featP + 64L * NPTS, 256L * NPTS, W3, g3, b3, 128,
                       featP, featH, xxb, dist, full, idx, flags, pbuf, rbuf, hilo, partials, msf, stream);

    mlp_gemm_kernel<<<dim3(16, 16, BATCH), 256, 0, stream>>>(featH, Wm, bm, mmax, mmin, statsd);
    finalize64_kernel<<<1, 64, 0, stream>>>(statsd, msd, 8, (double)(128L * NPTS));
    mlp_final_kernel<<<(BATCH * 1024 + 255) / 256, 256, 0, stream>>>(mmax, mmin, msd, gm, betam, x4);
    (void)in_sizes; (void)n_in; (void)out_size; (void)ws_size;
}

// Round 14
// 593.313 us; speedup vs baseline: 4.5212x; 1.0205x over previous
//
#include <hip/hip_runtime.h>
#include <hip/hip_bf16.h>

#define NPTS 2048
#define KNN 80
#define KSEL 81
#define BATCH 4

__device__ __forceinline__ unsigned f2key(float f) {
    unsigned u = __float_as_uint(f);
    return u ^ ((u & 0x80000000u) ? 0xFFFFFFFFu : 0x80000000u);
}
__device__ __forceinline__ float key2f(unsigned k) {
    unsigned u = (k & 0x80000000u) ? (k ^ 0x80000000u) : ~k;
    return __uint_as_float(u);
}

// ---------------- xx (fp64) ----------------
__global__ void xx64_kernel(const float* __restrict__ x, long sb, int C, double* __restrict__ xx) {
    int i = blockIdx.x * 256 + threadIdx.x;
    if (i >= BATCH * NPTS) return;
    int b = i / NPTS, n = i % NPTS;
    const float* xp = x + (long)b * sb + n;
    double s = 0.0;
    for (int c = 0; c < C; ++c) { double v = (double)xp[(long)c * NPTS]; s = fma(v, v, s); }
    xx[i] = s;
}

// ---------------- dist: fp32 accumulate, fp64 final combine -> fp32 ----------------
__global__ __launch_bounds__(256) void dist_kernel(
    const float* __restrict__ x, long sb, int C,
    const double* __restrict__ xx, float* __restrict__ dist, int b_base) {
    int bz = blockIdx.z;
    int b = b_base + bz;
    int i0 = blockIdx.y * 64, j0 = blockIdx.x * 64;
    __shared__ float xi[32][64];
    __shared__ float xj[32][64];
    const float* xb = x + (long)b * sb;
    int tid = threadIdx.x, tx = tid & 15, ty = tid >> 4;
    float acc[4][4] = {};
    for (int cc = 0; cc < C; cc += 32) {
        int Cc = C - cc; if (Cc > 32) Cc = 32;
        for (int t = tid; t < Cc * 64; t += 256) {
            int c = t >> 6, l = t & 63;
            xi[c][l] = xb[(long)(cc + c) * NPTS + i0 + l];
            xj[c][l] = xb[(long)(cc + c) * NPTS + j0 + l];
        }
        __syncthreads();
        for (int c = 0; c < Cc; ++c) {
            float a[4], bb[4];
#pragma unroll
            for (int u = 0; u < 4; ++u) a[u] = xi[c][ty * 4 + u];
#pragma unroll
            for (int v = 0; v < 4; ++v) bb[v] = xj[c][tx * 4 + v];
#pragma unroll
            for (int u = 0; u < 4; ++u)
#pragma unroll
                for (int v = 0; v < 4; ++v) acc[u][v] = fmaf(a[u], bb[v], acc[u][v]);
        }
        __syncthreads();
    }
    const double* xxb = xx + b * NPTS;
    float* drow = dist + (long)bz * NPTS * NPTS;
#pragma unroll
    for (int u = 0; u < 4; ++u) {
        int i = i0 + ty * 4 + u;
        double xxi = xxb[i];
#pragma unroll
        for (int v = 0; v < 4; ++v) {
            int j = j0 + tx * 4 + v;
            drow[(long)i * NPTS + j] = (float)(2.0 * (double)acc[u][v] - xxi - xxb[j]);
        }
    }
}

// ---------------- top-81: wave-per-row radix select, 4-copy histogram ----------------
__global__ __launch_bounds__(256) void topk_wave_kernel(
    const float* __restrict__ dist, int* __restrict__ idxout,
    int* __restrict__ flags, int b_base) {
    int bz = blockIdx.z;
    int b = b_base + bz;
    int tid = threadIdx.x;
    int lane = tid & 63, w = tid >> 6;
    int row = blockIdx.x * 4 + w;
    const float* dr = dist + ((long)bz * NPTS + row) * NPTS;

    unsigned kv[32];
#pragma unroll
    for (int i = 0; i < 8; ++i) {
        float4 a = *(const float4*)(dr + i * 256 + lane * 4);
        kv[i * 4 + 0] = f2key(a.x);
        kv[i * 4 + 1] = f2key(a.y);
        kv[i * 4 + 2] = f2key(a.z);
        kv[i * 4 + 3] = f2key(a.w);
    }

    __shared__ unsigned hist[4][256][4];   // [wave][bin][copy]
    __shared__ int sel_s[4][KSEL];
    __shared__ float selv_s[4][KSEL];

    unsigned prefix = 0;
    int rem = KSEL;
    int cp = lane & 3;

    for (int pass = 0; pass < 4; ++pass) {
        int shift = 24 - pass * 8;
        uint4* h4 = (uint4*)&hist[w][0][0];
#pragma unroll
        for (int t = 0; t < 4; ++t) h4[lane + t * 64] = make_uint4(0u, 0u, 0u, 0u);
        unsigned pm = (pass == 0) ? 0u : (0xFFFFFFFFu << (shift + 8));
#pragma unroll
        for (int u = 0; u < 32; ++u) {
            if ((kv[u] & pm) == prefix)
                atomicAdd(&hist[w][(kv[u] >> shift) & 255u][cp], 1u);
        }
        uint4 c0 = h4[lane * 4 + 0];
        uint4 c1 = h4[lane * 4 + 1];
        uint4 c2 = h4[lane * 4 + 2];
        uint4 c3 = h4[lane * 4 + 3];
        unsigned b0 = c0.x + c0.y + c0.z + c0.w;
        unsigned b1 = c1.x + c1.y + c1.z + c1.w;
        unsigned b2 = c2.x + c2.y + c2.z + c2.w;
        unsigned b3 = c3.x + c3.y + c3.z + c3.w;
        unsigned loc3 = b3, loc2 = b3 + b2, loc1 = b3 + b2 + b1, loc0 = b3 + b2 + b1 + b0;
        unsigned tot = loc0;
        unsigned suf = tot;
#pragma unroll
        for (int d = 1; d < 64; d <<= 1) {
            unsigned o = __shfl_down(suf, d);
            suf += (lane + d < 64) ? o : 0u;
        }
        unsigned after = suf - tot;
        int fdig = -1, frem = 0;
        unsigned ge, gt;
        ge = loc0 + after; gt = loc1 + after;
        if (ge >= (unsigned)rem && gt < (unsigned)rem) { fdig = lane * 4 + 0; frem = rem - (int)gt; }
        ge = loc1 + after; gt = loc2 + after;
        if (ge >= (unsigned)rem && gt < (unsigned)rem) { fdig = lane * 4 + 1; frem = rem - (int)gt; }
        ge = loc2 + after; gt = loc3 + after;
        if (ge >= (unsigned)rem && gt < (unsigned)rem) { fdig = lane * 4 + 2; frem = rem - (int)gt; }
        ge = loc3 + after; gt = after;
        if (ge >= (unsigned)rem && gt < (unsigned)rem) { fdig = lane * 4 + 3; frem = rem - (int)gt; }
        unsigned long long bal = __ballot(fdig >= 0);
        int src = __ffsll((unsigned long long)bal) - 1;
        fdig = __shfl(fdig, src);
        frem = __shfl(frem, src);
        prefix |= ((unsigned)fdig) << shift;
        rem = frem;
    }

    int myc = 0;
#pragma unroll
    for (int u = 0; u < 32; ++u) myc += (kv[u] > prefix) ? 1 : 0;
    int inc = myc;
#pragma unroll
    for (int d = 1; d < 64; d <<= 1) {
        int o = __shfl_up(inc, d);
        inc += (lane >= d) ? o : 0;
    }
    int off = inc - myc;
    int pos = off;
#pragma unroll
    for (int u = 0; u < 32; ++u) {
        if (kv[u] > prefix) {
            int e = (u >> 2) * 256 + lane * 4 + (u & 3);
            sel_s[w][pos] = e;
            selv_s[w][pos] = key2f(kv[u]);
            ++pos;
        }
    }
    int cgt = __shfl(inc, 63);

    unsigned tmask = 0;
#pragma unroll
    for (int u = 0; u < 32; ++u)
        if (kv[u] == prefix) tmask |= (1u << u);
    float vtie = key2f(prefix);
    for (int t = 0; t < rem; ++t) {
        int best = 0x7FFFFFFF;
        unsigned m = tmask;
        while (m) {
            int u = __ffs(m) - 1;
            m &= m - 1;
            int e = (u >> 2) * 256 + lane * 4 + (u & 3);
            best = min(best, e);
        }
#pragma unroll
        for (int d = 32; d > 0; d >>= 1) best = min(best, __shfl_xor(best, d));
        if (((best >> 2) & 63) == lane) {
            int u = ((best >> 8) << 2) | (best & 3);
            tmask &= ~(1u << u);
        }
        if (lane == 0) { sel_s[w][cgt + t] = best; selv_s[w][cgt + t] = vtie; }
    }

    unsigned bk = 0xFFFFFFFFu; int bi = -1, bp = -1;
    if (lane < KSEL) { bk = f2key(selv_s[w][lane]); bi = sel_s[w][lane]; bp = lane; }
    int l2 = lane + 64;
    if (l2 < KSEL) {
        unsigned k2 = f2key(selv_s[w][l2]); int i2 = sel_s[w][l2];
        if (k2 < bk || (k2 == bk && i2 > bi)) { bk = k2; bi = i2; bp = l2; }
    }
#pragma unroll
    for (int d = 32; d > 0; d >>= 1) {
        unsigned ok = __shfl_xor(bk, d);
        int oi = __shfl_xor(bi, d);
        int op = __shfl_xor(bp, d);
        if (ok < bk || (ok == bk && oi > bi)) { bk = ok; bi = oi; bp = op; }
    }
    int p81 = bp;
    bk = 0xFFFFFFFFu; bi = -1; bp = -1;
    if (lane < KSEL && lane != p81) { bk = f2key(selv_s[w][lane]); bi = sel_s[w][lane]; bp = lane; }
    if (l2 < KSEL && l2 != p81) {
        unsigned k2 = f2key(selv_s[w][l2]); int i2 = sel_s[w][l2];
        if (k2 < bk || (k2 == bk && i2 > bi)) { bk = k2; bi = i2; bp = l2; }
    }
#pragma unroll
    for (int d = 32; d > 0; d >>= 1) {
        unsigned ok = __shfl_xor(bk, d);
        int oi = __shfl_xor(bi, d);
        int op = __shfl_xor(bp, d);
        if (ok < bk || (ok == bk && oi > bi)) { bk = ok; bi = oi; bp = op; }
    }
    int p80 = bp;

    if (lane == 0) {
        int ts; float tv;
        ts = sel_s[w][80]; sel_s[w][80] = sel_s[w][p81]; sel_s[w][p81] = ts;
        tv = selv_s[w][80]; selv_s[w][80] = selv_s[w][p81]; selv_s[w][p81] = tv;
        if (p80 == 80) p80 = p81;
        ts = sel_s[w][79]; sel_s[w][79] = sel_s[w][p80]; sel_s[w][p80] = ts;
        tv = selv_s[w][79]; selv_s[w][79] = selv_s[w][p80]; selv_s[w][p80] = tv;
        float d80f = selv_s[w][79], d81f = selv_s[w][80];
        float eta = 8e-5f + 4e-6f * fabsf(d80f);
        flags[b * NPTS + row] = ((d80f - d81f) <= eta) ? 1 : 0;
    }
    int* outp = idxout + ((long)b * NPTS + row) * KSEL;
    for (int t = lane; t < KSEL; t += 64) outp[t] = sel_s[w][t];
}

// ---------------- p/r projections ----------------
template<int C, int O>
__global__ __launch_bounds__(256) void pr_kernel(
    const float* __restrict__ x, long sb, const float* __restrict__ W,
    float* __restrict__ p, float* __restrict__ r) {
    __shared__ float wp[C * O];
    __shared__ float wr[C * O];
    __shared__ float xs[C][32];
    int nb = NPTS / 32;
    int b = blockIdx.x / nb;
    int n0 = (blockIdx.x % nb) * 32;
    int tid = threadIdx.x;
    for (int t = tid; t < C * O; t += 256) {
        int o = t / C, c = t % C;
        float w1 = W[o * 2 * C + c];
        wp[o * C + c] = w1;
        wr[o * C + c] = W[o * 2 * C + C + c] - w1;
    }
    const float* xb = x + (long)b * sb;
    for (int t = tid; t < C * 32; t += 256) {
        int c = t / 32, nn = t & 31;
        xs[c][nn] = xb[(long)c * NPTS + n0 + nn];
    }
    __syncthreads();
    int o = tid % O;
    int nl0 = tid / O, per = 256 / O;
    for (int nl = nl0; nl < 32; nl += per) {
        float pa = 0.f, ra = 0.f;
        for (int c = 0; c < C; ++c) {
            float xv = xs[c][nl];
            pa = fmaf(wp[o * C + c], xv, pa);
            ra = fmaf(wr[o * C + c], xv, ra);
        }
        long po = ((long)b * NPTS + n0 + nl) * O + o;
        p[po] = pa;
        r[po] = ra;
    }
}

// ---------------- FUSED gather: fp32 dual accumulators, kk unrolled x4 ----------------
template<int O>
__global__ __launch_bounds__(256) void gather_kernel(
    const float* __restrict__ p, const float* __restrict__ r,
    const int* __restrict__ idx, float4* __restrict__ hilo,
    double* __restrict__ partials) {
    const int NT = 4;
    const int R = (NT * O) / 256;
    const int STEP = 256 / O;
    __shared__ float r_s[NT * O];
    __shared__ int idx_s[NT * KSEL];
    __shared__ double gs8[8], gq8[8];
    int nb = NPTS / NT;
    int b = blockIdx.x / nb;
    int n0 = (blockIdx.x % nb) * NT;
    int tid = threadIdx.x;
    for (int t = tid; t < NT * O; t += 256) r_s[t] = r[((long)b * NPTS + n0) * O + t];
    for (int t = tid; t < NT * KSEL; t += 256) idx_s[t] = idx[((long)b * NPTS + n0) * KSEL + t];
    __syncthreads();
    int o = tid % O;
    int nlb = tid / O;
    const float* pb = p + (long)b * NPTS * O;
    float hi[R], lo[R], ha[R], hb[R], rv[R];
    int nlr[R];
#pragma unroll
    for (int u = 0; u < R; ++u) {
        nlr[u] = nlb + u * STEP;
        rv[u] = r_s[nlr[u] * O + o];
        hi[u] = -3.0e38f; lo[u] = 3.0e38f;
    }
    float s0 = 0.f, s1 = 0.f, q0 = 0.f, q1 = 0.f;
    int kk = 0;
    for (; kk + 3 < KNN - 1; kk += 4) {
        int j0[R], j1[R], j2[R], j3[R];
#pragma unroll
        for (int u = 0; u < R; ++u) {
            const int* ip = &idx_s[nlr[u] * KSEL + kk];
            j0[u] = ip[0]; j1[u] = ip[1]; j2[u] = ip[2]; j3[u] = ip[3];
        }
#pragma unroll
        for (int u = 0; u < R; ++u) {
            float h0 = pb[(long)j0[u] * O + o] + rv[u];
            float h1 = pb[(long)j1[u] * O + o] + rv[u];
            float h2 = pb[(long)j2[u] * O + o] + rv[u];
            float h3 = pb[(long)j3[u] * O + o] + rv[u];
            hi[u] = fmaxf(hi[u], fmaxf(fmaxf(h0, h1), fmaxf(h2, h3)));
            lo[u] = fminf(lo[u], fminf(fminf(h0, h1), fminf(h2, h3)));
            s0 += h0 + h2;
            s1 += h1 + h3;
            q0 = fmaf(h0, h0, q0); q0 = fmaf(h2, h2, q0);
            q1 = fmaf(h1, h1, q1); q1 = fmaf(h3, h3, q1);
        }
    }
    for (; kk < KNN - 1; ++kk) {
#pragma unroll
        for (int u = 0; u < R; ++u) {
            int j = idx_s[nlr[u] * KSEL + kk];
            float h = pb[(long)j * O + o] + rv[u];
            hi[u] = fmaxf(hi[u], h);
            lo[u] = fminf(lo[u], h);
            s0 += h;
            q0 = fmaf(h, h, q0);
        }
    }
#pragma unroll
    for (int u = 0; u < R; ++u) {
        int j = idx_s[nlr[u] * KSEL + (KNN - 1)];
        ha[u] = pb[(long)j * O + o] + rv[u];
        s0 += ha[u];
        q0 = fmaf(ha[u], ha[u], q0);
        int j2 = idx_s[nlr[u] * KSEL + KNN];
        hb[u] = pb[(long)j2 * O + o] + rv[u];
    }
#pragma unroll
    for (int u = 0; u < R; ++u)
        hilo[((long)b * NPTS + n0 + nlr[u]) * O + o] = make_float4(hi[u], lo[u], ha[u], hb[u]);
    double s = (double)s0 + (double)s1;
    double q = (double)q0 + (double)q1;
    for (int off = 16; off > 0; off >>= 1) {
        s += __shfl_xor(s, off);
        q += __shfl_xor(q, off);
    }
    int hw = tid >> 5;
    if ((tid & 31) == 0) { gs8[hw] = s; gq8[hw] = q; }
    __syncthreads();
    if (tid < 2) {
        double ss = 0.0, qq = 0.0;
        for (int h2 = 0; h2 < 8; ++h2) {
            int o0 = (h2 * 32) % O;
            int g = o0 / (O / 2);
            if (g == tid) { ss += gs8[h2]; qq += gq8[h2]; }
        }
        partials[(long)blockIdx.x * 4 + tid * 2 + 0] = ss;
        partials[(long)blockIdx.x * 4 + tid * 2 + 1] = qq;
    }
}

__global__ void reduce_stats(const double* __restrict__ partials, int nblkb, double M,
                             float* __restrict__ ms) {
    int i = threadIdx.x;
    if (i >= BATCH * 2) return;
    int b = i >> 1, g = i & 1;
    double s = 0.0, q = 0.0;
    for (int t = 0; t < nblkb; ++t) {
        long blk = (long)b * nblkb + t;
        s += partials[blk * 4 + g * 2 + 0];
        q += partials[blk * 4 + g * 2 + 1];
    }
    double mean = s / M;
    double var = q / M - mean * mean;
    ms[i * 2 + 0] = (float)mean;
    ms[i * 2 + 1] = (float)(1.0 / sqrt(var + 1e-5));
}

// ---------------- finalize: normalize extremes + leaky + hedge -> feat ----------------
template<int O>
__global__ __launch_bounds__(256) void finalize_kernel(
    const float4* __restrict__ hilo, const int* __restrict__ flags,
    const float* __restrict__ ms, const float* __restrict__ gamma, const float* __restrict__ beta,
    float* __restrict__ featP, float* __restrict__ featH, int coff) {
    const int NT = 16;
    __shared__ float smP[O * NT], smH[O * NT];
    __shared__ float sc_s[O], sh_s[O];
    __shared__ int flag_s[NT];
    int nb = NPTS / NT;
    int b = blockIdx.x / nb;
    int n0 = (blockIdx.x % nb) * NT;
    int tid = threadIdx.x;
    if (tid < NT) flag_s[tid] = flags[b * NPTS + n0 + tid];
    if (tid < O) {
        int g = tid / (O / 2);
        float mean = ms[(b * 2 + g) * 2 + 0], rstd = ms[(b * 2 + g) * 2 + 1];
        float sc = rstd * gamma[tid];
        sc_s[tid] = sc;
        sh_s[tid] = beta[tid] - mean * sc;
    }
    __syncthreads();
    int o = tid % O;
    int nl0 = tid / O, nrep = 256 / O;
    float sc = sc_s[o], sh = sh_s[o];
    bool pos = (sc >= 0.f);
    for (int nl = nl0; nl < NT; nl += nrep) {
        float4 v = hilo[((long)b * NPTS + n0 + nl) * O + o];
        float h0 = pos ? fmaxf(v.x, v.z) : fminf(v.y, v.z);
        float h1 = pos ? fmaxf(v.x, v.w) : fminf(v.y, v.w);
        float v0 = h0 * sc + sh; v0 = v0 >= 0.f ? v0 : 0.2f * v0;
        float v1 = h1 * sc + sh; v1 = v1 >= 0.f ? v1 : 0.2f * v1;
        float outv = v0;
        if (flag_s[nl] && fabsf(v0 - v1) <= 0.45f) outv = 0.5f * (v0 + v1);
        smP[o * NT + nl] = v0;
        smH[o * NT + nl] = outv;
    }
    __syncthreads();
    long obase = ((long)b * 256 + coff) * NPTS + n0;
    for (int i = tid; i < O * NT; i += 256) {
        int oo = i / NT, nl = i % NT;
        featP[obase + (long)oo * NPTS + nl] = smP[i];
        featH[obase + (long)oo * NPTS + nl] = smH[i];
    }
}

// ---------------- MLP GEMM: 128o x 128n tile, 8x8/thread, kc=64, fused max/min+stats ----------------
__global__ __launch_bounds__(256) void mlp_gemm_kernel(
    const float* __restrict__ xf, const float* __restrict__ Wm, const float* __restrict__ bm,
    unsigned* __restrict__ mmax, unsigned* __restrict__ mmin, double* __restrict__ stats) {
    int b = blockIdx.z;
    int o0 = blockIdx.y * 128, n0 = blockIdx.x * 128;
    __shared__ float wm_s[128][65];   // [o][c] — reads are 16-lane broadcasts
    __shared__ float xf_s[64][128];   // [c][n]
    int tid = threadIdx.x;
    int tx = tid & 15, ty = tid >> 4;
    float acc[8][8] = {};
    for (int kc = 0; kc < 256; kc += 64) {
#pragma unroll
        for (int i = 0; i < 8; ++i) {
            int f = tid + i * 256;          // float4 index in 128x64 tile
            int o = f >> 4;                  // 16 float4 per o-row
            int c4 = (f & 15) * 4;
            float4 wv = *(const float4*)&Wm[(long)(o0 + o) * 256 + kc + c4];
            wm_s[o][c4 + 0] = wv.x;
            wm_s[o][c4 + 1] = wv.y;
            wm_s[o][c4 + 2] = wv.z;
            wm_s[o][c4 + 3] = wv.w;
        }
#pragma unroll
        for (int i = 0; i < 8; ++i) {
            int f = tid + i * 256;          // float4 index in 64x128 tile
            int c = f >> 5;                  // 32 float4 per c-row
            int n4 = (f & 31) * 4;
            float4 v = *(const float4*)&xf[(long)b * 256 * NPTS + (long)(kc + c) * NPTS + n0 + n4];
            *(float4*)&xf_s[c][n4] = v;
        }
        __syncthreads();
        for (int c = 0; c < 64; ++c) {
            float a[8], bb[8];
#pragma unroll
            for (int u = 0; u < 4; ++u) {
                a[u] = wm_s[ty * 4 + u][c];
                a[4 + u] = wm_s[64 + ty * 4 + u][c];
            }
            float4 bA = *(const float4*)&xf_s[c][tx * 4];
            float4 bB = *(const float4*)&xf_s[c][64 + tx * 4];
            bb[0] = bA.x; bb[1] = bA.y; bb[2] = bA.z; bb[3] = bA.w;
            bb[4] = bB.x; bb[5] = bB.y; bb[6] = bB.z; bb[7] = bB.w;
#pragma unroll
            for (int u = 0; u < 8; ++u)
#pragma unroll
                for (int v = 0; v < 8; ++v) acc[u][v] = fmaf(a[u], bb[v], acc[u][v]);
        }
        __syncthreads();
    }
    double s = 0.0, q = 0.0;
#pragma unroll
    for (int u = 0; u < 8; ++u) {
        int o = o0 + ((u < 4) ? (ty * 4 + u) : (64 + ty * 4 + (u - 4)));
        float bv = bm[o];
        float mx = -3.0e38f, mn = 3.0e38f;
#pragma unroll
        for (int v = 0; v < 8; ++v) {
            float hv = acc[u][v] + bv;
            mx = fmaxf(mx, hv);
            mn = fminf(mn, hv);
            s += (double)hv;
            q += (double)hv * (double)hv;
        }
        for (int d = 1; d < 16; d <<= 1) {
            mx = fmaxf(mx, __shfl_xor(mx, d));
            mn = fminf(mn, __shfl_xor(mn, d));
        }
        if (tx == 0) {
            atomicMax(&mmax[((long)b << 10) + o], f2key(mx));
            atomicMin(&mmin[((long)b << 10) + o], f2key(mn));
        }
    }
    for (int off = 32; off > 0; off >>= 1) {
        s += __shfl_xor(s, off);
        q += __shfl_xor(q, off);
    }
    __shared__ double rs[4], rq[4];
    int wid = tid >> 6;
    if ((tid & 63) == 0) { rs[wid] = s; rq[wid] = q; }
    __syncthreads();
    if (tid == 0) {
        s = rs[0] + rs[1] + rs[2] + rs[3];
        q = rq[0] + rq[1] + rq[2] + rq[3];
        int g = o0 >> 7;
        atomicAdd(&stats[(b * 8 + g) * 2 + 0], s);
        atomicAdd(&stats[(b * 8 + g) * 2 + 1], q);
    }
}

// ---------------- MLP final: recompute ms per block + normalize + relu ----------------
__global__ void mlp_final2_kernel(
    const double* __restrict__ st, const unsigned* __restrict__ mmax,
    const unsigned* __restrict__ mmin, const float* __restrict__ gm,
    const float* __restrict__ betam, float* __restrict__ x4) {
    __shared__ double ms_s[64];
    int tid = threadIdx.x;
    if (tid < 32) {
        double s = st[tid * 2], q = st[tid * 2 + 1];
        double M = 128.0 * 2048.0;
        double mean = s / M;
        double var = q / M - mean * mean;
        ms_s[tid * 2] = mean;
        ms_s[tid * 2 + 1] = 1.0 / sqrt(var + 1e-5);
    }
    __syncthreads();
    int i = blockIdx.x * 256 + tid;
    if (i >= BATCH * 1024) return;
    int b = i >> 10, o = i & 1023;
    int g = o >> 7;
    float mean = (float)ms_s[(b * 8 + g) * 2], rstd = (float)ms_s[(b * 8 + g) * 2 + 1];
    float sc = rstd * gm[o], sh = betam[o] - mean * sc;
    float hsel = (sc >= 0.f) ? key2f(mmax[i]) : key2f(mmin[i]);
    x4[i] = fmaxf(hsel * sc + sh, 0.f);
}

template<int C, int O>
static void run_layer(const float* xin, long sb, const float* W,
                      const float* gamma, const float* beta, int coff,
                      float* featP, float* featH,
                      double* xxb, float* dist, bool full, int* idx, int* flags,
                      float* pbuf, float* rbuf, float4* hilo,
                      double* partials, float* msf, hipStream_t stream) {
    xx64_kernel<<<(BATCH * NPTS + 255) / 256, 256, 0, stream>>>(xin, sb, C, xxb);
    if (full) {
        dist_kernel<<<dim3(32, 32, BATCH), 256, 0, stream>>>(xin, sb, C, xxb, dist, 0);
        topk_wave_kernel<<<dim3(NPTS / 4, 1, BATCH), 256, 0, stream>>>(dist, idx, flags, 0);
    } else {
        for (int b = 0; b < BATCH; ++b) {
            dist_kernel<<<dim3(32, 32, 1), 256, 0, stream>>>(xin, sb, C, xxb, dist, b);
            topk_wave_kernel<<<dim3(NPTS / 4, 1, 1), 256, 0, stream>>>(dist, idx, flags, b);
        }
    }
    pr_kernel<C, O><<<BATCH * NPTS / 32, 256, 0, stream>>>(xin, sb, W, pbuf, rbuf);
    gather_kernel<O><<<BATCH * NPTS / 4, 256, 0, stream>>>(pbuf, rbuf, idx, hilo, partials);
    double M = (double)((long)(O / 2) * NPTS * KNN);
    reduce_stats<<<1, 64, 0, stream>>>(partials, NPTS / 4, M, msf);
    finalize_kernel<O><<<BATCH * NPTS / 16, 256, 0, stream>>>(hilo, flags, msf,
                                                              gamma, beta, featP, featH, coff);
}

extern "C" void kernel_launch(void* const* d_in, const int* in_sizes, int n_in,
                              void* d_out, int out_size, void* d_ws, size_t ws_size,
                              hipStream_t stream) {
    const float* x = (const float*)d_in[0];
    const float* W1 = (const float*)d_in[1];
    const float* g1 = (const float*)d_in[2];
    const float* b1 = (const float*)d_in[3];
    const float* W2 = (const float*)d_in[4];
    const float* g2 = (const float*)d_in[5];
    const float* b2 = (const float*)d_in[6];
    const float* W3 = (const float*)d_in[7];
    const float* g3 = (const float*)d_in[8];
    const float* b3 = (const float*)d_in[9];
    const float* Wm = (const float*)d_in[10];
    const float* bm = (const float*)d_in[11];
    const float* gm = (const float*)d_in[12];
    const float* betam = (const float*)d_in[13];

    float* out = (float*)d_out;
    float* x4 = out;
    float* featH = out + BATCH * 1024;

    char* ws = (char*)d_ws;
    size_t off = 0;
    auto alloc = [&](size_t bytes) -> void* {
        void* pp = ws + off;
        off += (bytes + 255) & ~(size_t)255;
        return pp;
    };
    double* xxb = (double*)alloc((size_t)BATCH * NPTS * 8);
    int* idx = (int*)alloc((size_t)BATCH * NPTS * KSEL * 4);
    int* flags = (int*)alloc((size_t)BATCH * NPTS * 4);
    float* featP = (float*)alloc((size_t)BATCH * 256 * NPTS * 4);
    float* pbuf = (float*)alloc((size_t)BATCH * NPTS * 128 * 4);
    float* rbuf = (float*)alloc((size_t)BATCH * NPTS * 128 * 4);
    float4* hilo = (float4*)alloc((size_t)BATCH * NPTS * 128 * 16);
    double* partials = (double*)alloc((size_t)(BATCH * NPTS / 4) * 4 * 8);
    float* msf = (float*)alloc(64 * 4);
    double* statsd = (double*)alloc(128 * 8);
    unsigned* mmax = (unsigned*)alloc((size_t)BATCH * 1024 * 4);
    unsigned* mmin = (unsigned*)alloc((size_t)BATCH * 1024 * 4);
    size_t base = off;
    bool full = (ws_size >= base + (size_t)BATCH * NPTS * NPTS * 4);
    float* dist = (float*)alloc(full ? (size_t)BATCH * NPTS * NPTS * 4
                                     : (size_t)NPTS * NPTS * 4);

    hipMemsetAsync(statsd, 0, 128 * 8, stream);
    hipMemsetAsync(mmax, 0x00, (size_t)BATCH * 1024 * 4, stream);
    hipMemsetAsync(mmin, 0xFF, (size_t)BATCH * 1024 * 4, stream);

    run_layer<3, 64>(x, 3L * NPTS, W1, g1, b1, 0,
                     featP, featH, xxb, dist, full, idx, flags, pbuf, rbuf, hilo, partials, msf, stream);
    run_layer<64, 64>(featP, 256L * NPTS, W2, g2, b2, 64,
                      featP, featH, xxb, dist, full, idx, flags, pbuf, rbuf, hilo, partials, msf, stream);
    run_layer<64, 128>(featP + 64L * NPTS, 256L * NPTS, W3, g3, b3, 128,
                       featP, featH, xxb, dist, full, idx, flags, pbuf, rbuf, hilo, partials, msf, stream);

    mlp_gemm_kernel<<<dim3(16, 8, BATCH), 256, 0, stream>>>(featH, Wm, bm, mmax, mmin, statsd);
    mlp_final2_kernel<<<(BATCH * 1024 + 255) / 256, 256, 0, stream>>>(statsd, mmax, mmin, gm, betam, x4);
    (void)in_sizes; (void)n_in; (void)out_size; (void)ws_size;
}

// Round 15
// 591.771 us; speedup vs baseline: 4.5329x; 1.0026x over previous
//
#include <hip/hip_runtime.h>
#include <hip/hip_bf16.h>

#define NPTS 2048
#define KNN 80
#define KSEL 81
#define BATCH 4

__device__ __forceinline__ unsigned f2key(float f) {
    unsigned u = __float_as_uint(f);
    return u ^ ((u & 0x80000000u) ? 0xFFFFFFFFu : 0x80000000u);
}
__device__ __forceinline__ float key2f(unsigned k) {
    unsigned u = (k & 0x80000000u) ? (k ^ 0x80000000u) : ~k;
    return __uint_as_float(u);
}

// ---------------- xx (fp64) ----------------
__global__ void xx64_kernel(const float* __restrict__ x, long sb, int C, double* __restrict__ xx) {
    int i = blockIdx.x * 256 + threadIdx.x;
    if (i >= BATCH * NPTS) return;
    int b = i / NPTS, n = i % NPTS;
    const float* xp = x + (long)b * sb + n;
    double s = 0.0;
    for (int c = 0; c < C; ++c) { double v = (double)xp[(long)c * NPTS]; s = fma(v, v, s); }
    xx[i] = s;
}

// ---------------- dist: fp32 accumulate, fp64 final combine -> fp32 ----------------
__global__ __launch_bounds__(256) void dist_kernel(
    const float* __restrict__ x, long sb, int C,
    const double* __restrict__ xx, float* __restrict__ dist, int b_base) {
    int bz = blockIdx.z;
    int b = b_base + bz;
    int i0 = blockIdx.y * 64, j0 = blockIdx.x * 64;
    __shared__ float xi[32][64];
    __shared__ float xj[32][64];
    const float* xb = x + (long)b * sb;
    int tid = threadIdx.x, tx = tid & 15, ty = tid >> 4;
    float acc[4][4] = {};
    for (int cc = 0; cc < C; cc += 32) {
        int Cc = C - cc; if (Cc > 32) Cc = 32;
        for (int t = tid; t < Cc * 64; t += 256) {
            int c = t >> 6, l = t & 63;
            xi[c][l] = xb[(long)(cc + c) * NPTS + i0 + l];
            xj[c][l] = xb[(long)(cc + c) * NPTS + j0 + l];
        }
        __syncthreads();
        for (int c = 0; c < Cc; ++c) {
            float a[4], bb[4];
#pragma unroll
            for (int u = 0; u < 4; ++u) a[u] = xi[c][ty * 4 + u];
#pragma unroll
            for (int v = 0; v < 4; ++v) bb[v] = xj[c][tx * 4 + v];
#pragma unroll
            for (int u = 0; u < 4; ++u)
#pragma unroll
                for (int v = 0; v < 4; ++v) acc[u][v] = fmaf(a[u], bb[v], acc[u][v]);
        }
        __syncthreads();
    }
    const double* xxb = xx + b * NPTS;
    float* drow = dist + (long)bz * NPTS * NPTS;
#pragma unroll
    for (int u = 0; u < 4; ++u) {
        int i = i0 + ty * 4 + u;
        double xxi = xxb[i];
#pragma unroll
        for (int v = 0; v < 4; ++v) {
            int j = j0 + tx * 4 + v;
            drow[(long)i * NPTS + j] = (float)(2.0 * (double)acc[u][v] - xxi - xxb[j]);
        }
    }
}

// ---------------- top-81: wave-per-row radix select, 4-copy histogram ----------------
__global__ __launch_bounds__(256) void topk_wave_kernel(
    const float* __restrict__ dist, int* __restrict__ idxout,
    int* __restrict__ flags, int b_base) {
    int bz = blockIdx.z;
    int b = b_base + bz;
    int tid = threadIdx.x;
    int lane = tid & 63, w = tid >> 6;
    int row = blockIdx.x * 4 + w;
    const float* dr = dist + ((long)bz * NPTS + row) * NPTS;

    unsigned kv[32];
#pragma unroll
    for (int i = 0; i < 8; ++i) {
        float4 a = *(const float4*)(dr + i * 256 + lane * 4);
        kv[i * 4 + 0] = f2key(a.x);
        kv[i * 4 + 1] = f2key(a.y);
        kv[i * 4 + 2] = f2key(a.z);
        kv[i * 4 + 3] = f2key(a.w);
    }

    __shared__ unsigned hist[4][256][4];   // [wave][bin][copy]
    __shared__ int sel_s[4][KSEL];
    __shared__ float selv_s[4][KSEL];

    unsigned prefix = 0;
    int rem = KSEL;
    int cp = lane & 3;

    for (int pass = 0; pass < 4; ++pass) {
        int shift = 24 - pass * 8;
        uint4* h4 = (uint4*)&hist[w][0][0];
#pragma unroll
        for (int t = 0; t < 4; ++t) h4[lane + t * 64] = make_uint4(0u, 0u, 0u, 0u);
        unsigned pm = (pass == 0) ? 0u : (0xFFFFFFFFu << (shift + 8));
#pragma unroll
        for (int u = 0; u < 32; ++u) {
            if ((kv[u] & pm) == prefix)
                atomicAdd(&hist[w][(kv[u] >> shift) & 255u][cp], 1u);
        }
        uint4 c0 = h4[lane * 4 + 0];
        uint4 c1 = h4[lane * 4 + 1];
        uint4 c2 = h4[lane * 4 + 2];
        uint4 c3 = h4[lane * 4 + 3];
        unsigned b0 = c0.x + c0.y + c0.z + c0.w;
        unsigned b1 = c1.x + c1.y + c1.z + c1.w;
        unsigned b2 = c2.x + c2.y + c2.z + c2.w;
        unsigned b3 = c3.x + c3.y + c3.z + c3.w;
        unsigned loc3 = b3, loc2 = b3 + b2, loc1 = b3 + b2 + b1, loc0 = b3 + b2 + b1 + b0;
        unsigned tot = loc0;
        unsigned suf = tot;
#pragma unroll
        for (int d = 1; d < 64; d <<= 1) {
            unsigned o = __shfl_down(suf, d);
            suf += (lane + d < 64) ? o : 0u;
        }
        unsigned after = suf - tot;
        int fdig = -1, frem = 0;
        unsigned ge, gt;
        ge = loc0 + after; gt = loc1 + after;
        if (ge >= (unsigned)rem && gt < (unsigned)rem) { fdig = lane * 4 + 0; frem = rem - (int)gt; }
        ge = loc1 + after; gt = loc2 + after;
        if (ge >= (unsigned)rem && gt < (unsigned)rem) { fdig = lane * 4 + 1; frem = rem - (int)gt; }
        ge = loc2 + after; gt = loc3 + after;
        if (ge >= (unsigned)rem && gt < (unsigned)rem) { fdig = lane * 4 + 2; frem = rem - (int)gt; }
        ge = loc3 + after; gt = after;
        if (ge >= (unsigned)rem && gt < (unsigned)rem) { fdig = lane * 4 + 3; frem = rem - (int)gt; }
        unsigned long long bal = __ballot(fdig >= 0);
        int src = __ffsll((unsigned long long)bal) - 1;
        fdig = __shfl(fdig, src);
        frem = __shfl(frem, src);
        prefix |= ((unsigned)fdig) << shift;
        rem = frem;
    }

    int myc = 0;
#pragma unroll
    for (int u = 0; u < 32; ++u) myc += (kv[u] > prefix) ? 1 : 0;
    int inc = myc;
#pragma unroll
    for (int d = 1; d < 64; d <<= 1) {
        int o = __shfl_up(inc, d);
        inc += (lane >= d) ? o : 0;
    }
    int off = inc - myc;
    int pos = off;
#pragma unroll
    for (int u = 0; u < 32; ++u) {
        if (kv[u] > prefix) {
            int e = (u >> 2) * 256 + lane * 4 + (u & 3);
            sel_s[w][pos] = e;
            selv_s[w][pos] = key2f(kv[u]);
            ++pos;
        }
    }
    int cgt = __shfl(inc, 63);

    unsigned tmask = 0;
#pragma unroll
    for (int u = 0; u < 32; ++u)
        if (kv[u] == prefix) tmask |= (1u << u);
    float vtie = key2f(prefix);
    for (int t = 0; t < rem; ++t) {
        int best = 0x7FFFFFFF;
        unsigned m = tmask;
        while (m) {
            int u = __ffs(m) - 1;
            m &= m - 1;
            int e = (u >> 2) * 256 + lane * 4 + (u & 3);
            best = min(best, e);
        }
#pragma unroll
        for (int d = 32; d > 0; d >>= 1) best = min(best, __shfl_xor(best, d));
        if (((best >> 2) & 63) == lane) {
            int u = ((best >> 8) << 2) | (best & 3);
            tmask &= ~(1u << u);
        }
        if (lane == 0) { sel_s[w][cgt + t] = best; selv_s[w][cgt + t] = vtie; }
    }

    unsigned bk = 0xFFFFFFFFu; int bi = -1, bp = -1;
    if (lane < KSEL) { bk = f2key(selv_s[w][lane]); bi = sel_s[w][lane]; bp = lane; }
    int l2 = lane + 64;
    if (l2 < KSEL) {
        unsigned k2 = f2key(selv_s[w][l2]); int i2 = sel_s[w][l2];
        if (k2 < bk || (k2 == bk && i2 > bi)) { bk = k2; bi = i2; bp = l2; }
    }
#pragma unroll
    for (int d = 32; d > 0; d >>= 1) {
        unsigned ok = __shfl_xor(bk, d);
        int oi = __shfl_xor(bi, d);
        int op = __shfl_xor(bp, d);
        if (ok < bk || (ok == bk && oi > bi)) { bk = ok; bi = oi; bp = op; }
    }
    int p81 = bp;
    bk = 0xFFFFFFFFu; bi = -1; bp = -1;
    if (lane < KSEL && lane != p81) { bk = f2key(selv_s[w][lane]); bi = sel_s[w][lane]; bp = lane; }
    if (l2 < KSEL && l2 != p81) {
        unsigned k2 = f2key(selv_s[w][l2]); int i2 = sel_s[w][l2];
        if (k2 < bk || (k2 == bk && i2 > bi)) { bk = k2; bi = i2; bp = l2; }
    }
#pragma unroll
    for (int d = 32; d > 0; d >>= 1) {
        unsigned ok = __shfl_xor(bk, d);
        int oi = __shfl_xor(bi, d);
        int op = __shfl_xor(bp, d);
        if (ok < bk || (ok == bk && oi > bi)) { bk = ok; bi = oi; bp = op; }
    }
    int p80 = bp;

    if (lane == 0) {
        int ts; float tv;
        ts = sel_s[w][80]; sel_s[w][80] = sel_s[w][p81]; sel_s[w][p81] = ts;
        tv = selv_s[w][80]; selv_s[w][80] = selv_s[w][p81]; selv_s[w][p81] = tv;
        if (p80 == 80) p80 = p81;
        ts = sel_s[w][79]; sel_s[w][79] = sel_s[w][p80]; sel_s[w][p80] = ts;
        tv = selv_s[w][79]; selv_s[w][79] = selv_s[w][p80]; selv_s[w][p80] = tv;
        float d80f = selv_s[w][79], d81f = selv_s[w][80];
        float eta = 8e-5f + 4e-6f * fabsf(d80f);
        flags[b * NPTS + row] = ((d80f - d81f) <= eta) ? 1 : 0;
    }
    int* outp = idxout + ((long)b * NPTS + row) * KSEL;
    for (int t = lane; t < KSEL; t += 64) outp[t] = sel_s[w][t];
}

// ---------------- p/r projections ----------------
template<int C, int O>
__global__ __launch_bounds__(256) void pr_kernel(
    const float* __restrict__ x, long sb, const float* __restrict__ W,
    float* __restrict__ p, float* __restrict__ r) {
    __shared__ float wp[C * O];
    __shared__ float wr[C * O];
    __shared__ float xs[C][32];
    int nb = NPTS / 32;
    int b = blockIdx.x / nb;
    int n0 = (blockIdx.x % nb) * 32;
    int tid = threadIdx.x;
    for (int t = tid; t < C * O; t += 256) {
        int o = t / C, c = t % C;
        float w1 = W[o * 2 * C + c];
        wp[o * C + c] = w1;
        wr[o * C + c] = W[o * 2 * C + C + c] - w1;
    }
    const float* xb = x + (long)b * sb;
    for (int t = tid; t < C * 32; t += 256) {
        int c = t / 32, nn = t & 31;
        xs[c][nn] = xb[(long)c * NPTS + n0 + nn];
    }
    __syncthreads();
    int o = tid % O;
    int nl0 = tid / O, per = 256 / O;
    for (int nl = nl0; nl < 32; nl += per) {
        float pa = 0.f, ra = 0.f;
        for (int c = 0; c < C; ++c) {
            float xv = xs[c][nl];
            pa = fmaf(wp[o * C + c], xv, pa);
            ra = fmaf(wr[o * C + c], xv, ra);
        }
        long po = ((long)b * NPTS + n0 + nl) * O + o;
        p[po] = pa;
        r[po] = ra;
    }
}

// ---------------- FUSED gather: fp32 dual accumulators, kk unrolled x4 ----------------
template<int O>
__global__ __launch_bounds__(256) void gather_kernel(
    const float* __restrict__ p, const float* __restrict__ r,
    const int* __restrict__ idx, float4* __restrict__ hilo,
    double* __restrict__ partials) {
    const int NT = 4;
    const int R = (NT * O) / 256;
    const int STEP = 256 / O;
    __shared__ float r_s[NT * O];
    __shared__ int idx_s[NT * KSEL];
    __shared__ double gs8[8], gq8[8];
    int nb = NPTS / NT;
    int b = blockIdx.x / nb;
    int n0 = (blockIdx.x % nb) * NT;
    int tid = threadIdx.x;
    for (int t = tid; t < NT * O; t += 256) r_s[t] = r[((long)b * NPTS + n0) * O + t];
    for (int t = tid; t < NT * KSEL; t += 256) idx_s[t] = idx[((long)b * NPTS + n0) * KSEL + t];
    __syncthreads();
    int o = tid % O;
    int nlb = tid / O;
    const float* pb = p + (long)b * NPTS * O;
    float hi[R], lo[R], ha[R], hb[R], rv[R];
    int nlr[R];
#pragma unroll
    for (int u = 0; u < R; ++u) {
        nlr[u] = nlb + u * STEP;
        rv[u] = r_s[nlr[u] * O + o];
        hi[u] = -3.0e38f; lo[u] = 3.0e38f;
    }
    float s0 = 0.f, s1 = 0.f, q0 = 0.f, q1 = 0.f;
    int kk = 0;
    for (; kk + 3 < KNN - 1; kk += 4) {
        int j0[R], j1[R], j2[R], j3[R];
#pragma unroll
        for (int u = 0; u < R; ++u) {
            const int* ip = &idx_s[nlr[u] * KSEL + kk];
            j0[u] = ip[0]; j1[u] = ip[1]; j2[u] = ip[2]; j3[u] = ip[3];
        }
#pragma unroll
        for (int u = 0; u < R; ++u) {
            float h0 = pb[(long)j0[u] * O + o] + rv[u];
            float h1 = pb[(long)j1[u] * O + o] + rv[u];
            float h2 = pb[(long)j2[u] * O + o] + rv[u];
            float h3 = pb[(long)j3[u] * O + o] + rv[u];
            hi[u] = fmaxf(hi[u], fmaxf(fmaxf(h0, h1), fmaxf(h2, h3)));
            lo[u] = fminf(lo[u], fminf(fminf(h0, h1), fminf(h2, h3)));
            s0 += h0 + h2;
            s1 += h1 + h3;
            q0 = fmaf(h0, h0, q0); q0 = fmaf(h2, h2, q0);
            q1 = fmaf(h1, h1, q1); q1 = fmaf(h3, h3, q1);
        }
    }
    for (; kk < KNN - 1; ++kk) {
#pragma unroll
        for (int u = 0; u < R; ++u) {
            int j = idx_s[nlr[u] * KSEL + kk];
            float h = pb[(long)j * O + o] + rv[u];
            hi[u] = fmaxf(hi[u], h);
            lo[u] = fminf(lo[u], h);
            s0 += h;
            q0 = fmaf(h, h, q0);
        }
    }
#pragma unroll
    for (int u = 0; u < R; ++u) {
        int j = idx_s[nlr[u] * KSEL + (KNN - 1)];
        ha[u] = pb[(long)j * O + o] + rv[u];
        s0 += ha[u];
        q0 = fmaf(ha[u], ha[u], q0);
        int j2 = idx_s[nlr[u] * KSEL + KNN];
        hb[u] = pb[(long)j2 * O + o] + rv[u];
    }
#pragma unroll
    for (int u = 0; u < R; ++u)
        hilo[((long)b * NPTS + n0 + nlr[u]) * O + o] = make_float4(hi[u], lo[u], ha[u], hb[u]);
    double s = (double)s0 + (double)s1;
    double q = (double)q0 + (double)q1;
    for (int off = 16; off > 0; off >>= 1) {
        s += __shfl_xor(s, off);
        q += __shfl_xor(q, off);
    }
    int hw = tid >> 5;
    if ((tid & 31) == 0) { gs8[hw] = s; gq8[hw] = q; }
    __syncthreads();
    if (tid < 2) {
        double ss = 0.0, qq = 0.0;
        for (int h2 = 0; h2 < 8; ++h2) {
            int o0 = (h2 * 32) % O;
            int g = o0 / (O / 2);
            if (g == tid) { ss += gs8[h2]; qq += gq8[h2]; }
        }
        partials[(long)blockIdx.x * 4 + tid * 2 + 0] = ss;
        partials[(long)blockIdx.x * 4 + tid * 2 + 1] = qq;
    }
}

__global__ void reduce_stats(const double* __restrict__ partials, int nblkb, double M,
                             float* __restrict__ ms) {
    int i = threadIdx.x;
    if (i >= BATCH * 2) return;
    int b = i >> 1, g = i & 1;
    double s = 0.0, q = 0.0;
    for (int t = 0; t < nblkb; ++t) {
        long blk = (long)b * nblkb + t;
        s += partials[blk * 4 + g * 2 + 0];
        q += partials[blk * 4 + g * 2 + 1];
    }
    double mean = s / M;
    double var = q / M - mean * mean;
    ms[i * 2 + 0] = (float)mean;
    ms[i * 2 + 1] = (float)(1.0 / sqrt(var + 1e-5));
}

// ---------------- finalize: normalize extremes + leaky + hedge -> feat ----------------
template<int O>
__global__ __launch_bounds__(256) void finalize_kernel(
    const float4* __restrict__ hilo, const int* __restrict__ flags,
    const float* __restrict__ ms, const float* __restrict__ gamma, const float* __restrict__ beta,
    float* __restrict__ featP, float* __restrict__ featH, int coff) {
    const int NT = 16;
    __shared__ float smP[O * NT], smH[O * NT];
    __shared__ float sc_s[O], sh_s[O];
    __shared__ int flag_s[NT];
    int nb = NPTS / NT;
    int b = blockIdx.x / nb;
    int n0 = (blockIdx.x % nb) * NT;
    int tid = threadIdx.x;
    if (tid < NT) flag_s[tid] = flags[b * NPTS + n0 + tid];
    if (tid < O) {
        int g = tid / (O / 2);
        float mean = ms[(b * 2 + g) * 2 + 0], rstd = ms[(b * 2 + g) * 2 + 1];
        float sc = rstd * gamma[tid];
        sc_s[tid] = sc;
        sh_s[tid] = beta[tid] - mean * sc;
    }
    __syncthreads();
    int o = tid % O;
    int nl0 = tid / O, nrep = 256 / O;
    float sc = sc_s[o], sh = sh_s[o];
    bool pos = (sc >= 0.f);
    for (int nl = nl0; nl < NT; nl += nrep) {
        float4 v = hilo[((long)b * NPTS + n0 + nl) * O + o];
        float h0 = pos ? fmaxf(v.x, v.z) : fminf(v.y, v.z);
        float h1 = pos ? fmaxf(v.x, v.w) : fminf(v.y, v.w);
        float v0 = h0 * sc + sh; v0 = v0 >= 0.f ? v0 : 0.2f * v0;
        float v1 = h1 * sc + sh; v1 = v1 >= 0.f ? v1 : 0.2f * v1;
        float outv = v0;
        if (flag_s[nl] && fabsf(v0 - v1) <= 0.45f) outv = 0.5f * (v0 + v1);
        smP[o * NT + nl] = v0;
        smH[o * NT + nl] = outv;
    }
    __syncthreads();
    long obase = ((long)b * 256 + coff) * NPTS + n0;
    for (int i = tid; i < O * NT; i += 256) {
        int oo = i / NT, nl = i % NT;
        featP[obase + (long)oo * NPTS + nl] = smP[i];
        featH[obase + (long)oo * NPTS + nl] = smH[i];
    }
}

// ---------------- MLP GEMM: 128o x 128n tile, 512 threads (8 waves), 4x8/thread, kc=64 ----------------
__global__ __launch_bounds__(512) void mlp_gemm_kernel(
    const float* __restrict__ xf, const float* __restrict__ Wm, const float* __restrict__ bm,
    unsigned* __restrict__ mmax, unsigned* __restrict__ mmin, double* __restrict__ stats) {
    int b = blockIdx.z;
    int o0 = blockIdx.y * 128, n0 = blockIdx.x * 128;
    __shared__ float wm_s[128][65];   // [o][c] — reads broadcast within 16-lane groups
    __shared__ float xf_s[64][128];   // [c][n]
    int tid = threadIdx.x;
    int tx = tid & 15, ty = tid >> 4;   // tx: 8n, ty 0..31: 4o each
    float acc[4][8] = {};
    for (int kc = 0; kc < 256; kc += 64) {
#pragma unroll
        for (int i = 0; i < 4; ++i) {
            int f = tid + i * 512;          // float4 index in 128x64 tile
            int o = f >> 4;                  // 16 float4 per o-row
            int c4 = (f & 15) * 4;
            float4 wv = *(const float4*)&Wm[(long)(o0 + o) * 256 + kc + c4];
            wm_s[o][c4 + 0] = wv.x;
            wm_s[o][c4 + 1] = wv.y;
            wm_s[o][c4 + 2] = wv.z;
            wm_s[o][c4 + 3] = wv.w;
        }
#pragma unroll
        for (int i = 0; i < 4; ++i) {
            int f = tid + i * 512;          // float4 index in 64x128 tile
            int c = f >> 5;                  // 32 float4 per c-row
            int n4 = (f & 31) * 4;
            float4 v = *(const float4*)&xf[(long)b * 256 * NPTS + (long)(kc + c) * NPTS + n0 + n4];
            *(float4*)&xf_s[c][n4] = v;
        }
        __syncthreads();
        for (int c = 0; c < 64; ++c) {
            float a[4], bb[8];
#pragma unroll
            for (int u = 0; u < 4; ++u) a[u] = wm_s[ty * 4 + u][c];
            float4 bA = *(const float4*)&xf_s[c][tx * 4];
            float4 bB = *(const float4*)&xf_s[c][64 + tx * 4];
            bb[0] = bA.x; bb[1] = bA.y; bb[2] = bA.z; bb[3] = bA.w;
            bb[4] = bB.x; bb[5] = bB.y; bb[6] = bB.z; bb[7] = bB.w;
#pragma unroll
            for (int u = 0; u < 4; ++u)
#pragma unroll
                for (int v = 0; v < 8; ++v) acc[u][v] = fmaf(a[u], bb[v], acc[u][v]);
        }
        __syncthreads();
    }
    double s = 0.0, q = 0.0;
#pragma unroll
    for (int u = 0; u < 4; ++u) {
        int o = o0 + ty * 4 + u;
        float bv = bm[o];
        float mx = -3.0e38f, mn = 3.0e38f;
#pragma unroll
        for (int v = 0; v < 8; ++v) {
            float hv = acc[u][v] + bv;
            mx = fmaxf(mx, hv);
            mn = fminf(mn, hv);
            s += (double)hv;
            q += (double)hv * (double)hv;
        }
        for (int d = 1; d < 16; d <<= 1) {
            mx = fmaxf(mx, __shfl_xor(mx, d));
            mn = fminf(mn, __shfl_xor(mn, d));
        }
        if (tx == 0) {
            atomicMax(&mmax[((long)b << 10) + o], f2key(mx));
            atomicMin(&mmin[((long)b << 10) + o], f2key(mn));
        }
    }
    for (int off = 32; off > 0; off >>= 1) {
        s += __shfl_xor(s, off);
        q += __shfl_xor(q, off);
    }
    __shared__ double rs[8], rq[8];
    int wid = tid >> 6;
    if ((tid & 63) == 0) { rs[wid] = s; rq[wid] = q; }
    __syncthreads();
    if (tid == 0) {
        s = 0.0; q = 0.0;
#pragma unroll
        for (int ww = 0; ww < 8; ++ww) { s += rs[ww]; q += rq[ww]; }
        int g = o0 >> 7;
        atomicAdd(&stats[(b * 8 + g) * 2 + 0], s);
        atomicAdd(&stats[(b * 8 + g) * 2 + 1], q);
    }
}

// ---------------- MLP final: recompute ms per block + normalize + relu ----------------
__global__ void mlp_final2_kernel(
    const double* __restrict__ st, const unsigned* __restrict__ mmax,
    const unsigned* __restrict__ mmin, const float* __restrict__ gm,
    const float* __restrict__ betam, float* __restrict__ x4) {
    __shared__ double ms_s[64];
    int tid = threadIdx.x;
    if (tid < 32) {
        double s = st[tid * 2], q = st[tid * 2 + 1];
        double M = 128.0 * 2048.0;
        double mean = s / M;
        double var = q / M - mean * mean;
        ms_s[tid * 2] = mean;
        ms_s[tid * 2 + 1] = 1.0 / sqrt(var + 1e-5);
    }
    __syncthreads();
    int i = blockIdx.x * 256 + tid;
    if (i >= BATCH * 1024) return;
    int b = i >> 10, o = i & 1023;
    int g = o >> 7;
    float mean = (float)ms_s[(b * 8 + g) * 2], rstd = (float)ms_s[(b * 8 + g) * 2 + 1];
    float sc = rstd * gm[o], sh = betam[o] - mean * sc;
    float hsel = (sc >= 0.f) ? key2f(mmax[i]) : key2f(mmin[i]);
    x4[i] = fmaxf(hsel * sc + sh, 0.f);
}

template<int C, int O>
static void run_layer(const float* xin, long sb, const float* W,
                      const float* gamma, const float* beta, int coff,
                      float* featP, float* featH,
                      double* xxb, float* dist, bool full, int* idx, int* flags,
                      float* pbuf, float* rbuf, float4* hilo,
                      double* partials, float* msf, hipStream_t stream) {
    xx64_kernel<<<(BATCH * NPTS + 255) / 256, 256, 0, stream>>>(xin, sb, C, xxb);
    if (full) {
        dist_kernel<<<dim3(32, 32, BATCH), 256, 0, stream>>>(xin, sb, C, xxb, dist, 0);
        topk_wave_kernel<<<dim3(NPTS / 4, 1, BATCH), 256, 0, stream>>>(dist, idx, flags, 0);
    } else {
        for (int b = 0; b < BATCH; ++b) {
            dist_kernel<<<dim3(32, 32, 1), 256, 0, stream>>>(xin, sb, C, xxb, dist, b);
            topk_wave_kernel<<<dim3(NPTS / 4, 1, 1), 256, 0, stream>>>(dist, idx, flags, b);
        }
    }
    pr_kernel<C, O><<<BATCH * NPTS / 32, 256, 0, stream>>>(xin, sb, W, pbuf, rbuf);
    gather_kernel<O><<<BATCH * NPTS / 4, 256, 0, stream>>>(pbuf, rbuf, idx, hilo, partials);
    double M = (double)((long)(O / 2) * NPTS * KNN);
    reduce_stats<<<1, 64, 0, stream>>>(partials, NPTS / 4, M, msf);
    finalize_kernel<O><<<BATCH * NPTS / 16, 256, 0, stream>>>(hilo, flags, msf,
                                                              gamma, beta, featP, featH, coff);
}

extern "C" void kernel_launch(void* const* d_in, const int* in_sizes, int n_in,
                              void* d_out, int out_size, void* d_ws, size_t ws_size,
                              hipStream_t stream) {
    const float* x = (const float*)d_in[0];
    const float* W1 = (const float*)d_in[1];
    const float* g1 = (const float*)d_in[2];
    const float* b1 = (const float*)d_in[3];
    const float* W2 = (const float*)d_in[4];
    const float* g2 = (const float*)d_in[5];
    const float* b2 = (const float*)d_in[6];
    const float* W3 = (const float*)d_in[7];
    const float* g3 = (const float*)d_in[8];
    const float* b3 = (const float*)d_in[9];
    const float* Wm = (const float*)d_in[10];
    const float* bm = (const float*)d_in[11];
    const float* gm = (const float*)d_in[12];
    const float* betam = (const float*)d_in[13];

    float* out = (float*)d_out;
    float* x4 = out;
    float* featH = out + BATCH * 1024;

    char* ws = (char*)d_ws;
    size_t off = 0;
    auto alloc = [&](size_t bytes) -> void* {
        void* pp = ws + off;
        off += (bytes + 255) & ~(size_t)255;
        return pp;
    };
    double* xxb = (double*)alloc((size_t)BATCH * NPTS * 8);
    int* idx = (int*)alloc((size_t)BATCH * NPTS * KSEL * 4);
    int* flags = (int*)alloc((size_t)BATCH * NPTS * 4);
    float* featP = (float*)alloc((size_t)BATCH * 256 * NPTS * 4);
    float* pbuf = (float*)alloc((size_t)BATCH * NPTS * 128 * 4);
    float* rbuf = (float*)alloc((size_t)BATCH * NPTS * 128 * 4);
    float4* hilo = (float4*)alloc((size_t)BATCH * NPTS * 128 * 16);
    double* partials = (double*)alloc((size_t)(BATCH * NPTS / 4) * 4 * 8);
    float* msf = (float*)alloc(64 * 4);
    double* statsd = (double*)alloc(128 * 8);
    unsigned* mmax = (unsigned*)alloc((size_t)BATCH * 1024 * 4);
    unsigned* mmin = (unsigned*)alloc((size_t)BATCH * 1024 * 4);
    size_t base = off;
    bool full = (ws_size >= base + (size_t)BATCH * NPTS * NPTS * 4);
    float* dist = (float*)alloc(full ? (size_t)BATCH * NPTS * NPTS * 4
                                     : (size_t)NPTS * NPTS * 4);

    hipMemsetAsync(statsd, 0, 128 * 8, stream);
    hipMemsetAsync(mmax, 0x00, (size_t)BATCH * 1024 * 4, stream);
    hipMemsetAsync(mmin, 0xFF, (size_t)BATCH * 1024 * 4, stream);

    run_layer<3, 64>(x, 3L * NPTS, W1, g1, b1, 0,
                     featP, featH, xxb, dist, full, idx, flags, pbuf, rbuf, hilo, partials, msf, stream);
    run_layer<64, 64>(featP, 256L * NPTS, W2, g2, b2, 64,
                      featP, featH, xxb, dist, full, idx, flags, pbuf, rbuf, hilo, partials, msf, stream);
    run_layer<64, 128>(featP + 64L * NPTS, 256L * NPTS, W3, g3, b3, 128,
                       featP, featH, xxb, dist, full, idx, flags, pbuf, rbuf, hilo, partials, msf, stream);

    mlp_gemm_kernel<<<dim3(16, 8, BATCH), 512, 0, stream>>>(featH, Wm, bm, mmax, mmin, statsd);
    mlp_final2_kernel<<<(BATCH * 1024 + 255) / 256, 256, 0, stream>>>(statsd, mmax, mmin, gm, betam, x4);
    (void)in_sizes; (void)n_in; (void)out_size; (void)ws_size;
}

// Round 16
// 488.165 us; speedup vs baseline: 5.4950x; 1.2122x over previous
//
#include <hip/hip_runtime.h>
#include <hip/hip_bf16.h>

#define NPTS 2048
#define KNN 80
#define KSEL 81
#define BATCH 4

__device__ __forceinline__ unsigned f2key(float f) {
    unsigned u = __float_as_uint(f);
    return u ^ ((u & 0x80000000u) ? 0xFFFFFFFFu : 0x80000000u);
}
__device__ __forceinline__ float key2f(unsigned k) {
    unsigned u = (k & 0x80000000u) ? (k ^ 0x80000000u) : ~k;
    return __uint_as_float(u);
}

// ---------------- xx (fp64) ----------------
__global__ void xx64_kernel(const float* __restrict__ x, long sb, int C, double* __restrict__ xx) {
    int i = blockIdx.x * 256 + threadIdx.x;
    if (i >= BATCH * NPTS) return;
    int b = i / NPTS, n = i % NPTS;
    const float* xp = x + (long)b * sb + n;
    double s = 0.0;
    for (int c = 0; c < C; ++c) { double v = (double)xp[(long)c * NPTS]; s = fma(v, v, s); }
    xx[i] = s;
}

// ---------------- dist: fp32 accumulate, fp64 final combine -> fp32 ----------------
__global__ __launch_bounds__(256) void dist_kernel(
    const float* __restrict__ x, long sb, int C,
    const double* __restrict__ xx, float* __restrict__ dist, int b_base) {
    int bz = blockIdx.z;
    int b = b_base + bz;
    int i0 = blockIdx.y * 64, j0 = blockIdx.x * 64;
    __shared__ float xi[32][64];
    __shared__ float xj[32][64];
    const float* xb = x + (long)b * sb;
    int tid = threadIdx.x, tx = tid & 15, ty = tid >> 4;
    float acc[4][4] = {};
    for (int cc = 0; cc < C; cc += 32) {
        int Cc = C - cc; if (Cc > 32) Cc = 32;
        for (int t = tid; t < Cc * 64; t += 256) {
            int c = t >> 6, l = t & 63;
            xi[c][l] = xb[(long)(cc + c) * NPTS + i0 + l];
            xj[c][l] = xb[(long)(cc + c) * NPTS + j0 + l];
        }
        __syncthreads();
        for (int c = 0; c < Cc; ++c) {
            float a[4], bb[4];
#pragma unroll
            for (int u = 0; u < 4; ++u) a[u] = xi[c][ty * 4 + u];
#pragma unroll
            for (int v = 0; v < 4; ++v) bb[v] = xj[c][tx * 4 + v];
#pragma unroll
            for (int u = 0; u < 4; ++u)
#pragma unroll
                for (int v = 0; v < 4; ++v) acc[u][v] = fmaf(a[u], bb[v], acc[u][v]);
        }
        __syncthreads();
    }
    const double* xxb = xx + b * NPTS;
    float* drow = dist + (long)bz * NPTS * NPTS;
#pragma unroll
    for (int u = 0; u < 4; ++u) {
        int i = i0 + ty * 4 + u;
        double xxi = xxb[i];
#pragma unroll
        for (int v = 0; v < 4; ++v) {
            int j = j0 + tx * 4 + v;
            drow[(long)i * NPTS + j] = (float)(2.0 * (double)acc[u][v] - xxi - xxb[j]);
        }
    }
}

// ---------------- top-81: wave-per-row radix select, 4-copy histogram ----------------
__global__ __launch_bounds__(256) void topk_wave_kernel(
    const float* __restrict__ dist, int* __restrict__ idxout,
    int* __restrict__ flags, int b_base) {
    int bz = blockIdx.z;
    int b = b_base + bz;
    int tid = threadIdx.x;
    int lane = tid & 63, w = tid >> 6;
    int row = blockIdx.x * 4 + w;
    const float* dr = dist + ((long)bz * NPTS + row) * NPTS;

    unsigned kv[32];
#pragma unroll
    for (int i = 0; i < 8; ++i) {
        float4 a = *(const float4*)(dr + i * 256 + lane * 4);
        kv[i * 4 + 0] = f2key(a.x);
        kv[i * 4 + 1] = f2key(a.y);
        kv[i * 4 + 2] = f2key(a.z);
        kv[i * 4 + 3] = f2key(a.w);
    }

    __shared__ unsigned hist[4][256][4];   // [wave][bin][copy]
    __shared__ int sel_s[4][KSEL];
    __shared__ float selv_s[4][KSEL];

    unsigned prefix = 0;
    int rem = KSEL;
    int cp = lane & 3;

    for (int pass = 0; pass < 4; ++pass) {
        int shift = 24 - pass * 8;
        uint4* h4 = (uint4*)&hist[w][0][0];
#pragma unroll
        for (int t = 0; t < 4; ++t) h4[lane + t * 64] = make_uint4(0u, 0u, 0u, 0u);
        unsigned pm = (pass == 0) ? 0u : (0xFFFFFFFFu << (shift + 8));
#pragma unroll
        for (int u = 0; u < 32; ++u) {
            if ((kv[u] & pm) == prefix)
                atomicAdd(&hist[w][(kv[u] >> shift) & 255u][cp], 1u);
        }
        uint4 c0 = h4[lane * 4 + 0];
        uint4 c1 = h4[lane * 4 + 1];
        uint4 c2 = h4[lane * 4 + 2];
        uint4 c3 = h4[lane * 4 + 3];
        unsigned b0 = c0.x + c0.y + c0.z + c0.w;
        unsigned b1 = c1.x + c1.y + c1.z + c1.w;
        unsigned b2 = c2.x + c2.y + c2.z + c2.w;
        unsigned b3 = c3.x + c3.y + c3.z + c3.w;
        unsigned loc3 = b3, loc2 = b3 + b2, loc1 = b3 + b2 + b1, loc0 = b3 + b2 + b1 + b0;
        unsigned tot = loc0;
        unsigned suf = tot;
#pragma unroll
        for (int d = 1; d < 64; d <<= 1) {
            unsigned o = __shfl_down(suf, d);
            suf += (lane + d < 64) ? o : 0u;
        }
        unsigned after = suf - tot;
        int fdig = -1, frem = 0;
        unsigned ge, gt;
        ge = loc0 + after; gt = loc1 + after;
        if (ge >= (unsigned)rem && gt < (unsigned)rem) { fdig = lane * 4 + 0; frem = rem - (int)gt; }
        ge = loc1 + after; gt = loc2 + after;
        if (ge >= (unsigned)rem && gt < (unsigned)rem) { fdig = lane * 4 + 1; frem = rem - (int)gt; }
        ge = loc2 + after; gt = loc3 + after;
        if (ge >= (unsigned)rem && gt < (unsigned)rem) { fdig = lane * 4 + 2; frem = rem - (int)gt; }
        ge = loc3 + after; gt = after;
        if (ge >= (unsigned)rem && gt < (unsigned)rem) { fdig = lane * 4 + 3; frem = rem - (int)gt; }
        unsigned long long bal = __ballot(fdig >= 0);
        int src = __ffsll((unsigned long long)bal) - 1;
        fdig = __shfl(fdig, src);
        frem = __shfl(frem, src);
        prefix |= ((unsigned)fdig) << shift;
        rem = frem;
    }

    int myc = 0;
#pragma unroll
    for (int u = 0; u < 32; ++u) myc += (kv[u] > prefix) ? 1 : 0;
    int inc = myc;
#pragma unroll
    for (int d = 1; d < 64; d <<= 1) {
        int o = __shfl_up(inc, d);
        inc += (lane >= d) ? o : 0;
    }
    int off = inc - myc;
    int pos = off;
#pragma unroll
    for (int u = 0; u < 32; ++u) {
        if (kv[u] > prefix) {
            int e = (u >> 2) * 256 + lane * 4 + (u & 3);
            sel_s[w][pos] = e;
            selv_s[w][pos] = key2f(kv[u]);
            ++pos;
        }
    }
    int cgt = __shfl(inc, 63);

    unsigned tmask = 0;
#pragma unroll
    for (int u = 0; u < 32; ++u)
        if (kv[u] == prefix) tmask |= (1u << u);
    float vtie = key2f(prefix);
    for (int t = 0; t < rem; ++t) {
        int best = 0x7FFFFFFF;
        unsigned m = tmask;
        while (m) {
            int u = __ffs(m) - 1;
            m &= m - 1;
            int e = (u >> 2) * 256 + lane * 4 + (u & 3);
            best = min(best, e);
        }
#pragma unroll
        for (int d = 32; d > 0; d >>= 1) best = min(best, __shfl_xor(best, d));
        if (((best >> 2) & 63) == lane) {
            int u = ((best >> 8) << 2) | (best & 3);
            tmask &= ~(1u << u);
        }
        if (lane == 0) { sel_s[w][cgt + t] = best; selv_s[w][cgt + t] = vtie; }
    }

    unsigned bk = 0xFFFFFFFFu; int bi = -1, bp = -1;
    if (lane < KSEL) { bk = f2key(selv_s[w][lane]); bi = sel_s[w][lane]; bp = lane; }
    int l2 = lane + 64;
    if (l2 < KSEL) {
        unsigned k2 = f2key(selv_s[w][l2]); int i2 = sel_s[w][l2];
        if (k2 < bk || (k2 == bk && i2 > bi)) { bk = k2; bi = i2; bp = l2; }
    }
#pragma unroll
    for (int d = 32; d > 0; d >>= 1) {
        unsigned ok = __shfl_xor(bk, d);
        int oi = __shfl_xor(bi, d);
        int op = __shfl_xor(bp, d);
        if (ok < bk || (ok == bk && oi > bi)) { bk = ok; bi = oi; bp = op; }
    }
    int p81 = bp;
    bk = 0xFFFFFFFFu; bi = -1; bp = -1;
    if (lane < KSEL && lane != p81) { bk = f2key(selv_s[w][lane]); bi = sel_s[w][lane]; bp = lane; }
    if (l2 < KSEL && l2 != p81) {
        unsigned k2 = f2key(selv_s[w][l2]); int i2 = sel_s[w][l2];
        if (k2 < bk || (k2 == bk && i2 > bi)) { bk = k2; bi = i2; bp = l2; }
    }
#pragma unroll
    for (int d = 32; d > 0; d >>= 1) {
        unsigned ok = __shfl_xor(bk, d);
        int oi = __shfl_xor(bi, d);
        int op = __shfl_xor(bp, d);
        if (ok < bk || (ok == bk && oi > bi)) { bk = ok; bi = oi; bp = op; }
    }
    int p80 = bp;

    if (lane == 0) {
        int ts; float tv;
        ts = sel_s[w][80]; sel_s[w][80] = sel_s[w][p81]; sel_s[w][p81] = ts;
        tv = selv_s[w][80]; selv_s[w][80] = selv_s[w][p81]; selv_s[w][p81] = tv;
        if (p80 == 80) p80 = p81;
        ts = sel_s[w][79]; sel_s[w][79] = sel_s[w][p80]; sel_s[w][p80] = ts;
        tv = selv_s[w][79]; selv_s[w][79] = selv_s[w][p80]; selv_s[w][p80] = tv;
        float d80f = selv_s[w][79], d81f = selv_s[w][80];
        float eta = 8e-5f + 4e-6f * fabsf(d80f);
        flags[b * NPTS + row] = ((d80f - d81f) <= eta) ? 1 : 0;
    }
    int* outp = idxout + ((long)b * NPTS + row) * KSEL;
    for (int t = lane; t < KSEL; t += 64) outp[t] = sel_s[w][t];
}

// ---------------- p/r projections ----------------
template<int C, int O>
__global__ __launch_bounds__(256) void pr_kernel(
    const float* __restrict__ x, long sb, const float* __restrict__ W,
    float* __restrict__ p, float* __restrict__ r) {
    __shared__ float wp[C * O];
    __shared__ float wr[C * O];
    __shared__ float xs[C][32];
    int nb = NPTS / 32;
    int b = blockIdx.x / nb;
    int n0 = (blockIdx.x % nb) * 32;
    int tid = threadIdx.x;
    for (int t = tid; t < C * O; t += 256) {
        int o = t / C, c = t % C;
        float w1 = W[o * 2 * C + c];
        wp[o * C + c] = w1;
        wr[o * C + c] = W[o * 2 * C + C + c] - w1;
    }
    const float* xb = x + (long)b * sb;
    for (int t = tid; t < C * 32; t += 256) {
        int c = t / 32, nn = t & 31;
        xs[c][nn] = xb[(long)c * NPTS + n0 + nn];
    }
    __syncthreads();
    int o = tid % O;
    int nl0 = tid / O, per = 256 / O;
    for (int nl = nl0; nl < 32; nl += per) {
        float pa = 0.f, ra = 0.f;
        for (int c = 0; c < C; ++c) {
            float xv = xs[c][nl];
            pa = fmaf(wp[o * C + c], xv, pa);
            ra = fmaf(wr[o * C + c], xv, ra);
        }
        long po = ((long)b * NPTS + n0 + nl) * O + o;
        p[po] = pa;
        r[po] = ra;
    }
}

// ---------------- FUSED gather: hilo + fp64 stats via global atomics ----------------
template<int O, int NT>
__global__ __launch_bounds__(256) void gather_kernel(
    const float* __restrict__ p, const float* __restrict__ r,
    const int* __restrict__ idx, float4* __restrict__ hilo,
    double* __restrict__ stats) {
    const int R = (NT * O) / 256;
    const int STEP = 256 / O;
    __shared__ float r_s[NT * O];
    __shared__ int idx_s[NT * KSEL];
    __shared__ double gs8[8], gq8[8];
    int nb = NPTS / NT;
    int b = blockIdx.x / nb;
    int n0 = (blockIdx.x % nb) * NT;
    int tid = threadIdx.x;
    for (int t = tid; t < NT * O; t += 256) r_s[t] = r[((long)b * NPTS + n0) * O + t];
    for (int t = tid; t < NT * KSEL; t += 256) idx_s[t] = idx[((long)b * NPTS + n0) * KSEL + t];
    __syncthreads();
    int o = tid % O;
    int nlb = tid / O;
    const float* pb = p + (long)b * NPTS * O;
    float hi[R], lo[R], ha[R], hb[R], rv[R];
    int nlr[R];
#pragma unroll
    for (int u = 0; u < R; ++u) {
        nlr[u] = nlb + u * STEP;
        rv[u] = r_s[nlr[u] * O + o];
        hi[u] = -3.0e38f; lo[u] = 3.0e38f;
    }
    float s0 = 0.f, s1 = 0.f, q0 = 0.f, q1 = 0.f;
    int kk = 0;
    for (; kk + 3 < KNN - 1; kk += 4) {
        int j0[R], j1[R], j2[R], j3[R];
#pragma unroll
        for (int u = 0; u < R; ++u) {
            const int* ip = &idx_s[nlr[u] * KSEL + kk];
            j0[u] = ip[0]; j1[u] = ip[1]; j2[u] = ip[2]; j3[u] = ip[3];
        }
#pragma unroll
        for (int u = 0; u < R; ++u) {
            float h0 = pb[(long)j0[u] * O + o] + rv[u];
            float h1 = pb[(long)j1[u] * O + o] + rv[u];
            float h2 = pb[(long)j2[u] * O + o] + rv[u];
            float h3 = pb[(long)j3[u] * O + o] + rv[u];
            hi[u] = fmaxf(hi[u], fmaxf(fmaxf(h0, h1), fmaxf(h2, h3)));
            lo[u] = fminf(lo[u], fminf(fminf(h0, h1), fminf(h2, h3)));
            s0 += h0 + h2;
            s1 += h1 + h3;
            q0 = fmaf(h0, h0, q0); q0 = fmaf(h2, h2, q0);
            q1 = fmaf(h1, h1, q1); q1 = fmaf(h3, h3, q1);
        }
    }
    for (; kk < KNN - 1; ++kk) {
#pragma unroll
        for (int u = 0; u < R; ++u) {
            int j = idx_s[nlr[u] * KSEL + kk];
            float h = pb[(long)j * O + o] + rv[u];
            hi[u] = fmaxf(hi[u], h);
            lo[u] = fminf(lo[u], h);
            s0 += h;
            q0 = fmaf(h, h, q0);
        }
    }
#pragma unroll
    for (int u = 0; u < R; ++u) {
        int j = idx_s[nlr[u] * KSEL + (KNN - 1)];
        ha[u] = pb[(long)j * O + o] + rv[u];
        s0 += ha[u];
        q0 = fmaf(ha[u], ha[u], q0);
        int j2 = idx_s[nlr[u] * KSEL + KNN];
        hb[u] = pb[(long)j2 * O + o] + rv[u];
    }
#pragma unroll
    for (int u = 0; u < R; ++u)
        hilo[((long)b * NPTS + n0 + nlr[u]) * O + o] = make_float4(hi[u], lo[u], ha[u], hb[u]);
    double s = (double)s0 + (double)s1;
    double q = (double)q0 + (double)q1;
    for (int off = 16; off > 0; off >>= 1) {
        s += __shfl_xor(s, off);
        q += __shfl_xor(q, off);
    }
    int hw = tid >> 5;
    if ((tid & 31) == 0) { gs8[hw] = s; gq8[hw] = q; }
    __syncthreads();
    if (tid < 2) {
        double ss = 0.0, qq = 0.0;
        for (int h2 = 0; h2 < 8; ++h2) {
            int o0 = (h2 * 32) % O;
            int g = o0 / (O / 2);
            if (g == tid) { ss += gs8[h2]; qq += gq8[h2]; }
        }
        atomicAdd(&stats[(b * 2 + tid) * 2 + 0], ss);
        atomicAdd(&stats[(b * 2 + tid) * 2 + 1], qq);
    }
}

// ---------------- finalize: compute ms from stats + normalize extremes + leaky + hedge ----------------
template<int O>
__global__ __launch_bounds__(256) void finalize_kernel(
    const float4* __restrict__ hilo, const int* __restrict__ flags,
    const double* __restrict__ st, double M,
    const float* __restrict__ gamma, const float* __restrict__ beta,
    float* __restrict__ featP, float* __restrict__ featH, int coff) {
    const int NT = 16;
    __shared__ float smP[O * NT], smH[O * NT];
    __shared__ float sc_s[O], sh_s[O];
    __shared__ int flag_s[NT];
    int nb = NPTS / NT;
    int b = blockIdx.x / nb;
    int n0 = (blockIdx.x % nb) * NT;
    int tid = threadIdx.x;
    if (tid < NT) flag_s[tid] = flags[b * NPTS + n0 + tid];
    if (tid < O) {
        int g = tid / (O / 2);
        double s = st[(b * 2 + g) * 2 + 0], q = st[(b * 2 + g) * 2 + 1];
        double meand = s / M;
        double var = q / M - meand * meand;
        float mean = (float)meand;
        float rstd = (float)(1.0 / sqrt(var + 1e-5));
        float sc = rstd * gamma[tid];
        sc_s[tid] = sc;
        sh_s[tid] = beta[tid] - mean * sc;
    }
    __syncthreads();
    int o = tid % O;
    int nl0 = tid / O, nrep = 256 / O;
    float sc = sc_s[o], sh = sh_s[o];
    bool pos = (sc >= 0.f);
    for (int nl = nl0; nl < NT; nl += nrep) {
        float4 v = hilo[((long)b * NPTS + n0 + nl) * O + o];
        float h0 = pos ? fmaxf(v.x, v.z) : fminf(v.y, v.z);
        float h1 = pos ? fmaxf(v.x, v.w) : fminf(v.y, v.w);
        float v0 = h0 * sc + sh; v0 = v0 >= 0.f ? v0 : 0.2f * v0;
        float v1 = h1 * sc + sh; v1 = v1 >= 0.f ? v1 : 0.2f * v1;
        float outv = v0;
        if (flag_s[nl] && fabsf(v0 - v1) <= 0.45f) outv = 0.5f * (v0 + v1);
        smP[o * NT + nl] = v0;
        smH[o * NT + nl] = outv;
    }
    __syncthreads();
    long obase = ((long)b * 256 + coff) * NPTS + n0;
    for (int i = tid; i < O * NT; i += 256) {
        int oo = i / NT, nl = i % NT;
        featP[obase + (long)oo * NPTS + nl] = smP[i];
        featH[obase + (long)oo * NPTS + nl] = smH[i];
    }
}

// ---------------- MLP GEMM: 128o x 128n tile, 512 threads (8 waves), 4x8/thread, kc=64 ----------------
__global__ __launch_bounds__(512) void mlp_gemm_kernel(
    const float* __restrict__ xf, const float* __restrict__ Wm, const float* __restrict__ bm,
    unsigned* __restrict__ mmax, unsigned* __restrict__ mmin, double* __restrict__ stats) {
    int b = blockIdx.z;
    int o0 = blockIdx.y * 128, n0 = blockIdx.x * 128;
    __shared__ float wm_s[128][65];
    __shared__ float xf_s[64][128];
    int tid = threadIdx.x;
    int tx = tid & 15, ty = tid >> 4;
    float acc[4][8] = {};
    for (int kc = 0; kc < 256; kc += 64) {
#pragma unroll
        for (int i = 0; i < 4; ++i) {
            int f = tid + i * 512;
            int o = f >> 4;
            int c4 = (f & 15) * 4;
            float4 wv = *(const float4*)&Wm[(long)(o0 + o) * 256 + kc + c4];
            wm_s[o][c4 + 0] = wv.x;
            wm_s[o][c4 + 1] = wv.y;
            wm_s[o][c4 + 2] = wv.z;
            wm_s[o][c4 + 3] = wv.w;
        }
#pragma unroll
        for (int i = 0; i < 4; ++i) {
            int f = tid + i * 512;
            int c = f >> 5;
            int n4 = (f & 31) * 4;
            float4 v = *(const float4*)&xf[(long)b * 256 * NPTS + (long)(kc + c) * NPTS + n0 + n4];
            *(float4*)&xf_s[c][n4] = v;
        }
        __syncthreads();
        for (int c = 0; c < 64; ++c) {
            float a[4], bb[8];
#pragma unroll
            for (int u = 0; u < 4; ++u) a[u] = wm_s[ty * 4 + u][c];
            float4 bA = *(const float4*)&xf_s[c][tx * 4];
            float4 bB = *(const float4*)&xf_s[c][64 + tx * 4];
            bb[0] = bA.x; bb[1] = bA.y; bb[2] = bA.z; bb[3] = bA.w;
            bb[4] = bB.x; bb[5] = bB.y; bb[6] = bB.z; bb[7] = bB.w;
#pragma unroll
            for (int u = 0; u < 4; ++u)
#pragma unroll
                for (int v = 0; v < 8; ++v) acc[u][v] = fmaf(a[u], bb[v], acc[u][v]);
        }
        __syncthreads();
    }
    double s = 0.0, q = 0.0;
#pragma unroll
    for (int u = 0; u < 4; ++u) {
        int o = o0 + ty * 4 + u;
        float bv = bm[o];
        float mx = -3.0e38f, mn = 3.0e38f;
#pragma unroll
        for (int v = 0; v < 8; ++v) {
            float hv = acc[u][v] + bv;
            mx = fmaxf(mx, hv);
            mn = fminf(mn, hv);
            s += (double)hv;
            q += (double)hv * (double)hv;
        }
        for (int d = 1; d < 16; d <<= 1) {
            mx = fmaxf(mx, __shfl_xor(mx, d));
            mn = fminf(mn, __shfl_xor(mn, d));
        }
        if (tx == 0) {
            atomicMax(&mmax[((long)b << 10) + o], f2key(mx));
            atomicMin(&mmin[((long)b << 10) + o], f2key(mn));
        }
    }
    for (int off = 32; off > 0; off >>= 1) {
        s += __shfl_xor(s, off);
        q += __shfl_xor(q, off);
    }
    __shared__ double rs[8], rq[8];
    int wid = tid >> 6;
    if ((tid & 63) == 0) { rs[wid] = s; rq[wid] = q; }
    __syncthreads();
    if (tid == 0) {
        s = 0.0; q = 0.0;
#pragma unroll
        for (int ww = 0; ww < 8; ++ww) { s += rs[ww]; q += rq[ww]; }
        int g = o0 >> 7;
        atomicAdd(&stats[(b * 8 + g) * 2 + 0], s);
        atomicAdd(&stats[(b * 8 + g) * 2 + 1], q);
    }
}

// ---------------- MLP final: recompute ms per block + normalize + relu ----------------
__global__ void mlp_final2_kernel(
    const double* __restrict__ st, const unsigned* __restrict__ mmax,
    const unsigned* __restrict__ mmin, const float* __restrict__ gm,
    const float* __restrict__ betam, float* __restrict__ x4) {
    __shared__ double ms_s[64];
    int tid = threadIdx.x;
    if (tid < 32) {
        double s = st[tid * 2], q = st[tid * 2 + 1];
        double M = 128.0 * 2048.0;
        double mean = s / M;
        double var = q / M - mean * mean;
        ms_s[tid * 2] = mean;
        ms_s[tid * 2 + 1] = 1.0 / sqrt(var + 1e-5);
    }
    __syncthreads();
    int i = blockIdx.x * 256 + tid;
    if (i >= BATCH * 1024) return;
    int b = i >> 10, o = i & 1023;
    int g = o >> 7;
    float mean = (float)ms_s[(b * 8 + g) * 2], rstd = (float)ms_s[(b * 8 + g) * 2 + 1];
    float sc = rstd * gm[o], sh = betam[o] - mean * sc;
    float hsel = (sc >= 0.f) ? key2f(mmax[i]) : key2f(mmin[i]);
    x4[i] = fmaxf(hsel * sc + sh, 0.f);
}

template<int C, int O>
static void run_layer(const float* xin, long sb, const float* W,
                      const float* gamma, const float* beta, int coff,
                      float* featP, float* featH,
                      double* xxb, float* dist, bool full, int* idx, int* flags,
                      float* pbuf, float* rbuf, float4* hilo,
                      double* stl, hipStream_t stream) {
    xx64_kernel<<<(BATCH * NPTS + 255) / 256, 256, 0, stream>>>(xin, sb, C, xxb);
    if (full) {
        dist_kernel<<<dim3(32, 32, BATCH), 256, 0, stream>>>(xin, sb, C, xxb, dist, 0);
        topk_wave_kernel<<<dim3(NPTS / 4, 1, BATCH), 256, 0, stream>>>(dist, idx, flags, 0);
    } else {
        for (int b = 0; b < BATCH; ++b) {
            dist_kernel<<<dim3(32, 32, 1), 256, 0, stream>>>(xin, sb, C, xxb, dist, b);
            topk_wave_kernel<<<dim3(NPTS / 4, 1, 1), 256, 0, stream>>>(dist, idx, flags, b);
        }
    }
    pr_kernel<C, O><<<BATCH * NPTS / 32, 256, 0, stream>>>(xin, sb, W, pbuf, rbuf);
    const int NT = (O == 64) ? 8 : 4;
    gather_kernel<O, NT><<<BATCH * NPTS / NT, 256, 0, stream>>>(pbuf, rbuf, idx, hilo, stl);
    double M = (double)((long)(O / 2) * NPTS * KNN);
    finalize_kernel<O><<<BATCH * NPTS / 16, 256, 0, stream>>>(hilo, flags, stl, M,
                                                              gamma, beta, featP, featH, coff);
}

extern "C" void kernel_launch(void* const* d_in, const int* in_sizes, int n_in,
                              void* d_out, int out_size, void* d_ws, size_t ws_size,
                              hipStream_t stream) {
    const float* x = (const float*)d_in[0];
    const float* W1 = (const float*)d_in[1];
    const float* g1 = (const float*)d_in[2];
    const float* b1 = (const float*)d_in[3];
    const float* W2 = (const float*)d_in[4];
    const float* g2 = (const float*)d_in[5];
    const float* b2 = (const float*)d_in[6];
    const float* W3 = (const float*)d_in[7];
    const float* g3 = (const float*)d_in[8];
    const float* b3 = (const float*)d_in[9];
    const float* Wm = (const float*)d_in[10];
    const float* bm = (const float*)d_in[11];
    const float* gm = (const float*)d_in[12];
    const float* betam = (const float*)d_in[13];

    float* out = (float*)d_out;
    float* x4 = out;
    float* featH = out + BATCH * 1024;

    char* ws = (char*)d_ws;
    size_t off = 0;
    auto alloc = [&](size_t bytes) -> void* {
        void* pp = ws + off;
        off += (bytes + 255) & ~(size_t)255;
        return pp;
    };
    double* xxb = (double*)alloc((size_t)BATCH * NPTS * 8);
    int* idx = (int*)alloc((size_t)BATCH * NPTS * KSEL * 4);
    int* flags = (int*)alloc((size_t)BATCH * NPTS * 4);
    float* featP = (float*)alloc((size_t)BATCH * 256 * NPTS * 4);
    float* pbuf = (float*)alloc((size_t)BATCH * NPTS * 128 * 4);
    float* rbuf = (float*)alloc((size_t)BATCH * NPTS * 128 * 4);
    float4* hilo = (float4*)alloc((size_t)BATCH * NPTS * 128 * 16);
    double* statsd = (double*)alloc(128 * 8);   // layers: +0,+16,+32 ; mlp: +64
    unsigned* mmax = (unsigned*)alloc((size_t)BATCH * 1024 * 4);
    unsigned* mmin = (unsigned*)alloc((size_t)BATCH * 1024 * 4);
    size_t base = off;
    bool full = (ws_size >= base + (size_t)BATCH * NPTS * NPTS * 4);
    float* dist = (float*)alloc(full ? (size_t)BATCH * NPTS * NPTS * 4
                                     : (size_t)NPTS * NPTS * 4);

    hipMemsetAsync(statsd, 0, 128 * 8, stream);
    hipMemsetAsync(mmax, 0x00, (size_t)BATCH * 1024 * 4, stream);
    hipMemsetAsync(mmin, 0xFF, (size_t)BATCH * 1024 * 4, stream);

    run_layer<3, 64>(x, 3L * NPTS, W1, g1, b1, 0,
                     featP, featH, xxb, dist, full, idx, flags, pbuf, rbuf, hilo, statsd + 0, stream);
    run_layer<64, 64>(featP, 256L * NPTS, W2, g2, b2, 64,
                      featP, featH, xxb, dist, full, idx, flags, pbuf, rbuf, hilo, statsd + 16, stream);
    run_layer<64, 128>(featP + 64L * NPTS, 256L * NPTS, W3, g3, b3, 128,
                       featP, featH, xxb, dist, full, idx, flags, pbuf, rbuf, hilo, statsd + 32, stream);

    mlp_gemm_kernel<<<dim3(16, 8, BATCH), 512, 0, stream>>>(featH, Wm, bm, mmax, mmin, statsd + 64);
    mlp_final2_kernel<<<(BATCH * 1024 + 255) / 256, 256, 0, stream>>>(statsd + 64, mmax, mmin, gm, betam, x4);
    (void)in_sizes; (void)n_in; (void)out_size; (void)ws_size;
}

// Round 17
// 464.498 us; speedup vs baseline: 5.7750x; 1.0510x over previous
//
#include <hip/hip_runtime.h>
#include <hip/hip_bf16.h>

#define NPTS 2048
#define KNN 80
#define KSEL 81
#define BATCH 4

__device__ __forceinline__ unsigned f2key(float f) {
    unsigned u = __float_as_uint(f);
    return u ^ ((u & 0x80000000u) ? 0xFFFFFFFFu : 0x80000000u);
}
__device__ __forceinline__ float key2f(unsigned k) {
    unsigned u = (k & 0x80000000u) ? (k ^ 0x80000000u) : ~k;
    return __uint_as_float(u);
}

// ---------------- xx (fp64) ----------------
__global__ void xx64_kernel(const float* __restrict__ x, long sb, int C, double* __restrict__ xx) {
    int i = blockIdx.x * 256 + threadIdx.x;
    if (i >= BATCH * NPTS) return;
    int b = i / NPTS, n = i % NPTS;
    const float* xp = x + (long)b * sb + n;
    double s = 0.0;
    for (int c = 0; c < C; ++c) { double v = (double)xp[(long)c * NPTS]; s = fma(v, v, s); }
    xx[i] = s;
}

// ---------------- dist: fp32 accumulate, fp64 final combine -> fp32 ----------------
__global__ __launch_bounds__(256) void dist_kernel(
    const float* __restrict__ x, long sb, int C,
    const double* __restrict__ xx, float* __restrict__ dist, int b_base) {
    int bz = blockIdx.z;
    int b = b_base + bz;
    int i0 = blockIdx.y * 64, j0 = blockIdx.x * 64;
    __shared__ float xi[32][64];
    __shared__ float xj[32][64];
    const float* xb = x + (long)b * sb;
    int tid = threadIdx.x, tx = tid & 15, ty = tid >> 4;
    float acc[4][4] = {};
    for (int cc = 0; cc < C; cc += 32) {
        int Cc = C - cc; if (Cc > 32) Cc = 32;
        for (int t = tid; t < Cc * 64; t += 256) {
            int c = t >> 6, l = t & 63;
            xi[c][l] = xb[(long)(cc + c) * NPTS + i0 + l];
            xj[c][l] = xb[(long)(cc + c) * NPTS + j0 + l];
        }
        __syncthreads();
        for (int c = 0; c < Cc; ++c) {
            float a[4], bb[4];
#pragma unroll
            for (int u = 0; u < 4; ++u) a[u] = xi[c][ty * 4 + u];
#pragma unroll
            for (int v = 0; v < 4; ++v) bb[v] = xj[c][tx * 4 + v];
#pragma unroll
            for (int u = 0; u < 4; ++u)
#pragma unroll
                for (int v = 0; v < 4; ++v) acc[u][v] = fmaf(a[u], bb[v], acc[u][v]);
        }
        __syncthreads();
    }
    const double* xxb = xx + b * NPTS;
    float* drow = dist + (long)bz * NPTS * NPTS;
#pragma unroll
    for (int u = 0; u < 4; ++u) {
        int i = i0 + ty * 4 + u;
        double xxi = xxb[i];
#pragma unroll
        for (int v = 0; v < 4; ++v) {
            int j = j0 + tx * 4 + v;
            drow[(long)i * NPTS + j] = (float)(2.0 * (double)acc[u][v] - xxi - xxb[j]);
        }
    }
}

// ---------------- top-81: wave-per-row radix select, 4-copy histogram ----------------
__global__ __launch_bounds__(256) void topk_wave_kernel(
    const float* __restrict__ dist, int* __restrict__ idxout,
    int* __restrict__ flags, int b_base) {
    int bz = blockIdx.z;
    int b = b_base + bz;
    int tid = threadIdx.x;
    int lane = tid & 63, w = tid >> 6;
    int row = blockIdx.x * 4 + w;
    const float* dr = dist + ((long)bz * NPTS + row) * NPTS;

    unsigned kv[32];
#pragma unroll
    for (int i = 0; i < 8; ++i) {
        float4 a = *(const float4*)(dr + i * 256 + lane * 4);
        kv[i * 4 + 0] = f2key(a.x);
        kv[i * 4 + 1] = f2key(a.y);
        kv[i * 4 + 2] = f2key(a.z);
        kv[i * 4 + 3] = f2key(a.w);
    }

    __shared__ unsigned hist[4][256][4];   // [wave][bin][copy]
    __shared__ int sel_s[4][KSEL];
    __shared__ float selv_s[4][KSEL];

    unsigned prefix = 0;
    int rem = KSEL;
    int cp = lane & 3;

    for (int pass = 0; pass < 4; ++pass) {
        int shift = 24 - pass * 8;
        uint4* h4 = (uint4*)&hist[w][0][0];
#pragma unroll
        for (int t = 0; t < 4; ++t) h4[lane + t * 64] = make_uint4(0u, 0u, 0u, 0u);
        unsigned pm = (pass == 0) ? 0u : (0xFFFFFFFFu << (shift + 8));
#pragma unroll
        for (int u = 0; u < 32; ++u) {
            if ((kv[u] & pm) == prefix)
                atomicAdd(&hist[w][(kv[u] >> shift) & 255u][cp], 1u);
        }
        uint4 c0 = h4[lane * 4 + 0];
        uint4 c1 = h4[lane * 4 + 1];
        uint4 c2 = h4[lane * 4 + 2];
        uint4 c3 = h4[lane * 4 + 3];
        unsigned b0 = c0.x + c0.y + c0.z + c0.w;
        unsigned b1 = c1.x + c1.y + c1.z + c1.w;
        unsigned b2 = c2.x + c2.y + c2.z + c2.w;
        unsigned b3 = c3.x + c3.y + c3.z + c3.w;
        unsigned loc3 = b3, loc2 = b3 + b2, loc1 = b3 + b2 + b1, loc0 = b3 + b2 + b1 + b0;
        unsigned tot = loc0;
        unsigned suf = tot;
#pragma unroll
        for (int d = 1; d < 64; d <<= 1) {
            unsigned o = __shfl_down(suf, d);
            suf += (lane + d < 64) ? o : 0u;
        }
        unsigned after = suf - tot;
        int fdig = -1, frem = 0;
        unsigned ge, gt;
        ge = loc0 + after; gt = loc1 + after;
        if (ge >= (unsigned)rem && gt < (unsigned)rem) { fdig = lane * 4 + 0; frem = rem - (int)gt; }
        ge = loc1 + after; gt = loc2 + after;
        if (ge >= (unsigned)rem && gt < (unsigned)rem) { fdig = lane * 4 + 1; frem = rem - (int)gt; }
        ge = loc2 + after; gt = loc3 + after;
        if (ge >= (unsigned)rem && gt < (unsigned)rem) { fdig = lane * 4 + 2; frem = rem - (int)gt; }
        ge = loc3 + after; gt = after;
        if (ge >= (unsigned)rem && gt < (unsigned)rem) { fdig = lane * 4 + 3; frem = rem - (int)gt; }
        unsigned long long bal = __ballot(fdig >= 0);
        int src = __ffsll((unsigned long long)bal) - 1;
        fdig = __shfl(fdig, src);
        frem = __shfl(frem, src);
        prefix |= ((unsigned)fdig) << shift;
        rem = frem;
    }

    int myc = 0;
#pragma unroll
    for (int u = 0; u < 32; ++u) myc += (kv[u] > prefix) ? 1 : 0;
    int inc = myc;
#pragma unroll
    for (int d = 1; d < 64; d <<= 1) {
        int o = __shfl_up(inc, d);
        inc += (lane >= d) ? o : 0;
    }
    int off = inc - myc;
    int pos = off;
#pragma unroll
    for (int u = 0; u < 32; ++u) {
        if (kv[u] > prefix) {
            int e = (u >> 2) * 256 + lane * 4 + (u & 3);
            sel_s[w][pos] = e;
            selv_s[w][pos] = key2f(kv[u]);
            ++pos;
        }
    }
    int cgt = __shfl(inc, 63);

    unsigned tmask = 0;
#pragma unroll
    for (int u = 0; u < 32; ++u)
        if (kv[u] == prefix) tmask |= (1u << u);
    float vtie = key2f(prefix);
    for (int t = 0; t < rem; ++t) {
        int best = 0x7FFFFFFF;
        unsigned m = tmask;
        while (m) {
            int u = __ffs(m) - 1;
            m &= m - 1;
            int e = (u >> 2) * 256 + lane * 4 + (u & 3);
            best = min(best, e);
        }
#pragma unroll
        for (int d = 32; d > 0; d >>= 1) best = min(best, __shfl_xor(best, d));
        if (((best >> 2) & 63) == lane) {
            int u = ((best >> 8) << 2) | (best & 3);
            tmask &= ~(1u << u);
        }
        if (lane == 0) { sel_s[w][cgt + t] = best; selv_s[w][cgt + t] = vtie; }
    }

    unsigned bk = 0xFFFFFFFFu; int bi = -1, bp = -1;
    if (lane < KSEL) { bk = f2key(selv_s[w][lane]); bi = sel_s[w][lane]; bp = lane; }
    int l2 = lane + 64;
    if (l2 < KSEL) {
        unsigned k2 = f2key(selv_s[w][l2]); int i2 = sel_s[w][l2];
        if (k2 < bk || (k2 == bk && i2 > bi)) { bk = k2; bi = i2; bp = l2; }
    }
#pragma unroll
    for (int d = 32; d > 0; d >>= 1) {
        unsigned ok = __shfl_xor(bk, d);
        int oi = __shfl_xor(bi, d);
        int op = __shfl_xor(bp, d);
        if (ok < bk || (ok == bk && oi > bi)) { bk = ok; bi = oi; bp = op; }
    }
    int p81 = bp;
    bk = 0xFFFFFFFFu; bi = -1; bp = -1;
    if (lane < KSEL && lane != p81) { bk = f2key(selv_s[w][lane]); bi = sel_s[w][lane]; bp = lane; }
    if (l2 < KSEL && l2 != p81) {
        unsigned k2 = f2key(selv_s[w][l2]); int i2 = sel_s[w][l2];
        if (k2 < bk || (k2 == bk && i2 > bi)) { bk = k2; bi = i2; bp = l2; }
    }
#pragma unroll
    for (int d = 32; d > 0; d >>= 1) {
        unsigned ok = __shfl_xor(bk, d);
        int oi = __shfl_xor(bi, d);
        int op = __shfl_xor(bp, d);
        if (ok < bk || (ok == bk && oi > bi)) { bk = ok; bi = oi; bp = op; }
    }
    int p80 = bp;

    if (lane == 0) {
        int ts; float tv;
        ts = sel_s[w][80]; sel_s[w][80] = sel_s[w][p81]; sel_s[w][p81] = ts;
        tv = selv_s[w][80]; selv_s[w][80] = selv_s[w][p81]; selv_s[w][p81] = tv;
        if (p80 == 80) p80 = p81;
        ts = sel_s[w][79]; sel_s[w][79] = sel_s[w][p80]; sel_s[w][p80] = ts;
        tv = selv_s[w][79]; selv_s[w][79] = selv_s[w][p80]; selv_s[w][p80] = tv;
        float d80f = selv_s[w][79], d81f = selv_s[w][80];
        float eta = 8e-5f + 4e-6f * fabsf(d80f);
        flags[b * NPTS + row] = ((d80f - d81f) <= eta) ? 1 : 0;
    }
    int* outp = idxout + ((long)b * NPTS + row) * KSEL;
    for (int t = lane; t < KSEL; t += 64) outp[t] = sel_s[w][t];
}

// ---------------- p/r projections ----------------
template<int C, int O>
__global__ __launch_bounds__(256) void pr_kernel(
    const float* __restrict__ x, long sb, const float* __restrict__ W,
    float* __restrict__ p, float* __restrict__ r) {
    __shared__ float wp[C * O];
    __shared__ float wr[C * O];
    __shared__ float xs[C][32];
    int nb = NPTS / 32;
    int b = blockIdx.x / nb;
    int n0 = (blockIdx.x % nb) * 32;
    int tid = threadIdx.x;
    for (int t = tid; t < C * O; t += 256) {
        int o = t / C, c = t % C;
        float w1 = W[o * 2 * C + c];
        wp[o * C + c] = w1;
        wr[o * C + c] = W[o * 2 * C + C + c] - w1;
    }
    const float* xb = x + (long)b * sb;
    for (int t = tid; t < C * 32; t += 256) {
        int c = t / 32, nn = t & 31;
        xs[c][nn] = xb[(long)c * NPTS + n0 + nn];
    }
    __syncthreads();
    int o = tid % O;
    int nl0 = tid / O, per = 256 / O;
    for (int nl = nl0; nl < 32; nl += per) {
        float pa = 0.f, ra = 0.f;
        for (int c = 0; c < C; ++c) {
            float xv = xs[c][nl];
            pa = fmaf(wp[o * C + c], xv, pa);
            ra = fmaf(wr[o * C + c], xv, ra);
        }
        long po = ((long)b * NPTS + n0 + nl) * O + o;
        p[po] = pa;
        r[po] = ra;
    }
}

// ---------------- FUSED gather: hilo + fp64 stats via global atomics ----------------
template<int O, int NT>
__global__ __launch_bounds__(256) void gather_kernel(
    const float* __restrict__ p, const float* __restrict__ r,
    const int* __restrict__ idx, float4* __restrict__ hilo,
    double* __restrict__ stats) {
    const int R = (NT * O) / 256;
    const int STEP = 256 / O;
    __shared__ float r_s[NT * O];
    __shared__ int idx_s[NT * KSEL];
    __shared__ double gs8[8], gq8[8];
    int nb = NPTS / NT;
    int b = blockIdx.x / nb;
    int n0 = (blockIdx.x % nb) * NT;
    int tid = threadIdx.x;
    for (int t = tid; t < NT * O; t += 256) r_s[t] = r[((long)b * NPTS + n0) * O + t];
    for (int t = tid; t < NT * KSEL; t += 256) idx_s[t] = idx[((long)b * NPTS + n0) * KSEL + t];
    __syncthreads();
    int o = tid % O;
    int nlb = tid / O;
    const float* pb = p + (long)b * NPTS * O;
    float hi[R], lo[R], ha[R], hb[R], rv[R];
    int nlr[R];
#pragma unroll
    for (int u = 0; u < R; ++u) {
        nlr[u] = nlb + u * STEP;
        rv[u] = r_s[nlr[u] * O + o];
        hi[u] = -3.0e38f; lo[u] = 3.0e38f;
    }
    float s0 = 0.f, s1 = 0.f, q0 = 0.f, q1 = 0.f;
    int kk = 0;
    for (; kk + 3 < KNN - 1; kk += 4) {
        int j0[R], j1[R], j2[R], j3[R];
#pragma unroll
        for (int u = 0; u < R; ++u) {
            const int* ip = &idx_s[nlr[u] * KSEL + kk];
            j0[u] = ip[0]; j1[u] = ip[1]; j2[u] = ip[2]; j3[u] = ip[3];
        }
#pragma unroll
        for (int u = 0; u < R; ++u) {
            float h0 = pb[(long)j0[u] * O + o] + rv[u];
            float h1 = pb[(long)j1[u] * O + o] + rv[u];
            float h2 = pb[(long)j2[u] * O + o] + rv[u];
            float h3 = pb[(long)j3[u] * O + o] + rv[u];
            hi[u] = fmaxf(hi[u], fmaxf(fmaxf(h0, h1), fmaxf(h2, h3)));
            lo[u] = fminf(lo[u], fminf(fminf(h0, h1), fminf(h2, h3)));
            s0 += h0 + h2;
            s1 += h1 + h3;
            q0 = fmaf(h0, h0, q0); q0 = fmaf(h2, h2, q0);
            q1 = fmaf(h1, h1, q1); q1 = fmaf(h3, h3, q1);
        }
    }
    for (; kk < KNN - 1; ++kk) {
#pragma unroll
        for (int u = 0; u < R; ++u) {
            int j = idx_s[nlr[u] * KSEL + kk];
            float h = pb[(long)j * O + o] + rv[u];
            hi[u] = fmaxf(hi[u], h);
            lo[u] = fminf(lo[u], h);
            s0 += h;
            q0 = fmaf(h, h, q0);
        }
    }
#pragma unroll
    for (int u = 0; u < R; ++u) {
        int j = idx_s[nlr[u] * KSEL + (KNN - 1)];
        ha[u] = pb[(long)j * O + o] + rv[u];
        s0 += ha[u];
        q0 = fmaf(ha[u], ha[u], q0);
        int j2 = idx_s[nlr[u] * KSEL + KNN];
        hb[u] = pb[(long)j2 * O + o] + rv[u];
    }
#pragma unroll
    for (int u = 0; u < R; ++u)
        hilo[((long)b * NPTS + n0 + nlr[u]) * O + o] = make_float4(hi[u], lo[u], ha[u], hb[u]);
    double s = (double)s0 + (double)s1;
    double q = (double)q0 + (double)q1;
    for (int off = 16; off > 0; off >>= 1) {
        s += __shfl_xor(s, off);
        q += __shfl_xor(q, off);
    }
    int hw = tid >> 5;
    if ((tid & 31) == 0) { gs8[hw] = s; gq8[hw] = q; }
    __syncthreads();
    if (tid < 2) {
        double ss = 0.0, qq = 0.0;
        for (int h2 = 0; h2 < 8; ++h2) {
            int o0 = (h2 * 32) % O;
            int g = o0 / (O / 2);
            if (g == tid) { ss += gs8[h2]; qq += gq8[h2]; }
        }
        atomicAdd(&stats[(b * 2 + tid) * 2 + 0], ss);
        atomicAdd(&stats[(b * 2 + tid) * 2 + 1], qq);
    }
}

// ---------------- finalize: compute ms from stats + normalize extremes + leaky + hedge ----------------
template<int O>
__global__ __launch_bounds__(256) void finalize_kernel(
    const float4* __restrict__ hilo, const int* __restrict__ flags,
    const double* __restrict__ st, double M,
    const float* __restrict__ gamma, const float* __restrict__ beta,
    float* __restrict__ featP, float* __restrict__ featH, int coff) {
    const int NT = 16;
    __shared__ float smP[O * NT], smH[O * NT];
    __shared__ float sc_s[O], sh_s[O];
    __shared__ int flag_s[NT];
    int nb = NPTS / NT;
    int b = blockIdx.x / nb;
    int n0 = (blockIdx.x % nb) * NT;
    int tid = threadIdx.x;
    if (tid < NT) flag_s[tid] = flags[b * NPTS + n0 + tid];
    if (tid < O) {
        int g = tid / (O / 2);
        double s = st[(b * 2 + g) * 2 + 0], q = st[(b * 2 + g) * 2 + 1];
        double meand = s / M;
        double var = q / M - meand * meand;
        float mean = (float)meand;
        float rstd = (float)(1.0 / sqrt(var + 1e-5));
        float sc = rstd * gamma[tid];
        sc_s[tid] = sc;
        sh_s[tid] = beta[tid] - mean * sc;
    }
    __syncthreads();
    int o = tid % O;
    int nl0 = tid / O, nrep = 256 / O;
    float sc = sc_s[o], sh = sh_s[o];
    bool pos = (sc >= 0.f);
    for (int nl = nl0; nl < NT; nl += nrep) {
        float4 v = hilo[((long)b * NPTS + n0 + nl) * O + o];
        float h0 = pos ? fmaxf(v.x, v.z) : fminf(v.y, v.z);
        float h1 = pos ? fmaxf(v.x, v.w) : fminf(v.y, v.w);
        float v0 = h0 * sc + sh; v0 = v0 >= 0.f ? v0 : 0.2f * v0;
        float v1 = h1 * sc + sh; v1 = v1 >= 0.f ? v1 : 0.2f * v1;
        float outv = v0;
        if (flag_s[nl] && fabsf(v0 - v1) <= 0.45f) outv = 0.5f * (v0 + v1);
        smP[o * NT + nl] = v0;
        smH[o * NT + nl] = outv;
    }
    __syncthreads();
    long obase = ((long)b * 256 + coff) * NPTS + n0;
    for (int i = tid; i < O * NT; i += 256) {
        int oo = i / NT, nl = i % NT;
        featP[obase + (long)oo * NPTS + nl] = smP[i];
        featH[obase + (long)oo * NPTS + nl] = smH[i];
    }
}

// ---------------- MLP GEMM: 128o x 128n tile, 512 threads, 4x8/thread, kc=32 (33KB LDS) ----------------
__global__ __launch_bounds__(512) void mlp_gemm_kernel(
    const float* __restrict__ xf, const float* __restrict__ Wm, const float* __restrict__ bm,
    unsigned* __restrict__ mmax, unsigned* __restrict__ mmin, double* __restrict__ stats) {
    int b = blockIdx.z;
    int o0 = blockIdx.y * 128, n0 = blockIdx.x * 128;
    __shared__ float wm_s[128][33];   // [o][c] — reads broadcast within 16-lane groups
    __shared__ float xf_s[32][128];   // [c][n]
    int tid = threadIdx.x;
    int tx = tid & 15, ty = tid >> 4;
    float acc[4][8] = {};
    for (int kc = 0; kc < 256; kc += 32) {
#pragma unroll
        for (int i = 0; i < 2; ++i) {
            int f = tid + i * 512;          // float4 index in 128x32 W tile
            int o = f >> 3;                  // 8 float4 per o-row
            int c4 = (f & 7) * 4;
            float4 wv = *(const float4*)&Wm[(long)(o0 + o) * 256 + kc + c4];
            wm_s[o][c4 + 0] = wv.x;
            wm_s[o][c4 + 1] = wv.y;
            wm_s[o][c4 + 2] = wv.z;
            wm_s[o][c4 + 3] = wv.w;
        }
#pragma unroll
        for (int i = 0; i < 2; ++i) {
            int f = tid + i * 512;          // float4 index in 32x128 xf tile
            int c = f >> 5;
            int n4 = (f & 31) * 4;
            float4 v = *(const float4*)&xf[(long)b * 256 * NPTS + (long)(kc + c) * NPTS + n0 + n4];
            *(float4*)&xf_s[c][n4] = v;
        }
        __syncthreads();
        for (int c = 0; c < 32; ++c) {
            float a[4], bb[8];
#pragma unroll
            for (int u = 0; u < 4; ++u) a[u] = wm_s[ty * 4 + u][c];
            float4 bA = *(const float4*)&xf_s[c][tx * 4];
            float4 bB = *(const float4*)&xf_s[c][64 + tx * 4];
            bb[0] = bA.x; bb[1] = bA.y; bb[2] = bA.z; bb[3] = bA.w;
            bb[4] = bB.x; bb[5] = bB.y; bb[6] = bB.z; bb[7] = bB.w;
#pragma unroll
            for (int u = 0; u < 4; ++u)
#pragma unroll
                for (int v = 0; v < 8; ++v) acc[u][v] = fmaf(a[u], bb[v], acc[u][v]);
        }
        __syncthreads();
    }
    double s = 0.0, q = 0.0;
#pragma unroll
    for (int u = 0; u < 4; ++u) {
        int o = o0 + ty * 4 + u;
        float bv = bm[o];
        float mx = -3.0e38f, mn = 3.0e38f;
#pragma unroll
        for (int v = 0; v < 8; ++v) {
            float hv = acc[u][v] + bv;
            mx = fmaxf(mx, hv);
            mn = fminf(mn, hv);
            s += (double)hv;
            q += (double)hv * (double)hv;
        }
        for (int d = 1; d < 16; d <<= 1) {
            mx = fmaxf(mx, __shfl_xor(mx, d));
            mn = fminf(mn, __shfl_xor(mn, d));
        }
        if (tx == 0) {
            atomicMax(&mmax[((long)b << 10) + o], f2key(mx));
            atomicMin(&mmin[((long)b << 10) + o], f2key(mn));
        }
    }
    for (int off = 32; off > 0; off >>= 1) {
        s += __shfl_xor(s, off);
        q += __shfl_xor(q, off);
    }
    __shared__ double rs[8], rq[8];
    int wid = tid >> 6;
    if ((tid & 63) == 0) { rs[wid] = s; rq[wid] = q; }
    __syncthreads();
    if (tid == 0) {
        s = 0.0; q = 0.0;
#pragma unroll
        for (int ww = 0; ww < 8; ++ww) { s += rs[ww]; q += rq[ww]; }
        int g = o0 >> 7;
        atomicAdd(&stats[(b * 8 + g) * 2 + 0], s);
        atomicAdd(&stats[(b * 8 + g) * 2 + 1], q);
    }
}

// ---------------- MLP final: recompute ms per block + normalize + relu ----------------
__global__ void mlp_final2_kernel(
    const double* __restrict__ st, const unsigned* __restrict__ mmax,
    const unsigned* __restrict__ mmin, const float* __restrict__ gm,
    const float* __restrict__ betam, float* __restrict__ x4) {
    __shared__ double ms_s[64];
    int tid = threadIdx.x;
    if (tid < 32) {
        double s = st[tid * 2], q = st[tid * 2 + 1];
        double M = 128.0 * 2048.0;
        double mean = s / M;
        double var = q / M - mean * mean;
        ms_s[tid * 2] = mean;
        ms_s[tid * 2 + 1] = 1.0 / sqrt(var + 1e-5);
    }
    __syncthreads();
    int i = blockIdx.x * 256 + tid;
    if (i >= BATCH * 1024) return;
    int b = i >> 10, o = i & 1023;
    int g = o >> 7;
    float mean = (float)ms_s[(b * 8 + g) * 2], rstd = (float)ms_s[(b * 8 + g) * 2 + 1];
    float sc = rstd * gm[o], sh = betam[o] - mean * sc;
    float hsel = (sc >= 0.f) ? key2f(mmax[i]) : key2f(mmin[i]);
    x4[i] = fmaxf(hsel * sc + sh, 0.f);
}

template<int C, int O>
static void run_layer(const float* xin, long sb, const float* W,
                      const float* gamma, const float* beta, int coff,
                      float* featP, float* featH,
                      double* xxb, float* dist, bool full, int* idx, int* flags,
                      float* pbuf, float* rbuf, float4* hilo,
                      double* stl, hipStream_t stream) {
    xx64_kernel<<<(BATCH * NPTS + 255) / 256, 256, 0, stream>>>(xin, sb, C, xxb);
    if (full) {
        dist_kernel<<<dim3(32, 32, BATCH), 256, 0, stream>>>(xin, sb, C, xxb, dist, 0);
        topk_wave_kernel<<<dim3(NPTS / 4, 1, BATCH), 256, 0, stream>>>(dist, idx, flags, 0);
    } else {
        for (int b = 0; b < BATCH; ++b) {
            dist_kernel<<<dim3(32, 32, 1), 256, 0, stream>>>(xin, sb, C, xxb, dist, b);
            topk_wave_kernel<<<dim3(NPTS / 4, 1, 1), 256, 0, stream>>>(dist, idx, flags, b);
        }
    }
    pr_kernel<C, O><<<BATCH * NPTS / 32, 256, 0, stream>>>(xin, sb, W, pbuf, rbuf);
    gather_kernel<O, 8><<<BATCH * NPTS / 8, 256, 0, stream>>>(pbuf, rbuf, idx, hilo, stl);
    double M = (double)((long)(O / 2) * NPTS * KNN);
    finalize_kernel<O><<<BATCH * NPTS / 16, 256, 0, stream>>>(hilo, flags, stl, M,
                                                              gamma, beta, featP, featH, coff);
}

extern "C" void kernel_launch(void* const* d_in, const int* in_sizes, int n_in,
                              void* d_out, int out_size, void* d_ws, size_t ws_size,
                              hipStream_t stream) {
    const float* x = (const float*)d_in[0];
    const float* W1 = (const float*)d_in[1];
    const float* g1 = (const float*)d_in[2];
    const float* b1 = (const float*)d_in[3];
    const float* W2 = (const float*)d_in[4];
    const float* g2 = (const float*)d_in[5];
    const float* b2 = (const float*)d_in[6];
    const float* W3 = (const float*)d_in[7];
    const float* g3 = (const float*)d_in[8];
    const float* b3 = (const float*)d_in[9];
    const float* Wm = (const float*)d_in[10];
    const float* bm = (const float*)d_in[11];
    const float* gm = (const float*)d_in[12];
    const float* betam = (const float*)d_in[13];

    float* out = (float*)d_out;
    float* x4 = out;
    float* featH = out + BATCH * 1024;

    char* ws = (char*)d_ws;
    size_t off = 0;
    auto alloc = [&](size_t bytes) -> void* {
        void* pp = ws + off;
        off += (bytes + 255) & ~(size_t)255;
        return pp;
    };
    double* xxb = (double*)alloc((size_t)BATCH * NPTS * 8);
    int* idx = (int*)alloc((size_t)BATCH * NPTS * KSEL * 4);
    int* flags = (int*)alloc((size_t)BATCH * NPTS * 4);
    float* featP = (float*)alloc((size_t)BATCH * 256 * NPTS * 4);
    float* pbuf = (float*)alloc((size_t)BATCH * NPTS * 128 * 4);
    float* rbuf = (float*)alloc((size_t)BATCH * NPTS * 128 * 4);
    float4* hilo = (float4*)alloc((size_t)BATCH * NPTS * 128 * 16);
    double* statsd = (double*)alloc(128 * 8);   // layers: +0,+16,+32 ; mlp: +64
    unsigned* mmax = (unsigned*)alloc((size_t)BATCH * 1024 * 4);
    unsigned* mmin = (unsigned*)alloc((size_t)BATCH * 1024 * 4);
    size_t base = off;
    bool full = (ws_size >= base + (size_t)BATCH * NPTS * NPTS * 4);
    float* dist = (float*)alloc(full ? (size_t)BATCH * NPTS * NPTS * 4
                                     : (size_t)NPTS * NPTS * 4);

    hipMemsetAsync(statsd, 0, 128 * 8, stream);
    hipMemsetAsync(mmax, 0x00, (size_t)BATCH * 1024 * 4, stream);
    hipMemsetAsync(mmin, 0xFF, (size_t)BATCH * 1024 * 4, stream);

    run_layer<3, 64>(x, 3L * NPTS, W1, g1, b1, 0,
                     featP, featH, xxb, dist, full, idx, flags, pbuf, rbuf, hilo, statsd + 0, stream);
    run_layer<64, 64>(featP, 256L * NPTS, W2, g2, b2, 64,
                      featP, featH, xxb, dist, full, idx, flags, pbuf, rbuf, hilo, statsd + 16, stream);
    run_layer<64, 128>(featP + 64L * NPTS, 256L * NPTS, W3, g3, b3, 128,
                       featP, featH, xxb, dist, full, idx, flags, pbuf, rbuf, hilo, statsd + 32, stream);

    mlp_gemm_kernel<<<dim3(16, 8, BATCH), 512, 0, stream>>>(featH, Wm, bm, mmax, mmin, statsd + 64);
    mlp_final2_kernel<<<(BATCH * 1024 + 255) / 256, 256, 0, stream>>>(statsd + 64, mmax, mmin, gm, betam, x4);
    (void)in_sizes; (void)n_in; (void)out_size; (void)ws_size;
}